// Round 2
// baseline (1369.441 us; speedup 1.0000x reference)
//
#include <hip/hip_runtime.h>

typedef __attribute__((ext_vector_type(8))) short short8;
typedef __attribute__((ext_vector_type(4))) float f32x4;
typedef __attribute__((ext_vector_type(4))) unsigned short u16x4;
typedef unsigned short u16;
typedef unsigned int u32;

#define DEV static __device__ __forceinline__

DEV u16 f2b(float f) {
  u32 u = __builtin_bit_cast(u32, f);
  return (u16)((u + 0x7fffu + ((u >> 16) & 1u)) >> 16);
}
DEV float b2f(u16 h) {
  u32 u = ((u32)h) << 16;
  return __builtin_bit_cast(float, u);
}
DEV short8 ld8(const u16* p) { return *reinterpret_cast<const short8*>(p); }
DEV f32x4 mfma16(short8 a, short8 b, f32x4 c) {
  return __builtin_amdgcn_mfma_f32_16x16x32_bf16(a, b, c, 0, 0, 0);
}
DEV float wredsum(float v) {
#pragma unroll
  for (int off = 1; off < 64; off <<= 1) v += __shfl_xor(v, off);
  return v;
}

// ---- weight arena (u16 element offsets) ----
#define WQKV   0         // [768][256]
#define WPROJ  196608    // [256][256]
#define WM1    262144    // [1024][256]
#define WM2    524288    // [256][1024]
#define WSKIP  786432    // [256][256]
#define WUP    851968    // [4][256][512]  kk = kh*2+kw

// ---- ws byte offsets (total need ~92MB) ----
#define OFF_BIAS 2752512u    // f32 [8][64][64]
#define OFF_SC   2883584u    // bf16 shortcut/x2 [73728][256]  (36MB)
#define OFF_WIN  40632320u   // bf16 win/ob [76832][256]; later h1 quarter
#define OFF_Q    79970304u   // bf16 per-image q [1568][49][32]
#define OFF_K    84887552u
#define OFF_VT   89804800u   // bf16 per-image v_t [1568][32][64]
#define WS_NEED  96227328u

__global__ void k_sentinel(float* out) { out[threadIdx.x] = 31337.0f; }

// ================= prep: weights -> bf16, up_w transpose, bias table ==========
__global__ __launch_bounds__(256) void k_prep(
    const float* qkv_w, const float* proj_w, const float* mlp_w1,
    const float* mlp_w2, const float* skip_w, const float* up_w,
    const float* rpb, u16* W, float* bias_g) {
  int i = blockIdx.x * 256 + threadIdx.x;
  if (i < 196608) { W[WQKV + i] = f2b(qkv_w[i]); return; }
  i -= 196608;
  if (i < 65536) { W[WPROJ + i] = f2b(proj_w[i]); return; }
  i -= 65536;
  if (i < 262144) { W[WM1 + i] = f2b(mlp_w1[i]); return; }
  i -= 262144;
  if (i < 262144) { W[WM2 + i] = f2b(mlp_w2[i]); return; }
  i -= 262144;
  if (i < 65536) { W[WSKIP + i] = f2b(skip_w[i]); return; }
  i -= 65536;
  if (i < 524288) {
    int ci = i & 511; int rest = i >> 9; int co = rest & 255; int kk = rest >> 8;
    W[WUP + i] = f2b(up_w[ci * 1024 + co * 4 + kk]);
    return;
  }
  i -= 524288;
  if (i < 32768) {
    int h = i >> 12, r = i & 4095, ii = r >> 6, j = r & 63;
    float v;
    if (j >= 49) v = -1e30f;
    else if (ii >= 49) v = 0.f;
    else {
      int d0 = (ii / 7 - j / 7) + 6, d1 = (ii % 7 - j % 7) + 6;
      v = rpb[(d0 * 13 + d1) * 8 + h];
    }
    bias_g[i] = v;
  }
}

// ============== K1: convT + skip 1x1 + LN1 + window partition =================
// grid: b*96 + h. Block covers all 96 output w (both kw parities) x 256 cols.
__global__ __launch_bounds__(256) void k1_conv(
    const u16* W, const float* xg, const float* skipg,
    const float* up_b, const float* g1, const float* be1,
    u16* sc, u16* win) {
  __shared__ __align__(16) u16 SL[26112];  // 52224B; xs[48][520] / ss[96][272] / y[96][264]
  int blk = blockIdx.x;
  int b = blk / 96, h = blk % 96;
  int kh = h & 1, ih = h >> 1;
  int tid = threadIdx.x;
  int lane = tid & 63, wave = tid >> 6;
  int m = lane & 15, gq = lane >> 4, k0 = gq * 8;
  // stage x slab: x[b][ci][ih][t] -> xs[t][ci], stride 520
  {
    const float* src = xg + (size_t)b * 512 * 2304 + (size_t)ih * 48;
    for (int it = 0; it < 96; it++) {
      int idx = it * 256 + tid;           // 512*48 = 24576
      int ci = idx / 48, t = idx - ci * 48;
      SL[t * 520 + ci] = f2b(src[(size_t)ci * 2304 + t]);
    }
  }
  __syncthreads();
  f32x4 acc[2][3][4] = {};
#pragma unroll 2
  for (int ks = 0; ks < 16; ks++) {
    short8 a[3];
#pragma unroll
    for (int mt = 0; mt < 3; mt++)
      a[mt] = ld8(&SL[(mt * 16 + m) * 520 + ks * 32 + k0]);
#pragma unroll
    for (int kw = 0; kw < 2; kw++)
#pragma unroll
      for (int nt = 0; nt < 4; nt++) {
        short8 bb = ld8(W + WUP + (size_t)(kh * 2 + kw) * 131072 +
                        (size_t)(wave * 64 + nt * 16 + m) * 512 + ks * 32 + k0);
#pragma unroll
        for (int mt = 0; mt < 3; mt++)
          acc[kw][mt][nt] = mfma16(a[mt], bb, acc[kw][mt][nt]);
      }
  }
  __syncthreads();  // done reading xs
  float ub[4];
#pragma unroll
  for (int nt = 0; nt < 4; nt++) ub[nt] = up_b[wave * 64 + nt * 16 + m];
  // shortcut = conv + up_b (global)
#pragma unroll
  for (int kw = 0; kw < 2; kw++)
#pragma unroll
    for (int mt = 0; mt < 3; mt++)
#pragma unroll
      for (int nt = 0; nt < 4; nt++)
#pragma unroll
        for (int r = 0; r < 4; r++) {
          int t = mt * 16 + gq * 4 + r;
          int w = kw + 2 * t;
          int c = wave * 64 + nt * 16 + m;
          sc[(((size_t)b * 96 + h) * 96 + w) * 256 + c] = f2b(acc[kw][mt][nt][r] + ub[nt]);
        }
  // stage skip slab: skip[b][ci][h][w] -> ss[w][ci], stride 272
  for (int it = 0; it < 96; it++) {
    int idx = it * 256 + tid;             // 256*96 = 24576
    int ci = idx / 96, w = idx - ci * 96;
    SL[w * 272 + ci] = f2b(skipg[(((size_t)b * 256 + ci) * 96 + h) * 96 + w]);
  }
  __syncthreads();
  // skip 1x1 GEMM (K=256), adds into acc
#pragma unroll 2
  for (int ks = 0; ks < 8; ks++) {
    short8 a2[2][3];
#pragma unroll
    for (int kw = 0; kw < 2; kw++)
#pragma unroll
      for (int mt = 0; mt < 3; mt++)
        a2[kw][mt] = ld8(&SL[(kw + 2 * (mt * 16 + m)) * 272 + ks * 32 + k0]);
#pragma unroll
    for (int nt = 0; nt < 4; nt++) {
      short8 bb = ld8(W + WSKIP + (size_t)(wave * 64 + nt * 16 + m) * 256 + ks * 32 + k0);
#pragma unroll
      for (int kw = 0; kw < 2; kw++)
#pragma unroll
        for (int mt = 0; mt < 3; mt++)
          acc[kw][mt][nt] = mfma16(a2[kw][mt], bb, acc[kw][mt][nt]);
    }
  }
  __syncthreads();  // done reading ss
  // y -> ylds bf16 [96][264]
#pragma unroll
  for (int kw = 0; kw < 2; kw++)
#pragma unroll
    for (int mt = 0; mt < 3; mt++)
#pragma unroll
      for (int nt = 0; nt < 4; nt++)
#pragma unroll
        for (int r = 0; r < 4; r++) {
          int t = mt * 16 + gq * 4 + r;
          int w = kw + 2 * t;
          int c = wave * 64 + nt * 16 + m;
          SL[w * 264 + c] = f2b(acc[kw][mt][nt][r] + ub[nt]);
        }
  __syncthreads();
  // LN1 + window-partition write (24 rows per wave)
  int hw7 = h / 7, hm7 = h % 7;
  f32x4 gg = *(const f32x4*)&g1[lane * 4];
  f32x4 be = *(const f32x4*)&be1[lane * 4];
  for (int tt = 0; tt < 24; tt++) {
    int w = wave * 24 + tt;
    u16x4 raw = *(const u16x4*)&SL[w * 264 + lane * 4];
    f32x4 v;
#pragma unroll
    for (int q2 = 0; q2 < 4; q2++) v[q2] = b2f(raw[q2]);
    float s1 = wredsum(v[0] + v[1] + v[2] + v[3]);
    float mean = s1 * 0.00390625f;
    f32x4 dv; float sq = 0.f;
#pragma unroll
    for (int q2 = 0; q2 < 4; q2++) { dv[q2] = v[q2] - mean; sq += dv[q2] * dv[q2]; }
    float s2 = wredsum(sq);
    float rstd = rsqrtf(s2 * 0.00390625f + 1e-6f);
    int b_ = b * 196 + hw7 * 14 + (w / 7);
    int iw = hm7 * 7 + (w % 7);
    u16x4 ov;
#pragma unroll
    for (int q2 = 0; q2 < 4; q2++) ov[q2] = f2b(dv[q2] * rstd * gg[q2] + be[q2]);
    *reinterpret_cast<u16x4*>(win + ((size_t)b_ * 49 + iw) * 256 + lane * 4) = ov;
  }
}

// ============== K2: qkv GEMM per image (9604 rows, N=768, K=256) ==============
__global__ __launch_bounds__(256) void k2_qkv(
    const u16* W, const u16* winb, const float* qkv_b,
    u16* qc, u16* kc, u16* vtc) {
  int lane = threadIdx.x & 63, wave = threadIdx.x >> 6;
  int m = lane & 15, gq = lane >> 4, k0 = gq * 8;
  int g0 = blockIdx.x * 16;
  int cbase = blockIdx.y * 256 + wave * 64;
  int row = g0 + m; if (row > 9603) row = 9603;
  const u16* A = winb + (size_t)row * 256;
  f32x4 acc[4] = {};
#pragma unroll 4
  for (int ks = 0; ks < 8; ks++) {
    short8 a = ld8(A + ks * 32 + k0);
#pragma unroll
    for (int nt = 0; nt < 4; nt++) {
      short8 bb = ld8(W + WQKV + (size_t)(cbase + nt * 16 + m) * 256 + ks * 32 + k0);
      acc[nt] = mfma16(a, bb, acc[nt]);
    }
  }
#pragma unroll
  for (int nt = 0; nt < 4; nt++) {
    int c = cbase + nt * 16 + m;
    float qb_ = qkv_b[c];
    int type = c >> 8, hh = (c >> 5) & 7, hd = c & 31;
#pragma unroll
    for (int r = 0; r < 4; r++) {
      int g = g0 + gq * 4 + r;
      if (g >= 9604) continue;
      int bl = g / 49, i = g - bl * 49;
      float v = acc[nt][r] + qb_;
      size_t bh = (size_t)bl * 8 + hh;
      if (type == 0) qc[bh * 1568 + i * 32 + hd] = f2b(v);
      else if (type == 1) kc[bh * 1568 + i * 32 + hd] = f2b(v);
      else vtc[bh * 2048 + hd * 64 + i] = f2b(v);
    }
  }
}

// ============== K3: window attention, one wave per (window, head) =============
__global__ __launch_bounds__(256) void k3_attn(
    const u16* qc, const u16* kc, const u16* vtc, const float* bias_g, u16* obb) {
  __shared__ u16 plds[4][64 * 64];
  int lane = threadIdx.x & 63, wave = threadIdx.x >> 6;
  int b_ = blockIdx.x >> 1;
  int h = (blockIdx.x & 1) * 4 + wave;
  int m = lane & 15, gq = lane >> 4, k0 = gq * 8;
  size_t bh = (size_t)b_ * 8 + h;
  const u16* Q = qc + bh * 1568;
  const u16* K = kc + bh * 1568;
  const u16* V = vtc + bh * 2048;
  const float* BI = bias_g + h * 4096;
  short8 aq[4], bk[4];
#pragma unroll
  for (int mt = 0; mt < 4; mt++) { int i = mt * 16 + m; if (i > 48) i = 48; aq[mt] = ld8(Q + i * 32 + k0); }
#pragma unroll
  for (int nt = 0; nt < 4; nt++) { int j = nt * 16 + m; if (j > 48) j = 48; bk[nt] = ld8(K + j * 32 + k0); }
  f32x4 s[4][4] = {};
#pragma unroll
  for (int mt = 0; mt < 4; mt++)
#pragma unroll
    for (int nt = 0; nt < 4; nt++)
      s[mt][nt] = mfma16(aq[mt], bk[nt], s[mt][nt]);
  const float scale = 0.1767766952966369f;  // 1/sqrt(32)
  float rsum[4][4];
#pragma unroll
  for (int mt = 0; mt < 4; mt++)
#pragma unroll
    for (int r = 0; r < 4; r++) {
      int i = mt * 16 + gq * 4 + r;
      float sv[4];
      float mx = -1e38f;
#pragma unroll
      for (int nt = 0; nt < 4; nt++) {
        sv[nt] = s[mt][nt][r] * scale + BI[i * 64 + nt * 16 + m];
        mx = fmaxf(mx, sv[nt]);
      }
      mx = fmaxf(mx, __shfl_xor(mx, 1));
      mx = fmaxf(mx, __shfl_xor(mx, 2));
      mx = fmaxf(mx, __shfl_xor(mx, 4));
      mx = fmaxf(mx, __shfl_xor(mx, 8));
      float sum = 0.f;
#pragma unroll
      for (int nt = 0; nt < 4; nt++) { sv[nt] = __expf(sv[nt] - mx); sum += sv[nt]; }
      sum += __shfl_xor(sum, 1);
      sum += __shfl_xor(sum, 2);
      sum += __shfl_xor(sum, 4);
      sum += __shfl_xor(sum, 8);
      rsum[mt][r] = sum;
      int isw = (i & 7) * 8;
#pragma unroll
      for (int nt = 0; nt < 4; nt++) {
        int j = nt * 16 + m;
        plds[wave][i * 64 + (j ^ isw)] = f2b(sv[nt]);
      }
    }
  __syncthreads();
  f32x4 o[4][2] = {};
#pragma unroll
  for (int ks = 0; ks < 2; ks++) {
    short8 bv[2];
#pragma unroll
    for (int nt = 0; nt < 2; nt++)
      bv[nt] = ld8(V + (size_t)(nt * 16 + m) * 64 + ks * 32 + k0);
#pragma unroll
    for (int mt = 0; mt < 4; mt++) {
      int i = mt * 16 + m;
      short8 ap = *reinterpret_cast<const short8*>(
          &plds[wave][i * 64 + ((ks * 32 + k0) ^ ((i & 7) * 8))]);
#pragma unroll
      for (int nt = 0; nt < 2; nt++)
        o[mt][nt] = mfma16(ap, bv[nt], o[mt][nt]);
    }
  }
#pragma unroll
  for (int mt = 0; mt < 4; mt++)
#pragma unroll
    for (int r = 0; r < 4; r++) {
      int i = mt * 16 + gq * 4 + r;
      if (i >= 49) continue;
      float rinv = 1.f / rsum[mt][r];
#pragma unroll
      for (int nt = 0; nt < 2; nt++) {
        int c = h * 32 + nt * 16 + m;
        obb[((size_t)b_ * 49 + i) * 256 + c] = f2b(o[mt][nt][r] * rinv);
      }
    }
}

// ============== K4: proj + shortcut -> x2 (in-place over sc) ==================
__global__ __launch_bounds__(256) void k4_proj(
    const u16* W, const u16* ob, const float* proj_b, u16* scx) {
  int lane = threadIdx.x & 63, wave = threadIdx.x >> 6;
  int m = lane & 15, gq = lane >> 4, k0 = gq * 8;
  int g0 = blockIdx.x * 16;
  const u16* A = ob + (size_t)g0 * 256;
  f32x4 acc[4] = {};
#pragma unroll 4
  for (int ks = 0; ks < 8; ks++) {
    short8 a = ld8(A + (size_t)m * 256 + ks * 32 + k0);
#pragma unroll
    for (int nt = 0; nt < 4; nt++) {
      short8 bb = ld8(W + WPROJ + (size_t)(wave * 64 + nt * 16 + m) * 256 + ks * 32 + k0);
      acc[nt] = mfma16(a, bb, acc[nt]);
    }
  }
#pragma unroll
  for (int r = 0; r < 4; r++) {
    int g = g0 + gq * 4 + r;
    int b_ = g / 49, i = g - b_ * 49;
    int b = b_ / 196, wrow = (b_ % 196) / 14, wcol = b_ % 14;
    int hh = wrow * 7 + i / 7, ww = wcol * 7 + i % 7;
    if (hh >= 96 || ww >= 96) continue;
    size_t tok = ((size_t)b * 96 + hh) * 96 + ww;
#pragma unroll
    for (int nt = 0; nt < 4; nt++) {
      int c = wave * 64 + nt * 16 + m;
      float v = acc[nt][r] + proj_b[c] + b2f(scx[tok * 256 + c]);
      scx[tok * 256 + c] = f2b(v);
    }
  }
}

// ============== K5: LN2 + mlp1 + exact GELU (32 tok x 256 col blocks) =========
__global__ __launch_bounds__(256) void k5_mlp1(
    const u16* W, const u16* x2b, const float* g2, const float* be2,
    const float* mb1, u16* h1q) {
  __shared__ __align__(16) u16 xl[32 * 264];
  int tid = threadIdx.x;
  int lane = tid & 63, wave = tid >> 6;
  int m = lane & 15, gq = lane >> 4, k0 = gq * 8;
  int tok0 = blockIdx.x * 32;
  // stage x2 tile
#pragma unroll
  for (int it = 0; it < 4; it++) {
    int flat = it * 2048 + tid * 8;
    int row = flat >> 8, col = flat & 255;
    *reinterpret_cast<short8*>(&xl[row * 264 + col]) =
        ld8(x2b + (size_t)(tok0 + row) * 256 + col);
  }
  __syncthreads();
  // LN2 in LDS (8 rows per wave)
  f32x4 gg = *(const f32x4*)&g2[lane * 4];
  f32x4 be = *(const f32x4*)&be2[lane * 4];
  for (int tt = 0; tt < 8; tt++) {
    int row = wave * 8 + tt;
    u16x4 raw = *(const u16x4*)&xl[row * 264 + lane * 4];
    f32x4 v;
#pragma unroll
    for (int q2 = 0; q2 < 4; q2++) v[q2] = b2f(raw[q2]);
    float s1 = wredsum(v[0] + v[1] + v[2] + v[3]);
    float mean = s1 * 0.00390625f;
    f32x4 dv; float sq = 0.f;
#pragma unroll
    for (int q2 = 0; q2 < 4; q2++) { dv[q2] = v[q2] - mean; sq += dv[q2] * dv[q2]; }
    float s2 = wredsum(sq);
    float rstd = rsqrtf(s2 * 0.00390625f + 1e-6f);
    u16x4 ov;
#pragma unroll
    for (int q2 = 0; q2 < 4; q2++) ov[q2] = f2b(dv[q2] * rstd * gg[q2] + be[q2]);
    *reinterpret_cast<u16x4*>(&xl[row * 264 + lane * 4]) = ov;
  }
  __syncthreads();
  int cbase = blockIdx.y * 256 + wave * 64;
  f32x4 acc[2][4] = {};
#pragma unroll 4
  for (int ks = 0; ks < 8; ks++) {
    short8 a0 = ld8(&xl[m * 264 + ks * 32 + k0]);
    short8 a1 = ld8(&xl[(16 + m) * 264 + ks * 32 + k0]);
#pragma unroll
    for (int nt = 0; nt < 4; nt++) {
      short8 bb = ld8(W + WM1 + (size_t)(cbase + nt * 16 + m) * 256 + ks * 32 + k0);
      acc[0][nt] = mfma16(a0, bb, acc[0][nt]);
      acc[1][nt] = mfma16(a1, bb, acc[1][nt]);
    }
  }
#pragma unroll
  for (int mt = 0; mt < 2; mt++)
#pragma unroll
    for (int nt = 0; nt < 4; nt++) {
      int c = cbase + nt * 16 + m;
      float bias = mb1[c];
#pragma unroll
      for (int r = 0; r < 4; r++) {
        int tok = tok0 + mt * 16 + gq * 4 + r;
        float v = acc[mt][nt][r] + bias;
        v = 0.5f * v * (1.f + erff(v * 0.7071067811865475f));
        h1q[(size_t)tok * 1024 + c] = f2b(v);
      }
    }
}

// ============== K6: mlp2 + residual + NCHW transpose-out ======================
__global__ __launch_bounds__(256) void k6_mlp2(
    const u16* W, const u16* h1q, const float* mb2, const u16* x2b,
    float* out, int tok_base) {
  __shared__ float ot[4][64 * 33];
  int lane = threadIdx.x & 63, wave = threadIdx.x >> 6;
  int m = lane & 15, gq = lane >> 4, k0 = gq * 8;
  int tok0 = blockIdx.x * 32;
  const u16* A = h1q + (size_t)tok0 * 1024;
  f32x4 acc[2][4] = {};
#pragma unroll 4
  for (int ks = 0; ks < 32; ks++) {
    short8 a0 = ld8(A + (size_t)m * 1024 + ks * 32 + k0);
    short8 a1 = ld8(A + (size_t)(16 + m) * 1024 + ks * 32 + k0);
#pragma unroll
    for (int nt = 0; nt < 4; nt++) {
      short8 bb = ld8(W + WM2 + (size_t)(wave * 64 + nt * 16 + m) * 1024 + ks * 32 + k0);
      acc[0][nt] = mfma16(a0, bb, acc[0][nt]);
      acc[1][nt] = mfma16(a1, bb, acc[1][nt]);
    }
  }
#pragma unroll
  for (int mt = 0; mt < 2; mt++)
#pragma unroll
    for (int nt = 0; nt < 4; nt++) {
      int cl = nt * 16 + m;
      int c = wave * 64 + cl;
      float bias = mb2[c];
#pragma unroll
      for (int r = 0; r < 4; r++) {
        int t = mt * 16 + gq * 4 + r;
        float v = acc[mt][nt][r] + bias + b2f(x2b[(size_t)(tok0 + t) * 256 + c]);
        ot[wave][cl * 33 + t] = v;
      }
    }
  __syncthreads();
  int tg = tok_base + tok0;
  int bimg = tg / 9216, hw0 = tg % 9216;
  int clh = lane >> 5, t = lane & 31;
#pragma unroll 8
  for (int j = 0; j < 32; j++) {
    int cl = j * 2 + clh;
    float v = ot[wave][cl * 33 + t];
    out[((size_t)bimg * 256 + wave * 64 + cl) * 9216 + hw0 + t] = v;
  }
}

extern "C" void kernel_launch(void* const* d_in, const int* in_sizes, int n_in,
                              void* d_out, int out_size, void* d_ws, size_t ws_size,
                              hipStream_t stream) {
  const float* x      = (const float*)d_in[0];
  const float* skipf  = (const float*)d_in[1];
  const float* up_w   = (const float*)d_in[2];
  const float* up_b   = (const float*)d_in[3];
  const float* skip_w = (const float*)d_in[4];
  const float* g1     = (const float*)d_in[5];
  const float* be1    = (const float*)d_in[6];
  const float* qkv_w  = (const float*)d_in[7];
  const float* qkv_b  = (const float*)d_in[8];
  const float* rpb    = (const float*)d_in[9];
  const float* proj_w = (const float*)d_in[10];
  const float* proj_b = (const float*)d_in[11];
  const float* g2     = (const float*)d_in[12];
  const float* be2    = (const float*)d_in[13];
  const float* m_w1   = (const float*)d_in[14];
  const float* m_b1   = (const float*)d_in[15];
  const float* m_w2   = (const float*)d_in[16];
  const float* m_b2   = (const float*)d_in[17];
  if (ws_size < WS_NEED) {  // diagnosable sentinel instead of silent no-op
    k_sentinel<<<1, 256, 0, stream>>>((float*)d_out);
    return;
  }
  char* ws = (char*)d_ws;
  u16*   W    = (u16*)ws;
  float* bias = (float*)(ws + OFF_BIAS);
  u16*   sc   = (u16*)(ws + OFF_SC);
  u16*   win  = (u16*)(ws + OFF_WIN);
  u16*   qc   = (u16*)(ws + OFF_Q);
  u16*   kc   = (u16*)(ws + OFF_K);
  u16*   vtc  = (u16*)(ws + OFF_VT);
  u16*   h1q  = win;  // reuse win region after K4

  k_prep<<<5504, 256, 0, stream>>>(qkv_w, proj_w, m_w1, m_w2, skip_w, up_w, rpb, W, bias);
  hipMemsetAsync(win, 0, 39337984u, stream);
  k1_conv<<<768, 256, 0, stream>>>(W, x, skipf, up_b, g1, be1, sc, win);
  for (int b = 0; b < 8; b++) {
    u16* winb = win + (size_t)b * 9604 * 256;
    hipMemsetAsync(vtc, 0, 6422528u, stream);
    k2_qkv<<<dim3(601, 3), 256, 0, stream>>>(W, winb, qkv_b, qc, kc, vtc);
    k3_attn<<<392, 256, 0, stream>>>(qc, kc, vtc, bias, winb);
  }
  k4_proj<<<4802, 256, 0, stream>>>(W, win, proj_b, sc);
  for (int q = 0; q < 4; q++) {
    const u16* x2b = sc + (size_t)q * 18432 * 256;
    k5_mlp1<<<dim3(576, 4), 256, 0, stream>>>(W, x2b, g2, be2, m_b1, h1q);
    k6_mlp2<<<576, 256, 0, stream>>>(W, h1q, m_b2, x2b, (float*)d_out, q * 18432);
  }
}

// Round 4
// 1333.111 us; speedup vs baseline: 1.0273x; 1.0273x over previous
//
#include <hip/hip_runtime.h>

typedef __attribute__((ext_vector_type(8))) short short8;
typedef __attribute__((ext_vector_type(4))) float f32x4;
typedef __attribute__((ext_vector_type(4))) unsigned short u16x4;
typedef unsigned short u16;
typedef unsigned int u32;

#define DEV static __device__ __forceinline__

DEV u16 f2b(float f) {
  u32 u = __builtin_bit_cast(u32, f);
  return (u16)((u + 0x7fffu + ((u >> 16) & 1u)) >> 16);
}
DEV float b2f(u16 h) {
  u32 u = ((u32)h) << 16;
  return __builtin_bit_cast(float, u);
}
DEV short8 ld8(const u16* p) { return *reinterpret_cast<const short8*>(p); }
DEV f32x4 mfma16(short8 a, short8 b, f32x4 c) {
  return __builtin_amdgcn_mfma_f32_16x16x32_bf16(a, b, c, 0, 0, 0);
}
DEV float wredsum(float v) {
#pragma unroll
  for (int off = 1; off < 64; off <<= 1) v += __shfl_xor(v, off);
  return v;
}

// ---- weight arena (u16 element offsets) ----
#define WQKV   0         // [768][256]
#define WPROJ  196608    // [256][256]
#define WM1    262144    // [1024][256]
#define WM2    524288    // [256][1024]
#define WSKIP  786432    // [256][256]
#define WUP    851968    // [4][256][512]  kk = kh*2+kw

// ---- ws byte offsets ----
#define OFF_BIAS 2752512u
#define OFF_SC   2883584u     // bf16 sc: conv-only shortcut, later x2 [73728][256]
#define OFF_OVR  40632320u    // 55,595,008B overlay:
// phase A: xt @OVR (18,874,368)
// phase B (per image): qc @OVR (4,917,248); kc @+4,917,248; vtc @+9,834,496
//   (6,422,528); sktb @+16,257,024 (4,718,592); obs @+20,975,616 (4,917,248)
// phase C: h1 @OVR (37,748,736)
#define WS_NEED  96227328u

__global__ void k_sentinel(float* out) { out[threadIdx.x] = 31337.0f; }

// ================= prep: weights -> bf16, up_w transpose, bias table ==========
__global__ __launch_bounds__(256) void k_prep(
    const float* qkv_w, const float* proj_w, const float* mlp_w1,
    const float* mlp_w2, const float* skip_w, const float* up_w,
    const float* rpb, u16* W, float* bias_g) {
  int i = blockIdx.x * 256 + threadIdx.x;
  if (i < 196608) { W[WQKV + i] = f2b(qkv_w[i]); return; }
  i -= 196608;
  if (i < 65536) { W[WPROJ + i] = f2b(proj_w[i]); return; }
  i -= 65536;
  if (i < 262144) { W[WM1 + i] = f2b(mlp_w1[i]); return; }
  i -= 262144;
  if (i < 262144) { W[WM2 + i] = f2b(mlp_w2[i]); return; }
  i -= 262144;
  if (i < 65536) { W[WSKIP + i] = f2b(skip_w[i]); return; }
  i -= 65536;
  if (i < 524288) {
    int ci = i & 511; int rest = i >> 9; int co = rest & 255; int kk = rest >> 8;
    W[WUP + i] = f2b(up_w[ci * 1024 + co * 4 + kk]);
    return;
  }
  i -= 524288;
  if (i < 32768) {
    int h = i >> 12, r = i & 4095, ii = r >> 6, j = r & 63;
    float v;
    if (j >= 49) v = -1e30f;
    else if (ii >= 49) v = 0.f;
    else {
      int d0 = (ii / 7 - j / 7) + 6, d1 = (ii % 7 - j % 7) + 6;
      v = rpb[(d0 * 13 + d1) * 8 + h];
    }
    bias_g[i] = v;
  }
}

// ============== NCHW f32 -> NHWC bf16 tiled transpose (for x) =================
__global__ __launch_bounds__(256) void k_tr(const float* src, u16* dst, int C, int HW) {
  __shared__ float t[32][33];
  int hw0 = blockIdx.x * 32, c0 = blockIdx.y * 32, b = blockIdx.z;
  int tx = threadIdx.x & 31, ty = threadIdx.x >> 5;
  const float* s = src + (size_t)b * C * HW;
  u16* d = dst + (size_t)b * C * HW;
#pragma unroll
  for (int i = 0; i < 4; i++)
    t[ty + i * 8][tx] = s[(size_t)(c0 + ty + i * 8) * HW + hw0 + tx];
  __syncthreads();
#pragma unroll
  for (int i = 0; i < 4; i++)
    d[(size_t)(hw0 + ty + i * 8) * C + c0 + tx] = f2b(t[tx][ty + i * 8]);
}

// ===== per-image skip transpose: skip[c][h][w] -> sktb[h][w][c] (bf16) ========
__global__ __launch_bounds__(256) void k_tr_skip(const float* src, u16* dst) {
  __shared__ float t[32][33];
  int w0 = blockIdx.x * 32, c0 = blockIdx.y * 32, h = blockIdx.z;
  int tx = threadIdx.x & 31, ty = threadIdx.x >> 5;
  const float* s = src + (size_t)h * 96;
  u16* d = dst + (size_t)h * 96 * 256;
#pragma unroll
  for (int i = 0; i < 4; i++)
    t[ty + i * 8][tx] = s[(size_t)(c0 + ty + i * 8) * 9216 + w0 + tx];
  __syncthreads();
#pragma unroll
  for (int i = 0; i < 4; i++)
    d[(size_t)(w0 + ty + i * 8) * 256 + c0 + tx] = f2b(t[tx][ty + i * 8]);
}

// ============== K1: convT only -> sc (conv-only shortcut) =====================
// grid (768, 2): x = b*96 + h2*2 + kw, y = par; h = 2*h2+par; 48 tokens x 256
__global__ __launch_bounds__(256) void k1_conv(
    const u16* W, const u16* xt, const float* up_b, u16* sc) {
  int blk = blockIdx.x;
  int par = blockIdx.y;
  int b = blk / 96, r0 = blk % 96;
  int h2 = r0 >> 1, kw = r0 & 1;
  int h = h2 * 2 + par;
  int lane = threadIdx.x & 63, wave = threadIdx.x >> 6;
  int m = lane & 15, gq = lane >> 4, k0 = gq * 8;
  const u16* A = xt + (((size_t)b * 48 + h2) * 48) * 512;
  const u16* B = W + WUP + (size_t)(par * 2 + kw) * 131072;
  f32x4 acc[3][4] = {};
#pragma unroll 4
  for (int ks = 0; ks < 16; ks++) {
    short8 a[3];
#pragma unroll
    for (int mt = 0; mt < 3; mt++)
      a[mt] = ld8(A + (size_t)(mt * 16 + m) * 512 + ks * 32 + k0);
#pragma unroll
    for (int nt = 0; nt < 4; nt++) {
      short8 bb = ld8(B + (size_t)(wave * 64 + nt * 16 + m) * 512 + ks * 32 + k0);
#pragma unroll
      for (int mt = 0; mt < 3; mt++)
        acc[mt][nt] = mfma16(a[mt], bb, acc[mt][nt]);
    }
  }
  float ub[4];
#pragma unroll
  for (int nt = 0; nt < 4; nt++) ub[nt] = up_b[wave * 64 + nt * 16 + m];
#pragma unroll
  for (int mt = 0; mt < 3; mt++)
#pragma unroll
    for (int nt = 0; nt < 4; nt++)
#pragma unroll
      for (int rr = 0; rr < 4; rr++) {
        int t = mt * 16 + gq * 4 + rr;
        int w = kw + 2 * t;
        int c = wave * 64 + nt * 16 + m;
        sc[(((size_t)b * 96 + h) * 96 + w) * 256 + c] = f2b(acc[mt][nt][rr] + ub[nt]);
      }
}

// ============== K2: gather + skip 1x1 + LN1 + qkv GEMM (per image) ============
// grid 301: 32 window-tokens per block; each wave: skip N=64, qkv N=192
__global__ __launch_bounds__(256) void k2_qkv(
    const u16* W, const u16* scb, const u16* sktb, const float* g1,
    const float* be1, const float* qkv_b, u16* qc, u16* kc, u16* vtc) {
  __shared__ __align__(16) u16 cv[32 * 264];
  __shared__ __align__(16) u16 sk[32 * 264];
  int tid = threadIdx.x;
  int lane = tid & 63, wave = tid >> 6;
  int m = lane & 15, gq = lane >> 4, k0 = gq * 8;
  int tok0 = blockIdx.x * 32;
  // gather conv + skip rows (zero for pad/phantom tokens)
#pragma unroll
  for (int it = 0; it < 4; it++) {
    int flat = it * 2048 + tid * 8;
    int row = flat >> 8, col = flat & 255;
    int g = tok0 + row;
    int w_ = g / 49, i = g - w_ * 49;
    int wrow = w_ / 14, wcol = w_ - wrow * 14;
    int hh = wrow * 7 + i / 7, ww = wcol * 7 + i % 7;
    bool valid = (g < 9604) && (hh < 96) && (ww < 96);
    short8 vc = {}, vs = {};
    if (valid) {
      size_t base = ((size_t)hh * 96 + ww) * 256 + col;
      vc = ld8(scb + base);
      vs = ld8(sktb + base);
    }
    *reinterpret_cast<short8*>(&cv[row * 264 + col]) = vc;
    *reinterpret_cast<short8*>(&sk[row * 264 + col]) = vs;
  }
  __syncthreads();
  // skip 1x1 GEMM (K=256), each wave owns 64 output cols
  f32x4 acc[2][4] = {};
#pragma unroll 4
  for (int ks = 0; ks < 8; ks++) {
    short8 a0 = ld8(&sk[m * 264 + ks * 32 + k0]);
    short8 a1 = ld8(&sk[(16 + m) * 264 + ks * 32 + k0]);
#pragma unroll
    for (int nt = 0; nt < 4; nt++) {
      short8 bb = ld8(W + WSKIP + (size_t)(wave * 64 + nt * 16 + m) * 256 + ks * 32 + k0);
      acc[0][nt] = mfma16(a0, bb, acc[0][nt]);
      acc[1][nt] = mfma16(a1, bb, acc[1][nt]);
    }
  }
  __syncthreads();  // all reads of sk complete
  // y = conv + skipterm -> overwrite sk
#pragma unroll
  for (int mt = 0; mt < 2; mt++)
#pragma unroll
    for (int nt = 0; nt < 4; nt++) {
      int c = wave * 64 + nt * 16 + m;
#pragma unroll
      for (int rr = 0; rr < 4; rr++) {
        int row = mt * 16 + gq * 4 + rr;
        float y = acc[mt][nt][rr] + b2f(cv[row * 264 + c]);
        sk[row * 264 + c] = f2b(y);
      }
    }
  __syncthreads();
  // LN1 on valid rows (pad rows stay zero)
  f32x4 gg = *(const f32x4*)&g1[lane * 4];
  f32x4 be = *(const f32x4*)&be1[lane * 4];
  for (int tt = 0; tt < 8; tt++) {
    int row = wave * 8 + tt;
    int g = tok0 + row;
    int w_ = g / 49, i = g - w_ * 49;
    int wrow = w_ / 14, wcol = w_ - wrow * 14;
    int hh = wrow * 7 + i / 7, ww = wcol * 7 + i % 7;
    if (!((g < 9604) && (hh < 96) && (ww < 96))) continue;
    u16x4 raw = *(const u16x4*)&sk[row * 264 + lane * 4];
    f32x4 v;
#pragma unroll
    for (int q2 = 0; q2 < 4; q2++) v[q2] = b2f(raw[q2]);
    float s1 = wredsum(v[0] + v[1] + v[2] + v[3]);
    float mean = s1 * 0.00390625f;
    f32x4 dv; float sq = 0.f;
#pragma unroll
    for (int q2 = 0; q2 < 4; q2++) { dv[q2] = v[q2] - mean; sq += dv[q2] * dv[q2]; }
    float s2 = wredsum(sq);
    float rstd = rsqrtf(s2 * 0.00390625f + 1e-6f);
    u16x4 ov;
#pragma unroll
    for (int q2 = 0; q2 < 4; q2++) ov[q2] = f2b(dv[q2] * rstd * gg[q2] + be[q2]);
    *reinterpret_cast<u16x4*>(&sk[row * 264 + lane * 4]) = ov;
  }
  __syncthreads();
  // qkv GEMM: each wave 3 chunks of 64 cols (total 768)
  for (int ch = 0; ch < 3; ch++) {
    int cbase = wave * 192 + ch * 64;
    f32x4 a2[2][4] = {};
#pragma unroll 4
    for (int ks = 0; ks < 8; ks++) {
      short8 a0 = ld8(&sk[m * 264 + ks * 32 + k0]);
      short8 a1 = ld8(&sk[(16 + m) * 264 + ks * 32 + k0]);
#pragma unroll
      for (int nt = 0; nt < 4; nt++) {
        short8 bb = ld8(W + WQKV + (size_t)(cbase + nt * 16 + m) * 256 + ks * 32 + k0);
        a2[0][nt] = mfma16(a0, bb, a2[0][nt]);
        a2[1][nt] = mfma16(a1, bb, a2[1][nt]);
      }
    }
#pragma unroll
    for (int mt = 0; mt < 2; mt++)
#pragma unroll
      for (int nt = 0; nt < 4; nt++) {
        int c = cbase + nt * 16 + m;
        float qb_ = qkv_b[c];
        int type = c >> 8, hh = (c >> 5) & 7, hd = c & 31;
#pragma unroll
        for (int rr = 0; rr < 4; rr++) {
          int g = tok0 + mt * 16 + gq * 4 + rr;
          if (g >= 9604) continue;
          int w_ = g / 49, i = g - w_ * 49;
          float v = a2[mt][nt][rr] + qb_;
          size_t bh = (size_t)w_ * 8 + hh;
          if (type == 0) qc[bh * 1568 + i * 32 + hd] = f2b(v);
          else if (type == 1) kc[bh * 1568 + i * 32 + hd] = f2b(v);
          else vtc[bh * 2048 + hd * 64 + i] = f2b(v);
        }
      }
  }
}

// ============== K3: window attention, one wave per (window, head) =============
__global__ __launch_bounds__(256) void k3_attn(
    const u16* qc, const u16* kc, const u16* vtc, const float* bias_g, u16* obb) {
  __shared__ u16 plds[4][64 * 64];
  int lane = threadIdx.x & 63, wave = threadIdx.x >> 6;
  int b_ = blockIdx.x >> 1;
  int h = (blockIdx.x & 1) * 4 + wave;
  int m = lane & 15, gq = lane >> 4, k0 = gq * 8;
  size_t bh = (size_t)b_ * 8 + h;
  const u16* Q = qc + bh * 1568;
  const u16* K = kc + bh * 1568;
  const u16* V = vtc + bh * 2048;
  const float* BI = bias_g + h * 4096;
  short8 aq[4], bk[4];
#pragma unroll
  for (int mt = 0; mt < 4; mt++) { int i = mt * 16 + m; if (i > 48) i = 48; aq[mt] = ld8(Q + i * 32 + k0); }
#pragma unroll
  for (int nt = 0; nt < 4; nt++) { int j = nt * 16 + m; if (j > 48) j = 48; bk[nt] = ld8(K + j * 32 + k0); }
  f32x4 s[4][4] = {};
#pragma unroll
  for (int mt = 0; mt < 4; mt++)
#pragma unroll
    for (int nt = 0; nt < 4; nt++)
      s[mt][nt] = mfma16(aq[mt], bk[nt], s[mt][nt]);
  const float scale = 0.1767766952966369f;  // 1/sqrt(32)
  float rsum[4][4];
#pragma unroll
  for (int mt = 0; mt < 4; mt++)
#pragma unroll
    for (int rr = 0; rr < 4; rr++) {
      int i = mt * 16 + gq * 4 + rr;
      float sv[4];
      float mx = -1e38f;
#pragma unroll
      for (int nt = 0; nt < 4; nt++) {
        sv[nt] = s[mt][nt][rr] * scale + BI[i * 64 + nt * 16 + m];
        mx = fmaxf(mx, sv[nt]);
      }
      mx = fmaxf(mx, __shfl_xor(mx, 1));
      mx = fmaxf(mx, __shfl_xor(mx, 2));
      mx = fmaxf(mx, __shfl_xor(mx, 4));
      mx = fmaxf(mx, __shfl_xor(mx, 8));
      float sum = 0.f;
#pragma unroll
      for (int nt = 0; nt < 4; nt++) { sv[nt] = __expf(sv[nt] - mx); sum += sv[nt]; }
      sum += __shfl_xor(sum, 1);
      sum += __shfl_xor(sum, 2);
      sum += __shfl_xor(sum, 4);
      sum += __shfl_xor(sum, 8);
      rsum[mt][rr] = sum;
      int isw = (i & 7) * 8;
#pragma unroll
      for (int nt = 0; nt < 4; nt++) {
        int j = nt * 16 + m;
        plds[wave][i * 64 + (j ^ isw)] = f2b(sv[nt]);
      }
    }
  __syncthreads();
  f32x4 o[4][2] = {};
#pragma unroll
  for (int ks = 0; ks < 2; ks++) {
    short8 bv[2];
#pragma unroll
    for (int nt = 0; nt < 2; nt++)
      bv[nt] = ld8(V + (size_t)(nt * 16 + m) * 64 + ks * 32 + k0);
#pragma unroll
    for (int mt = 0; mt < 4; mt++) {
      int i = mt * 16 + m;
      short8 ap = *reinterpret_cast<const short8*>(
          &plds[wave][i * 64 + ((ks * 32 + k0) ^ ((i & 7) * 8))]);
#pragma unroll
      for (int nt = 0; nt < 2; nt++)
        o[mt][nt] = mfma16(ap, bv[nt], o[mt][nt]);
    }
  }
#pragma unroll
  for (int mt = 0; mt < 4; mt++)
#pragma unroll
    for (int rr = 0; rr < 4; rr++) {
      int i = mt * 16 + gq * 4 + rr;
      if (i >= 49) continue;
      float rinv = 1.f / rsum[mt][rr];
#pragma unroll
      for (int nt = 0; nt < 2; nt++) {
        int c = h * 32 + nt * 16 + m;
        obb[((size_t)b_ * 49 + i) * 256 + c] = f2b(o[mt][nt][rr] * rinv);
      }
    }
}

// ============== K4: proj + shortcut -> x2 (per image, in-place over sc) =======
__global__ __launch_bounds__(256) void k4_proj(
    const u16* W, const u16* obs, const float* proj_b, u16* scb) {
  int lane = threadIdx.x & 63, wave = threadIdx.x >> 6;
  int m = lane & 15, gq = lane >> 4, k0 = gq * 8;
  int g0 = blockIdx.x * 16;
  int row = g0 + m; if (row > 9603) row = 9603;
  const u16* A = obs + (size_t)row * 256;
  f32x4 acc[4] = {};
#pragma unroll 4
  for (int ks = 0; ks < 8; ks++) {
    short8 a = ld8(A + ks * 32 + k0);
#pragma unroll
    for (int nt = 0; nt < 4; nt++) {
      short8 bb = ld8(W + WPROJ + (size_t)(wave * 64 + nt * 16 + m) * 256 + ks * 32 + k0);
      acc[nt] = mfma16(a, bb, acc[nt]);
    }
  }
#pragma unroll
  for (int rr = 0; rr < 4; rr++) {
    int g = g0 + gq * 4 + rr;
    if (g >= 9604) continue;
    int w_ = g / 49, i = g - w_ * 49;
    int wrow = w_ / 14, wcol = w_ - wrow * 14;
    int hh = wrow * 7 + i / 7, ww = wcol * 7 + i % 7;
    if (hh >= 96 || ww >= 96) continue;
    size_t tok = (size_t)hh * 96 + ww;
#pragma unroll
    for (int nt = 0; nt < 4; nt++) {
      int c = wave * 64 + nt * 16 + m;
      float v = acc[nt][rr] + proj_b[c] + b2f(scb[tok * 256 + c]);
      scb[tok * 256 + c] = f2b(v);
    }
  }
}

// ============== K5: LN2 + mlp1 + exact GELU ==================================
__global__ __launch_bounds__(256) void k5_mlp1(
    const u16* W, const u16* x2b, const float* g2, const float* be2,
    const float* mb1, u16* h1q) {
  __shared__ __align__(16) u16 xl[32 * 264];
  int tid = threadIdx.x;
  int lane = tid & 63, wave = tid >> 6;
  int m = lane & 15, gq = lane >> 4, k0 = gq * 8;
  int tok0 = blockIdx.x * 32;
#pragma unroll
  for (int it = 0; it < 4; it++) {
    int flat = it * 2048 + tid * 8;
    int row = flat >> 8, col = flat & 255;
    *reinterpret_cast<short8*>(&xl[row * 264 + col]) =
        ld8(x2b + (size_t)(tok0 + row) * 256 + col);
  }
  __syncthreads();
  f32x4 gg = *(const f32x4*)&g2[lane * 4];
  f32x4 be = *(const f32x4*)&be2[lane * 4];
  for (int tt = 0; tt < 8; tt++) {
    int row = wave * 8 + tt;
    u16x4 raw = *(const u16x4*)&xl[row * 264 + lane * 4];
    f32x4 v;
#pragma unroll
    for (int q2 = 0; q2 < 4; q2++) v[q2] = b2f(raw[q2]);
    float s1 = wredsum(v[0] + v[1] + v[2] + v[3]);
    float mean = s1 * 0.00390625f;
    f32x4 dv; float sq = 0.f;
#pragma unroll
    for (int q2 = 0; q2 < 4; q2++) { dv[q2] = v[q2] - mean; sq += dv[q2] * dv[q2]; }
    float s2 = wredsum(sq);
    float rstd = rsqrtf(s2 * 0.00390625f + 1e-6f);
    u16x4 ov;
#pragma unroll
    for (int q2 = 0; q2 < 4; q2++) ov[q2] = f2b(dv[q2] * rstd * gg[q2] + be[q2]);
    *reinterpret_cast<u16x4*>(&xl[row * 264 + lane * 4]) = ov;
  }
  __syncthreads();
  int cbase = blockIdx.y * 256 + wave * 64;
  f32x4 acc[2][4] = {};
#pragma unroll 4
  for (int ks = 0; ks < 8; ks++) {
    short8 a0 = ld8(&xl[m * 264 + ks * 32 + k0]);
    short8 a1 = ld8(&xl[(16 + m) * 264 + ks * 32 + k0]);
#pragma unroll
    for (int nt = 0; nt < 4; nt++) {
      short8 bb = ld8(W + WM1 + (size_t)(cbase + nt * 16 + m) * 256 + ks * 32 + k0);
      acc[0][nt] = mfma16(a0, bb, acc[0][nt]);
      acc[1][nt] = mfma16(a1, bb, acc[1][nt]);
    }
  }
#pragma unroll
  for (int mt = 0; mt < 2; mt++)
#pragma unroll
    for (int nt = 0; nt < 4; nt++) {
      int c = cbase + nt * 16 + m;
      float bias = mb1[c];
#pragma unroll
      for (int rr = 0; rr < 4; rr++) {
        int tok = tok0 + mt * 16 + gq * 4 + rr;
        float v = acc[mt][nt][rr] + bias;
        v = 0.5f * v * (1.f + erff(v * 0.7071067811865475f));
        h1q[(size_t)tok * 1024 + c] = f2b(v);
      }
    }
}

// ============== K6: mlp2 + residual + NCHW transpose-out ======================
__global__ __launch_bounds__(256) void k6_mlp2(
    const u16* W, const u16* h1q, const float* mb2, const u16* x2b,
    float* out, int tok_base) {
  __shared__ float ot[4][64 * 33];
  int lane = threadIdx.x & 63, wave = threadIdx.x >> 6;
  int m = lane & 15, gq = lane >> 4, k0 = gq * 8;
  int tok0 = blockIdx.x * 32;
  const u16* A = h1q + (size_t)tok0 * 1024;
  f32x4 acc[2][4] = {};
#pragma unroll 4
  for (int ks = 0; ks < 32; ks++) {
    short8 a0 = ld8(A + (size_t)m * 1024 + ks * 32 + k0);
    short8 a1 = ld8(A + (size_t)(16 + m) * 1024 + ks * 32 + k0);
#pragma unroll
    for (int nt = 0; nt < 4; nt++) {
      short8 bb = ld8(W + WM2 + (size_t)(wave * 64 + nt * 16 + m) * 1024 + ks * 32 + k0);
      acc[0][nt] = mfma16(a0, bb, acc[0][nt]);
      acc[1][nt] = mfma16(a1, bb, acc[1][nt]);
    }
  }
#pragma unroll
  for (int mt = 0; mt < 2; mt++)
#pragma unroll
    for (int nt = 0; nt < 4; nt++) {
      int cl = nt * 16 + m;
      int c = wave * 64 + cl;
      float bias = mb2[c];
#pragma unroll
      for (int rr = 0; rr < 4; rr++) {
        int t = mt * 16 + gq * 4 + rr;
        float v = acc[mt][nt][rr] + bias + b2f(x2b[(size_t)(tok0 + t) * 256 + c]);
        ot[wave][cl * 33 + t] = v;
      }
    }
  __syncthreads();
  int tg = tok_base + tok0;
  int bimg = tg / 9216, hw0 = tg % 9216;
  int clh = lane >> 5, t = lane & 31;
#pragma unroll 8
  for (int j = 0; j < 32; j++) {
    int cl = j * 2 + clh;
    float v = ot[wave][cl * 33 + t];
    out[((size_t)bimg * 256 + wave * 64 + cl) * 9216 + hw0 + t] = v;
  }
}

extern "C" void kernel_launch(void* const* d_in, const int* in_sizes, int n_in,
                              void* d_out, int out_size, void* d_ws, size_t ws_size,
                              hipStream_t stream) {
  const float* x      = (const float*)d_in[0];
  const float* skipf  = (const float*)d_in[1];
  const float* up_w   = (const float*)d_in[2];
  const float* up_b   = (const float*)d_in[3];
  const float* skip_w = (const float*)d_in[4];
  const float* g1     = (const float*)d_in[5];
  const float* be1    = (const float*)d_in[6];
  const float* qkv_w  = (const float*)d_in[7];
  const float* qkv_b  = (const float*)d_in[8];
  const float* rpb    = (const float*)d_in[9];
  const float* proj_w = (const float*)d_in[10];
  const float* proj_b = (const float*)d_in[11];
  const float* g2     = (const float*)d_in[12];
  const float* be2    = (const float*)d_in[13];
  const float* m_w1   = (const float*)d_in[14];
  const float* m_b1   = (const float*)d_in[15];
  const float* m_w2   = (const float*)d_in[16];
  const float* m_b2   = (const float*)d_in[17];
  if (ws_size < WS_NEED) {
    k_sentinel<<<1, 256, 0, stream>>>((float*)d_out);
    return;
  }
  char* ws = (char*)d_ws;
  u16*   W    = (u16*)ws;
  float* bias = (float*)(ws + OFF_BIAS);
  u16*   sc   = (u16*)(ws + OFF_SC);
  u16*   xt   = (u16*)(ws + OFF_OVR);
  u16*   qc   = (u16*)(ws + OFF_OVR);
  u16*   kc   = (u16*)(ws + OFF_OVR + 4917248u);
  u16*   vtc  = (u16*)(ws + OFF_OVR + 9834496u);
  u16*   sktb = (u16*)(ws + OFF_OVR + 16257024u);
  u16*   obs  = (u16*)(ws + OFF_OVR + 20975616u);
  u16*   h1q  = (u16*)(ws + OFF_OVR);

  k_prep<<<5504, 256, 0, stream>>>(qkv_w, proj_w, m_w1, m_w2, skip_w, up_w, rpb, W, bias);
  k_tr<<<dim3(72, 16, 8), 256, 0, stream>>>(x, xt, 512, 2304);
  k1_conv<<<dim3(768, 2), 256, 0, stream>>>(W, xt, up_b, sc);
  for (int b = 0; b < 8; b++) {
    const u16* scb = sc + (size_t)b * 9216 * 256;
    k_tr_skip<<<dim3(3, 8, 96), 256, 0, stream>>>(skipf + (size_t)b * 256 * 9216, sktb);
    k2_qkv<<<301, 256, 0, stream>>>(W, scb, sktb, g1, be1, qkv_b, qc, kc, vtc);
    k3_attn<<<392, 256, 0, stream>>>(qc, kc, vtc, bias, obs);
    k4_proj<<<601, 256, 0, stream>>>(W, obs, proj_b, sc + (size_t)b * 9216 * 256);
  }
  for (int q = 0; q < 4; q++) {
    const u16* x2b = sc + (size_t)q * 18432 * 256;
    k5_mlp1<<<dim3(576, 4), 256, 0, stream>>>(W, x2b, g2, be2, m_b1, h1q);
    k6_mlp2<<<576, 256, 0, stream>>>(W, h1q, m_b2, x2b, (float*)d_out, q * 18432);
  }
}

// Round 5
// 1030.624 us; speedup vs baseline: 1.3287x; 1.2935x over previous
//
#include <hip/hip_runtime.h>

typedef __attribute__((ext_vector_type(8))) short short8;
typedef __attribute__((ext_vector_type(4))) float f32x4;
typedef __attribute__((ext_vector_type(4))) unsigned short u16x4;
typedef unsigned short u16;
typedef unsigned int u32;

#define DEV static __device__ __forceinline__

DEV u16 f2b(float f) {
  u32 u = __builtin_bit_cast(u32, f);
  return (u16)((u + 0x7fffu + ((u >> 16) & 1u)) >> 16);
}
DEV float b2f(u16 h) {
  u32 u = ((u32)h) << 16;
  return __builtin_bit_cast(float, u);
}
DEV short8 ld8(const u16* p) { return *reinterpret_cast<const short8*>(p); }
DEV f32x4 mfma16(short8 a, short8 b, f32x4 c) {
  return __builtin_amdgcn_mfma_f32_16x16x32_bf16(a, b, c, 0, 0, 0);
}
DEV float wredsum(float v) {
#pragma unroll
  for (int off = 1; off < 64; off <<= 1) v += __shfl_xor(v, off);
  return v;
}

// ---- weight arena (u16 element offsets) ----
#define WQKV   0         // [768][256]
#define WPROJ  196608    // [256][256]
#define WM1    262144    // [1024][256]
#define WM2    524288    // [256][1024]
#define WSKIP  786432    // [256][256]
#define WUP    851968    // [4][256][512]  kk = kh*2+kw

// ---- ws byte offsets ----
#define OFF_BIAS 2752512u
#define OFF_SC   2883584u     // bf16 sc: conv shortcut -> x2 [73728][256]
#define OFF_OVR  40632320u    // 55,595,008B overlay:
// phase A: xt @OVR (18,874,368)          [dead after k1]
// phase B: skt @OVR (37,748,736)         [written after k1; dead after k234]
// phase C: h1 @OVR (37,748,736)
#define WS_NEED  96227328u

__global__ void k_sentinel(float* out) { out[threadIdx.x] = 31337.0f; }

// ================= prep: weights -> bf16, up_w transpose, bias table ==========
__global__ __launch_bounds__(256) void k_prep(
    const float* qkv_w, const float* proj_w, const float* mlp_w1,
    const float* mlp_w2, const float* skip_w, const float* up_w,
    const float* rpb, u16* W, float* bias_g) {
  int i = blockIdx.x * 256 + threadIdx.x;
  if (i < 196608) { W[WQKV + i] = f2b(qkv_w[i]); return; }
  i -= 196608;
  if (i < 65536) { W[WPROJ + i] = f2b(proj_w[i]); return; }
  i -= 65536;
  if (i < 262144) { W[WM1 + i] = f2b(mlp_w1[i]); return; }
  i -= 262144;
  if (i < 262144) { W[WM2 + i] = f2b(mlp_w2[i]); return; }
  i -= 262144;
  if (i < 65536) { W[WSKIP + i] = f2b(skip_w[i]); return; }
  i -= 65536;
  if (i < 524288) {
    int ci = i & 511; int rest = i >> 9; int co = rest & 255; int kk = rest >> 8;
    W[WUP + i] = f2b(up_w[ci * 1024 + co * 4 + kk]);
    return;
  }
  i -= 524288;
  if (i < 32768) {
    int h = i >> 12, r = i & 4095, ii = r >> 6, j = r & 63;
    float v;
    if (j >= 49) v = -1e30f;
    else if (ii >= 49) v = 0.f;
    else {
      int d0 = (ii / 7 - j / 7) + 6, d1 = (ii % 7 - j % 7) + 6;
      v = rpb[(d0 * 13 + d1) * 8 + h];
    }
    bias_g[i] = v;
  }
}

// ============== NCHW f32 -> NHWC bf16 tiled transpose (for x) =================
__global__ __launch_bounds__(256) void k_tr(const float* src, u16* dst, int C, int HW) {
  __shared__ float t[32][33];
  int hw0 = blockIdx.x * 32, c0 = blockIdx.y * 32, b = blockIdx.z;
  int tx = threadIdx.x & 31, ty = threadIdx.x >> 5;
  const float* s = src + (size_t)b * C * HW;
  u16* d = dst + (size_t)b * C * HW;
#pragma unroll
  for (int i = 0; i < 4; i++)
    t[ty + i * 8][tx] = s[(size_t)(c0 + ty + i * 8) * HW + hw0 + tx];
  __syncthreads();
#pragma unroll
  for (int i = 0; i < 4; i++)
    d[(size_t)(hw0 + ty + i * 8) * C + c0 + tx] = f2b(t[tx][ty + i * 8]);
}

// ===== batched skip transpose: skip[b][c][h][w] -> skt[b][h][w][c] (bf16) =====
__global__ __launch_bounds__(256) void k_tr_skip(const float* src, u16* dst) {
  __shared__ float t[32][33];
  int w0 = blockIdx.x * 32, c0 = blockIdx.y * 32;
  int z = blockIdx.z;
  int b = z / 96, h = z - b * 96;
  int tx = threadIdx.x & 31, ty = threadIdx.x >> 5;
  const float* s = src + (size_t)b * 256 * 9216 + (size_t)h * 96;
  u16* d = dst + (((size_t)b * 96 + h) * 96) * 256;
#pragma unroll
  for (int i = 0; i < 4; i++)
    t[ty + i * 8][tx] = s[(size_t)(c0 + ty + i * 8) * 9216 + w0 + tx];
  __syncthreads();
#pragma unroll
  for (int i = 0; i < 4; i++)
    d[(size_t)(w0 + ty + i * 8) * 256 + c0 + tx] = f2b(t[tx][ty + i * 8]);
}

// ============== K1: convT only -> sc (conv-only shortcut) =====================
__global__ __launch_bounds__(256) void k1_conv(
    const u16* W, const u16* xt, const float* up_b, u16* sc) {
  int blk = blockIdx.x;
  int par = blockIdx.y;
  int b = blk / 96, r0 = blk % 96;
  int h2 = r0 >> 1, kw = r0 & 1;
  int h = h2 * 2 + par;
  int lane = threadIdx.x & 63, wave = threadIdx.x >> 6;
  int m = lane & 15, gq = lane >> 4, k0 = gq * 8;
  const u16* A = xt + (((size_t)b * 48 + h2) * 48) * 512;
  const u16* B = W + WUP + (size_t)(par * 2 + kw) * 131072;
  f32x4 acc[3][4] = {};
#pragma unroll 4
  for (int ks = 0; ks < 16; ks++) {
    short8 a[3];
#pragma unroll
    for (int mt = 0; mt < 3; mt++)
      a[mt] = ld8(A + (size_t)(mt * 16 + m) * 512 + ks * 32 + k0);
#pragma unroll
    for (int nt = 0; nt < 4; nt++) {
      short8 bb = ld8(B + (size_t)(wave * 64 + nt * 16 + m) * 512 + ks * 32 + k0);
#pragma unroll
      for (int mt = 0; mt < 3; mt++)
        acc[mt][nt] = mfma16(a[mt], bb, acc[mt][nt]);
    }
  }
  float ub[4];
#pragma unroll
  for (int nt = 0; nt < 4; nt++) ub[nt] = up_b[wave * 64 + nt * 16 + m];
#pragma unroll
  for (int mt = 0; mt < 3; mt++)
#pragma unroll
    for (int nt = 0; nt < 4; nt++)
#pragma unroll
      for (int rr = 0; rr < 4; rr++) {
        int t = mt * 16 + gq * 4 + rr;
        int w = kw + 2 * t;
        int c = wave * 64 + nt * 16 + m;
        sc[(((size_t)b * 96 + h) * 96 + w) * 256 + c] = f2b(acc[mt][nt][rr] + ub[nt]);
      }
}

// ============== K234: skip+LN1+qkv+attn+proj, one block per window ============
// grid 1568. LDS: yl[52][264] shared; pws[wave][6144] private:
//   vt @0 (32x64), q @2048 (49x32), k @3616 (49x32), P @2048 (64x64, over q/k)
__global__ __launch_bounds__(256) void k234(
    const u16* W, u16* sc, const u16* skt, const float* g1, const float* be1,
    const float* qkv_b, const float* bias_g, const float* proj_b) {
  __shared__ __align__(16) u16 yl[52 * 264];
  __shared__ __align__(16) u16 pws[4][6144];
  int tid = threadIdx.x;
  int lane = tid & 63, wave = tid >> 6;
  int m = lane & 15, gq = lane >> 4, k0 = gq * 8;
  int blk = blockIdx.x;
  int bimg = blk / 196, w_ = blk - bimg * 196;
  int wrow = w_ / 14, wcol = w_ - wrow * 14;
  int h0 = wrow * 7, w0 = wcol * 7;
  u16* scb = sc + (size_t)bimg * 9216 * 256;
  const u16* skb = skt + (size_t)bimg * 9216 * 256;
  u16* prv = pws[wave];
  // zero vt region once (cols j>=49 are never written, must not be Inf/NaN)
#pragma unroll
  for (int t = 0; t < 8; t++) {
    u16x4 z = {};
    *reinterpret_cast<u16x4*>(&prv[t * 256 + lane * 4]) = z;
  }
  // stage skip rows -> yl (phantom rows = 0)
  for (int it = 0; it < 7; it++) {
    int flat = it * 2048 + tid * 8;
    if (flat < 12544) {
      int row = flat >> 8, col = flat & 255;
      int hh = h0 + row / 7, ww = w0 + row % 7;
      short8 v = {};
      if (hh < 96 && ww < 96) v = ld8(skb + ((size_t)hh * 96 + ww) * 256 + col);
      *reinterpret_cast<short8*>(&yl[row * 264 + col]) = v;
    }
  }
  __syncthreads();
  // skip 1x1 GEMM (K=256), wave owns 64 cols
  int cb = wave * 64;
  {
    f32x4 acc[4][4] = {};
#pragma unroll 2
    for (int ks = 0; ks < 8; ks++) {
      short8 a[4];
#pragma unroll
      for (int mt = 0; mt < 4; mt++) {
        int row = mt * 16 + m; if (row > 48) row = 48;
        a[mt] = ld8(&yl[row * 264 + ks * 32 + k0]);
      }
#pragma unroll
      for (int nt = 0; nt < 4; nt++) {
        short8 bb = ld8(W + WSKIP + (size_t)(cb + nt * 16 + m) * 256 + ks * 32 + k0);
#pragma unroll
        for (int mt = 0; mt < 4; mt++)
          acc[mt][nt] = mfma16(a[mt], bb, acc[mt][nt]);
      }
    }
    __syncthreads();
    // y = skipterm + conv(shortcut) -> yl
#pragma unroll
    for (int mt = 0; mt < 4; mt++)
#pragma unroll
      for (int rr = 0; rr < 4; rr++) {
        int row = mt * 16 + gq * 4 + rr;
        if (row >= 49) continue;
        int hh = h0 + row / 7, ww = w0 + row % 7;
        bool valid = (hh < 96 && ww < 96);
        size_t tok = (size_t)hh * 96 + ww;
#pragma unroll
        for (int nt = 0; nt < 4; nt++) {
          int c = cb + nt * 16 + m;
          float y = acc[mt][nt][rr];
          if (valid) y += b2f(scb[tok * 256 + c]);
          yl[row * 264 + c] = f2b(y);
        }
      }
  }
  __syncthreads();
  // LN1 (valid rows only; phantom rows stay exactly 0)
  {
    f32x4 gg = *(const f32x4*)&g1[lane * 4];
    f32x4 be = *(const f32x4*)&be1[lane * 4];
    for (int tt = 0; tt < 13; tt++) {
      int row = tt * 4 + wave;
      if (row >= 49) break;
      int hh = h0 + row / 7, ww = w0 + row % 7;
      if (hh >= 96 || ww >= 96) continue;
      u16x4 raw = *(const u16x4*)&yl[row * 264 + lane * 4];
      f32x4 v;
#pragma unroll
      for (int q2 = 0; q2 < 4; q2++) v[q2] = b2f(raw[q2]);
      float s1 = wredsum(v[0] + v[1] + v[2] + v[3]);
      float mean = s1 * 0.00390625f;
      f32x4 dv; float sq = 0.f;
#pragma unroll
      for (int q2 = 0; q2 < 4; q2++) { dv[q2] = v[q2] - mean; sq += dv[q2] * dv[q2]; }
      float s2 = wredsum(sq);
      float rstd = rsqrtf(s2 * 0.00390625f + 1e-6f);
      u16x4 ov;
#pragma unroll
      for (int q2 = 0; q2 < 4; q2++) ov[q2] = f2b(dv[q2] * rstd * gg[q2] + be[q2]);
      *reinterpret_cast<u16x4*>(&yl[row * 264 + lane * 4]) = ov;
    }
  }
  __syncthreads();
  // per-head-pair: qkv -> attention (o kept in registers)
  f32x4 oh[2][4][2];
  const float scale = 0.1767766952966369f;  // 1/sqrt(32)
#pragma unroll
  for (int hp = 0; hp < 2; hp++) {
    int h = wave * 2 + hp;
    // qkv GEMM: N=96 (q,k,v x 32) for head h
    {
      f32x4 acc[4][6] = {};
#pragma unroll 2
      for (int ks = 0; ks < 8; ks++) {
        short8 a[4];
#pragma unroll
        for (int mt = 0; mt < 4; mt++) {
          int row = mt * 16 + m; if (row > 48) row = 48;
          a[mt] = ld8(&yl[row * 264 + ks * 32 + k0]);
        }
#pragma unroll
        for (int nt = 0; nt < 6; nt++) {
          int brow = (nt >> 1) * 256 + h * 32 + (nt & 1) * 16 + m;
          short8 bb = ld8(W + WQKV + (size_t)brow * 256 + ks * 32 + k0);
#pragma unroll
          for (int mt = 0; mt < 4; mt++)
            acc[mt][nt] = mfma16(a[mt], bb, acc[mt][nt]);
        }
      }
      // store q/k/vt to private LDS (+bias); rows < 49 only
#pragma unroll
      for (int nt = 0; nt < 6; nt++) {
        int hd = (nt & 1) * 16 + m;
        int c = (nt >> 1) * 256 + h * 32 + hd;
        float qb_ = qkv_b[c];
#pragma unroll
        for (int mt = 0; mt < 4; mt++)
#pragma unroll
          for (int rr = 0; rr < 4; rr++) {
            int row = mt * 16 + gq * 4 + rr;
            if (row >= 49) continue;
            u16 val = f2b(acc[mt][nt][rr] + qb_);
            if ((nt >> 1) == 0) prv[2048 + row * 32 + hd] = val;
            else if ((nt >> 1) == 1) prv[3616 + row * 32 + hd] = val;
            else prv[hd * 64 + row] = val;
          }
      }
    }
    __syncthreads();
    // QK^T
    short8 aq[4], bk[4];
#pragma unroll
    for (int mt = 0; mt < 4; mt++) { int i = mt * 16 + m; if (i > 48) i = 48; aq[mt] = ld8(&prv[2048 + i * 32 + k0]); }
#pragma unroll
    for (int nt = 0; nt < 4; nt++) { int j = nt * 16 + m; if (j > 48) j = 48; bk[nt] = ld8(&prv[3616 + j * 32 + k0]); }
    f32x4 s[4][4] = {};
#pragma unroll
    for (int mt = 0; mt < 4; mt++)
#pragma unroll
      for (int nt = 0; nt < 4; nt++)
        s[mt][nt] = mfma16(aq[mt], bk[nt], s[mt][nt]);
    const float* BI = bias_g + h * 4096;
    float rsum[4][4];
#pragma unroll
    for (int mt = 0; mt < 4; mt++)
#pragma unroll
      for (int rr = 0; rr < 4; rr++) {
        int i = mt * 16 + gq * 4 + rr;
        float sv[4];
        float mx = -1e38f;
#pragma unroll
        for (int nt = 0; nt < 4; nt++) {
          sv[nt] = s[mt][nt][rr] * scale + BI[i * 64 + nt * 16 + m];
          mx = fmaxf(mx, sv[nt]);
        }
        mx = fmaxf(mx, __shfl_xor(mx, 1));
        mx = fmaxf(mx, __shfl_xor(mx, 2));
        mx = fmaxf(mx, __shfl_xor(mx, 4));
        mx = fmaxf(mx, __shfl_xor(mx, 8));
        float sum = 0.f;
#pragma unroll
        for (int nt = 0; nt < 4; nt++) { sv[nt] = __expf(sv[nt] - mx); sum += sv[nt]; }
        sum += __shfl_xor(sum, 1);
        sum += __shfl_xor(sum, 2);
        sum += __shfl_xor(sum, 4);
        sum += __shfl_xor(sum, 8);
        rsum[mt][rr] = sum;
        int isw = (i & 7) * 8;
#pragma unroll
        for (int nt = 0; nt < 4; nt++) {
          int j = nt * 16 + m;
          prv[2048 + i * 64 + (j ^ isw)] = f2b(sv[nt]);
        }
      }
    __syncthreads();
    // PV
    f32x4 o[4][2] = {};
#pragma unroll
    for (int ks = 0; ks < 2; ks++) {
      short8 bv[2];
#pragma unroll
      for (int nt = 0; nt < 2; nt++)
        bv[nt] = ld8(&prv[(nt * 16 + m) * 64 + ks * 32 + k0]);
#pragma unroll
      for (int mt = 0; mt < 4; mt++) {
        int i = mt * 16 + m;
        short8 ap = *reinterpret_cast<const short8*>(
            &prv[2048 + i * 64 + ((ks * 32 + k0) ^ ((i & 7) * 8))]);
#pragma unroll
        for (int nt = 0; nt < 2; nt++)
          o[mt][nt] = mfma16(ap, bv[nt], o[mt][nt]);
      }
    }
#pragma unroll
    for (int mt = 0; mt < 4; mt++)
#pragma unroll
      for (int rr = 0; rr < 4; rr++) {
        float rinv = 1.f / rsum[mt][rr];
#pragma unroll
        for (int nt = 0; nt < 2; nt++)
          oh[hp][mt][nt][rr] = o[mt][nt][rr] * rinv;
      }
    __syncthreads();
  }
  // write o (both heads) into yl (qkv reads done for all waves)
#pragma unroll
  for (int hp = 0; hp < 2; hp++)
#pragma unroll
    for (int mt = 0; mt < 4; mt++)
#pragma unroll
      for (int rr = 0; rr < 4; rr++) {
        int row = mt * 16 + gq * 4 + rr;
        if (row >= 49) continue;
#pragma unroll
        for (int nt = 0; nt < 2; nt++) {
          int col = wave * 64 + hp * 32 + nt * 16 + m;
          yl[row * 264 + col] = f2b(oh[hp][mt][nt][rr]);
        }
      }
  __syncthreads();
  // proj GEMM + shortcut -> x2 in-place over sc
  {
    f32x4 acc[4][4] = {};
#pragma unroll 2
    for (int ks = 0; ks < 8; ks++) {
      short8 a[4];
#pragma unroll
      for (int mt = 0; mt < 4; mt++) {
        int row = mt * 16 + m; if (row > 48) row = 48;
        a[mt] = ld8(&yl[row * 264 + ks * 32 + k0]);
      }
#pragma unroll
      for (int nt = 0; nt < 4; nt++) {
        short8 bb = ld8(W + WPROJ + (size_t)(cb + nt * 16 + m) * 256 + ks * 32 + k0);
#pragma unroll
        for (int mt = 0; mt < 4; mt++)
          acc[mt][nt] = mfma16(a[mt], bb, acc[mt][nt]);
      }
    }
#pragma unroll
    for (int mt = 0; mt < 4; mt++)
#pragma unroll
      for (int rr = 0; rr < 4; rr++) {
        int row = mt * 16 + gq * 4 + rr;
        if (row >= 49) continue;
        int hh = h0 + row / 7, ww = w0 + row % 7;
        if (hh >= 96 || ww >= 96) continue;
        size_t tok = (size_t)hh * 96 + ww;
#pragma unroll
        for (int nt = 0; nt < 4; nt++) {
          int c = cb + nt * 16 + m;
          float v = acc[mt][nt][rr] + proj_b[c] + b2f(scb[tok * 256 + c]);
          scb[tok * 256 + c] = f2b(v);
        }
      }
  }
}

// ============== K5: LN2 + mlp1 + exact GELU ==================================
__global__ __launch_bounds__(256) void k5_mlp1(
    const u16* W, const u16* x2b, const float* g2, const float* be2,
    const float* mb1, u16* h1q) {
  __shared__ __align__(16) u16 xl[32 * 264];
  int tid = threadIdx.x;
  int lane = tid & 63, wave = tid >> 6;
  int m = lane & 15, gq = lane >> 4, k0 = gq * 8;
  int tok0 = blockIdx.x * 32;
#pragma unroll
  for (int it = 0; it < 4; it++) {
    int flat = it * 2048 + tid * 8;
    int row = flat >> 8, col = flat & 255;
    *reinterpret_cast<short8*>(&xl[row * 264 + col]) =
        ld8(x2b + (size_t)(tok0 + row) * 256 + col);
  }
  __syncthreads();
  f32x4 gg = *(const f32x4*)&g2[lane * 4];
  f32x4 be = *(const f32x4*)&be2[lane * 4];
  for (int tt = 0; tt < 8; tt++) {
    int row = wave * 8 + tt;
    u16x4 raw = *(const u16x4*)&xl[row * 264 + lane * 4];
    f32x4 v;
#pragma unroll
    for (int q2 = 0; q2 < 4; q2++) v[q2] = b2f(raw[q2]);
    float s1 = wredsum(v[0] + v[1] + v[2] + v[3]);
    float mean = s1 * 0.00390625f;
    f32x4 dv; float sq = 0.f;
#pragma unroll
    for (int q2 = 0; q2 < 4; q2++) { dv[q2] = v[q2] - mean; sq += dv[q2] * dv[q2]; }
    float s2 = wredsum(sq);
    float rstd = rsqrtf(s2 * 0.00390625f + 1e-6f);
    u16x4 ov;
#pragma unroll
    for (int q2 = 0; q2 < 4; q2++) ov[q2] = f2b(dv[q2] * rstd * gg[q2] + be[q2]);
    *reinterpret_cast<u16x4*>(&xl[row * 264 + lane * 4]) = ov;
  }
  __syncthreads();
  int cbase = blockIdx.y * 256 + wave * 64;
  f32x4 acc[2][4] = {};
#pragma unroll 4
  for (int ks = 0; ks < 8; ks++) {
    short8 a0 = ld8(&xl[m * 264 + ks * 32 + k0]);
    short8 a1 = ld8(&xl[(16 + m) * 264 + ks * 32 + k0]);
#pragma unroll
    for (int nt = 0; nt < 4; nt++) {
      short8 bb = ld8(W + WM1 + (size_t)(cbase + nt * 16 + m) * 256 + ks * 32 + k0);
      acc[0][nt] = mfma16(a0, bb, acc[0][nt]);
      acc[1][nt] = mfma16(a1, bb, acc[1][nt]);
    }
  }
#pragma unroll
  for (int mt = 0; mt < 2; mt++)
#pragma unroll
    for (int nt = 0; nt < 4; nt++) {
      int c = cbase + nt * 16 + m;
      float bias = mb1[c];
#pragma unroll
      for (int rr = 0; rr < 4; rr++) {
        int tok = tok0 + mt * 16 + gq * 4 + rr;
        float v = acc[mt][nt][rr] + bias;
        v = 0.5f * v * (1.f + erff(v * 0.7071067811865475f));
        h1q[(size_t)tok * 1024 + c] = f2b(v);
      }
    }
}

// ============== K6: mlp2 + residual + NCHW transpose-out ======================
__global__ __launch_bounds__(256) void k6_mlp2(
    const u16* W, const u16* h1q, const float* mb2, const u16* x2b,
    float* out, int tok_base) {
  __shared__ float ot[4][64 * 33];
  int lane = threadIdx.x & 63, wave = threadIdx.x >> 6;
  int m = lane & 15, gq = lane >> 4, k0 = gq * 8;
  int tok0 = blockIdx.x * 32;
  const u16* A = h1q + (size_t)tok0 * 1024;
  f32x4 acc[2][4] = {};
#pragma unroll 4
  for (int ks = 0; ks < 32; ks++) {
    short8 a0 = ld8(A + (size_t)m * 1024 + ks * 32 + k0);
    short8 a1 = ld8(A + (size_t)(16 + m) * 1024 + ks * 32 + k0);
#pragma unroll
    for (int nt = 0; nt < 4; nt++) {
      short8 bb = ld8(W + WM2 + (size_t)(wave * 64 + nt * 16 + m) * 1024 + ks * 32 + k0);
      acc[0][nt] = mfma16(a0, bb, acc[0][nt]);
      acc[1][nt] = mfma16(a1, bb, acc[1][nt]);
    }
  }
#pragma unroll
  for (int mt = 0; mt < 2; mt++)
#pragma unroll
    for (int nt = 0; nt < 4; nt++) {
      int cl = nt * 16 + m;
      int c = wave * 64 + cl;
      float bias = mb2[c];
#pragma unroll
      for (int rr = 0; rr < 4; rr++) {
        int t = mt * 16 + gq * 4 + rr;
        float v = acc[mt][nt][rr] + bias + b2f(x2b[(size_t)(tok0 + t) * 256 + c]);
        ot[wave][cl * 33 + t] = v;
      }
    }
  __syncthreads();
  int tg = tok_base + tok0;
  int bimg = tg / 9216, hw0 = tg % 9216;
  int clh = lane >> 5, t = lane & 31;
#pragma unroll 8
  for (int j = 0; j < 32; j++) {
    int cl = j * 2 + clh;
    float v = ot[wave][cl * 33 + t];
    out[((size_t)bimg * 256 + wave * 64 + cl) * 9216 + hw0 + t] = v;
  }
}

extern "C" void kernel_launch(void* const* d_in, const int* in_sizes, int n_in,
                              void* d_out, int out_size, void* d_ws, size_t ws_size,
                              hipStream_t stream) {
  const float* x      = (const float*)d_in[0];
  const float* skipf  = (const float*)d_in[1];
  const float* up_w   = (const float*)d_in[2];
  const float* up_b   = (const float*)d_in[3];
  const float* skip_w = (const float*)d_in[4];
  const float* g1     = (const float*)d_in[5];
  const float* be1    = (const float*)d_in[6];
  const float* qkv_w  = (const float*)d_in[7];
  const float* qkv_b  = (const float*)d_in[8];
  const float* rpb    = (const float*)d_in[9];
  const float* proj_w = (const float*)d_in[10];
  const float* proj_b = (const float*)d_in[11];
  const float* g2     = (const float*)d_in[12];
  const float* be2    = (const float*)d_in[13];
  const float* m_w1   = (const float*)d_in[14];
  const float* m_b1   = (const float*)d_in[15];
  const float* m_w2   = (const float*)d_in[16];
  const float* m_b2   = (const float*)d_in[17];
  if (ws_size < WS_NEED) {
    k_sentinel<<<1, 256, 0, stream>>>((float*)d_out);
    return;
  }
  char* ws = (char*)d_ws;
  u16*   W    = (u16*)ws;
  float* bias = (float*)(ws + OFF_BIAS);
  u16*   sc   = (u16*)(ws + OFF_SC);
  u16*   xt   = (u16*)(ws + OFF_OVR);
  u16*   skt  = (u16*)(ws + OFF_OVR);
  u16*   h1q  = (u16*)(ws + OFF_OVR);

  k_prep<<<5504, 256, 0, stream>>>(qkv_w, proj_w, m_w1, m_w2, skip_w, up_w, rpb, W, bias);
  k_tr<<<dim3(72, 16, 8), 256, 0, stream>>>(x, xt, 512, 2304);
  k1_conv<<<dim3(768, 2), 256, 0, stream>>>(W, xt, up_b, sc);
  k_tr_skip<<<dim3(3, 8, 768), 256, 0, stream>>>(skipf, skt);
  k234<<<1568, 256, 0, stream>>>(W, sc, skt, g1, be1, qkv_b, bias, proj_b);
  for (int q = 0; q < 4; q++) {
    const u16* x2b = sc + (size_t)q * 18432 * 256;
    k5_mlp1<<<dim3(576, 4), 256, 0, stream>>>(W, x2b, g2, be2, m_b1, h1q);
    k6_mlp2<<<576, 256, 0, stream>>>(W, h1q, m_b2, x2b, (float*)d_out, q * 18432);
  }
}

// Round 6
// 827.681 us; speedup vs baseline: 1.6546x; 1.2452x over previous
//
#include <hip/hip_runtime.h>

typedef __attribute__((ext_vector_type(8))) short short8;
typedef __attribute__((ext_vector_type(4))) float f32x4;
typedef __attribute__((ext_vector_type(4))) unsigned short u16x4;
typedef unsigned short u16;
typedef unsigned int u32;

#define DEV static __device__ __forceinline__

DEV u16 f2b(float f) {
  u32 u = __builtin_bit_cast(u32, f);
  return (u16)((u + 0x7fffu + ((u >> 16) & 1u)) >> 16);
}
DEV float b2f(u16 h) {
  u32 u = ((u32)h) << 16;
  return __builtin_bit_cast(float, u);
}
DEV short8 ld8(const u16* p) { return *reinterpret_cast<const short8*>(p); }
DEV f32x4 mfma16(short8 a, short8 b, f32x4 c) {
  return __builtin_amdgcn_mfma_f32_16x16x32_bf16(a, b, c, 0, 0, 0);
}
DEV float wredsum(float v) {
#pragma unroll
  for (int off = 1; off < 64; off <<= 1) v += __shfl_xor(v, off);
  return v;
}

#define GLL(gp, lp) __builtin_amdgcn_global_load_lds( \
    (const __attribute__((address_space(1))) void*)(gp), \
    (__attribute__((address_space(3))) void*)(lp), 16, 0, 0)

// ---- weight arena (u16 element offsets) ----
#define WQKV   0         // [768][256]
#define WPROJ  196608    // [256][256]
#define WM1    262144    // [1024][256]
#define WM2    524288    // [256][1024]
#define WSKIP  786432    // [256][256]
#define WUP    851968    // [4][256][512]  kk = kh*2+kw

// ---- ws byte offsets ----
#define OFF_BIAS 2752512u
#define OFF_SC   2883584u     // bf16 sc: conv shortcut -> x2 [73728][256]
#define OFF_OVR  40632320u    // 55,595,008B overlay:
// phase A: xt @OVR (18,874,368)          [dead after k1]
// phase B: skt @OVR (37,748,736)         [dead after k234]
// phase C (per quarter): ln2q @OVR (9,437,184); h1q @OVR+9437184 (37,748,736)
#define WS_NEED  96227328u

__global__ void k_sentinel(float* out) { out[threadIdx.x] = 31337.0f; }

// ================= prep: weights -> bf16, up_w transpose, bias table ==========
__global__ __launch_bounds__(256) void k_prep(
    const float* qkv_w, const float* proj_w, const float* mlp_w1,
    const float* mlp_w2, const float* skip_w, const float* up_w,
    const float* rpb, u16* W, float* bias_g) {
  int i = blockIdx.x * 256 + threadIdx.x;
  if (i < 196608) { W[WQKV + i] = f2b(qkv_w[i]); return; }
  i -= 196608;
  if (i < 65536) { W[WPROJ + i] = f2b(proj_w[i]); return; }
  i -= 65536;
  if (i < 262144) { W[WM1 + i] = f2b(mlp_w1[i]); return; }
  i -= 262144;
  if (i < 262144) { W[WM2 + i] = f2b(mlp_w2[i]); return; }
  i -= 262144;
  if (i < 65536) { W[WSKIP + i] = f2b(skip_w[i]); return; }
  i -= 65536;
  if (i < 524288) {
    int ci = i & 511; int rest = i >> 9; int co = rest & 255; int kk = rest >> 8;
    W[WUP + i] = f2b(up_w[ci * 1024 + co * 4 + kk]);
    return;
  }
  i -= 524288;
  if (i < 32768) {
    int h = i >> 12, r = i & 4095, ii = r >> 6, j = r & 63;
    float v;
    if (j >= 49) v = -1e30f;
    else if (ii >= 49) v = 0.f;
    else {
      int d0 = (ii / 7 - j / 7) + 6, d1 = (ii % 7 - j % 7) + 6;
      v = rpb[(d0 * 13 + d1) * 8 + h];
    }
    bias_g[i] = v;
  }
}

// ============== NCHW f32 -> NHWC bf16 tiled transpose (for x) =================
__global__ __launch_bounds__(256) void k_tr(const float* src, u16* dst, int C, int HW) {
  __shared__ float t[32][33];
  int hw0 = blockIdx.x * 32, c0 = blockIdx.y * 32, b = blockIdx.z;
  int tx = threadIdx.x & 31, ty = threadIdx.x >> 5;
  const float* s = src + (size_t)b * C * HW;
  u16* d = dst + (size_t)b * C * HW;
#pragma unroll
  for (int i = 0; i < 4; i++)
    t[ty + i * 8][tx] = s[(size_t)(c0 + ty + i * 8) * HW + hw0 + tx];
  __syncthreads();
#pragma unroll
  for (int i = 0; i < 4; i++)
    d[(size_t)(hw0 + ty + i * 8) * C + c0 + tx] = f2b(t[tx][ty + i * 8]);
}

// ===== batched skip transpose: skip[b][c][h][w] -> skt[b][h][w][c] (bf16) =====
__global__ __launch_bounds__(256) void k_tr_skip(const float* src, u16* dst) {
  __shared__ float t[32][33];
  int w0 = blockIdx.x * 32, c0 = blockIdx.y * 32;
  int z = blockIdx.z;
  int b = z / 96, h = z - b * 96;
  int tx = threadIdx.x & 31, ty = threadIdx.x >> 5;
  const float* s = src + (size_t)b * 256 * 9216 + (size_t)h * 96;
  u16* d = dst + (((size_t)b * 96 + h) * 96) * 256;
#pragma unroll
  for (int i = 0; i < 4; i++)
    t[ty + i * 8][tx] = s[(size_t)(c0 + ty + i * 8) * 9216 + w0 + tx];
  __syncthreads();
#pragma unroll
  for (int i = 0; i < 4; i++)
    d[(size_t)(w0 + ty + i * 8) * 256 + c0 + tx] = f2b(t[tx][ty + i * 8]);
}

// ============== K1: convT only -> sc (conv-only shortcut) =====================
__global__ __launch_bounds__(256) void k1_conv(
    const u16* W, const u16* xt, const float* up_b, u16* sc) {
  int blk = blockIdx.x;
  int par = blockIdx.y;
  int b = blk / 96, r0 = blk % 96;
  int h2 = r0 >> 1, kw = r0 & 1;
  int h = h2 * 2 + par;
  int lane = threadIdx.x & 63, wave = threadIdx.x >> 6;
  int m = lane & 15, gq = lane >> 4, k0 = gq * 8;
  const u16* A = xt + (((size_t)b * 48 + h2) * 48) * 512;
  const u16* B = W + WUP + (size_t)(par * 2 + kw) * 131072;
  f32x4 acc[3][4] = {};
#pragma unroll 4
  for (int ks = 0; ks < 16; ks++) {
    short8 a[3];
#pragma unroll
    for (int mt = 0; mt < 3; mt++)
      a[mt] = ld8(A + (size_t)(mt * 16 + m) * 512 + ks * 32 + k0);
#pragma unroll
    for (int nt = 0; nt < 4; nt++) {
      short8 bb = ld8(B + (size_t)(wave * 64 + nt * 16 + m) * 512 + ks * 32 + k0);
#pragma unroll
      for (int mt = 0; mt < 3; mt++)
        acc[mt][nt] = mfma16(a[mt], bb, acc[mt][nt]);
    }
  }
  float ub[4];
#pragma unroll
  for (int nt = 0; nt < 4; nt++) ub[nt] = up_b[wave * 64 + nt * 16 + m];
#pragma unroll
  for (int mt = 0; mt < 3; mt++)
#pragma unroll
    for (int nt = 0; nt < 4; nt++)
#pragma unroll
      for (int rr = 0; rr < 4; rr++) {
        int t = mt * 16 + gq * 4 + rr;
        int w = kw + 2 * t;
        int c = wave * 64 + nt * 16 + m;
        sc[(((size_t)b * 96 + h) * 96 + w) * 256 + c] = f2b(acc[mt][nt][rr] + ub[nt]);
      }
}

// ============== K234: skip+LN1+qkv+attn+proj, one block per window ============
// Barriers only around shared yl; q/k/vt/P are wave-private (lgkmcnt-ordered).
__global__ __launch_bounds__(256) void k234(
    const u16* W, u16* sc, const u16* skt, const float* g1, const float* be1,
    const float* qkv_b, const float* bias_g, const float* proj_b) {
  __shared__ __align__(16) u16 yl[52 * 264];
  __shared__ __align__(16) u16 pws[4][6144];
  int tid = threadIdx.x;
  int lane = tid & 63, wave = tid >> 6;
  int m = lane & 15, gq = lane >> 4, k0 = gq * 8;
  int blk = blockIdx.x;
  int bimg = blk / 196, w_ = blk - bimg * 196;
  int wrow = w_ / 14, wcol = w_ - wrow * 14;
  int h0 = wrow * 7, w0 = wcol * 7;
  u16* scb = sc + (size_t)bimg * 9216 * 256;
  const u16* skb = skt + (size_t)bimg * 9216 * 256;
  u16* prv = pws[wave];
  // zero vt region once (cols j>=49 never written, must be finite)
#pragma unroll
  for (int t = 0; t < 8; t++) {
    u16x4 z = {};
    *reinterpret_cast<u16x4*>(&prv[t * 256 + lane * 4]) = z;
  }
  // stage skip rows -> yl (phantom rows = 0)
  for (int it = 0; it < 7; it++) {
    int flat = it * 2048 + tid * 8;
    if (flat < 12544) {
      int row = flat >> 8, col = flat & 255;
      int hh = h0 + row / 7, ww = w0 + row % 7;
      short8 v = {};
      if (hh < 96 && ww < 96) v = ld8(skb + ((size_t)hh * 96 + ww) * 256 + col);
      *reinterpret_cast<short8*>(&yl[row * 264 + col]) = v;
    }
  }
  __syncthreads();
  // skip 1x1 GEMM (K=256), wave owns 64 cols
  int cb = wave * 64;
  {
    f32x4 acc[4][4] = {};
#pragma unroll 2
    for (int ks = 0; ks < 8; ks++) {
      short8 a[4];
#pragma unroll
      for (int mt = 0; mt < 4; mt++) {
        int row = mt * 16 + m; if (row > 48) row = 48;
        a[mt] = ld8(&yl[row * 264 + ks * 32 + k0]);
      }
#pragma unroll
      for (int nt = 0; nt < 4; nt++) {
        short8 bb = ld8(W + WSKIP + (size_t)(cb + nt * 16 + m) * 256 + ks * 32 + k0);
#pragma unroll
        for (int mt = 0; mt < 4; mt++)
          acc[mt][nt] = mfma16(a[mt], bb, acc[mt][nt]);
      }
    }
    __syncthreads();
    // y = skipterm + conv(shortcut) -> yl
#pragma unroll
    for (int mt = 0; mt < 4; mt++)
#pragma unroll
      for (int rr = 0; rr < 4; rr++) {
        int row = mt * 16 + gq * 4 + rr;
        if (row >= 49) continue;
        int hh = h0 + row / 7, ww = w0 + row % 7;
        bool valid = (hh < 96 && ww < 96);
        size_t tok = (size_t)hh * 96 + ww;
#pragma unroll
        for (int nt = 0; nt < 4; nt++) {
          int c = cb + nt * 16 + m;
          float y = acc[mt][nt][rr];
          if (valid) y += b2f(scb[tok * 256 + c]);
          yl[row * 264 + c] = f2b(y);
        }
      }
  }
  __syncthreads();
  // LN1
  {
    f32x4 gg = *(const f32x4*)&g1[lane * 4];
    f32x4 be = *(const f32x4*)&be1[lane * 4];
    for (int tt = 0; tt < 13; tt++) {
      int row = tt * 4 + wave;
      if (row >= 49) break;
      int hh = h0 + row / 7, ww = w0 + row % 7;
      if (hh >= 96 || ww >= 96) continue;
      u16x4 raw = *(const u16x4*)&yl[row * 264 + lane * 4];
      f32x4 v;
#pragma unroll
      for (int q2 = 0; q2 < 4; q2++) v[q2] = b2f(raw[q2]);
      float s1 = wredsum(v[0] + v[1] + v[2] + v[3]);
      float mean = s1 * 0.00390625f;
      f32x4 dv; float sq = 0.f;
#pragma unroll
      for (int q2 = 0; q2 < 4; q2++) { dv[q2] = v[q2] - mean; sq += dv[q2] * dv[q2]; }
      float s2 = wredsum(sq);
      float rstd = rsqrtf(s2 * 0.00390625f + 1e-6f);
      u16x4 ov;
#pragma unroll
      for (int q2 = 0; q2 < 4; q2++) ov[q2] = f2b(dv[q2] * rstd * gg[q2] + be[q2]);
      *reinterpret_cast<u16x4*>(&yl[row * 264 + lane * 4]) = ov;
    }
  }
  __syncthreads();
  // per-head-pair: qkv -> attention (o in registers); NO block barriers inside
  f32x4 oh[2][4][2];
  const float scale = 0.1767766952966369f;  // 1/sqrt(32)
#pragma unroll
  for (int hp = 0; hp < 2; hp++) {
    int h = wave * 2 + hp;
    {
      f32x4 acc[4][6] = {};
#pragma unroll 2
      for (int ks = 0; ks < 8; ks++) {
        short8 a[4];
#pragma unroll
        for (int mt = 0; mt < 4; mt++) {
          int row = mt * 16 + m; if (row > 48) row = 48;
          a[mt] = ld8(&yl[row * 264 + ks * 32 + k0]);
        }
#pragma unroll
        for (int nt = 0; nt < 6; nt++) {
          int brow = (nt >> 1) * 256 + h * 32 + (nt & 1) * 16 + m;
          short8 bb = ld8(W + WQKV + (size_t)brow * 256 + ks * 32 + k0);
#pragma unroll
          for (int mt = 0; mt < 4; mt++)
            acc[mt][nt] = mfma16(a[mt], bb, acc[mt][nt]);
        }
      }
#pragma unroll
      for (int nt = 0; nt < 6; nt++) {
        int hd = (nt & 1) * 16 + m;
        int c = (nt >> 1) * 256 + h * 32 + hd;
        float qb_ = qkv_b[c];
#pragma unroll
        for (int mt = 0; mt < 4; mt++)
#pragma unroll
          for (int rr = 0; rr < 4; rr++) {
            int row = mt * 16 + gq * 4 + rr;
            if (row >= 49) continue;
            u16 val = f2b(acc[mt][nt][rr] + qb_);
            if ((nt >> 1) == 0) prv[2048 + row * 32 + hd] = val;
            else if ((nt >> 1) == 1) prv[3616 + row * 32 + hd] = val;
            else prv[hd * 64 + row] = val;
          }
      }
    }
    // QK^T (same-wave LDS ordering via lgkmcnt)
    short8 aq[4], bk[4];
#pragma unroll
    for (int mt = 0; mt < 4; mt++) { int i = mt * 16 + m; if (i > 48) i = 48; aq[mt] = ld8(&prv[2048 + i * 32 + k0]); }
#pragma unroll
    for (int nt = 0; nt < 4; nt++) { int j = nt * 16 + m; if (j > 48) j = 48; bk[nt] = ld8(&prv[3616 + j * 32 + k0]); }
    f32x4 s[4][4] = {};
#pragma unroll
    for (int mt = 0; mt < 4; mt++)
#pragma unroll
      for (int nt = 0; nt < 4; nt++)
        s[mt][nt] = mfma16(aq[mt], bk[nt], s[mt][nt]);
    const float* BI = bias_g + h * 4096;
    float rsum[4][4];
#pragma unroll
    for (int mt = 0; mt < 4; mt++)
#pragma unroll
      for (int rr = 0; rr < 4; rr++) {
        int i = mt * 16 + gq * 4 + rr;
        float sv[4];
        float mx = -1e38f;
#pragma unroll
        for (int nt = 0; nt < 4; nt++) {
          sv[nt] = s[mt][nt][rr] * scale + BI[i * 64 + nt * 16 + m];
          mx = fmaxf(mx, sv[nt]);
        }
        mx = fmaxf(mx, __shfl_xor(mx, 1));
        mx = fmaxf(mx, __shfl_xor(mx, 2));
        mx = fmaxf(mx, __shfl_xor(mx, 4));
        mx = fmaxf(mx, __shfl_xor(mx, 8));
        float sum = 0.f;
#pragma unroll
        for (int nt = 0; nt < 4; nt++) { sv[nt] = __expf(sv[nt] - mx); sum += sv[nt]; }
        sum += __shfl_xor(sum, 1);
        sum += __shfl_xor(sum, 2);
        sum += __shfl_xor(sum, 4);
        sum += __shfl_xor(sum, 8);
        rsum[mt][rr] = sum;
        int isw = (i & 7) * 8;
#pragma unroll
        for (int nt = 0; nt < 4; nt++) {
          int j = nt * 16 + m;
          prv[2048 + i * 64 + (j ^ isw)] = f2b(sv[nt]);
        }
      }
    // PV
    f32x4 o[4][2] = {};
#pragma unroll
    for (int ks = 0; ks < 2; ks++) {
      short8 bv[2];
#pragma unroll
      for (int nt = 0; nt < 2; nt++)
        bv[nt] = ld8(&prv[(nt * 16 + m) * 64 + ks * 32 + k0]);
#pragma unroll
      for (int mt = 0; mt < 4; mt++) {
        int i = mt * 16 + m;
        short8 ap = *reinterpret_cast<const short8*>(
            &prv[2048 + i * 64 + ((ks * 32 + k0) ^ ((i & 7) * 8))]);
#pragma unroll
        for (int nt = 0; nt < 2; nt++)
          o[mt][nt] = mfma16(ap, bv[nt], o[mt][nt]);
      }
    }
#pragma unroll
    for (int mt = 0; mt < 4; mt++)
#pragma unroll
      for (int rr = 0; rr < 4; rr++) {
        float rinv = 1.f / rsum[mt][rr];
#pragma unroll
        for (int nt = 0; nt < 2; nt++)
          oh[hp][mt][nt][rr] = o[mt][nt][rr] * rinv;
      }
  }
  __syncthreads();  // all waves done reading yl
#pragma unroll
  for (int hp = 0; hp < 2; hp++)
#pragma unroll
    for (int mt = 0; mt < 4; mt++)
#pragma unroll
      for (int rr = 0; rr < 4; rr++) {
        int row = mt * 16 + gq * 4 + rr;
        if (row >= 49) continue;
#pragma unroll
        for (int nt = 0; nt < 2; nt++) {
          int col = wave * 64 + hp * 32 + nt * 16 + m;
          yl[row * 264 + col] = f2b(oh[hp][mt][nt][rr]);
        }
      }
  __syncthreads();
  // proj GEMM + shortcut -> x2 in-place over sc
  {
    f32x4 acc[4][4] = {};
#pragma unroll 2
    for (int ks = 0; ks < 8; ks++) {
      short8 a[4];
#pragma unroll
      for (int mt = 0; mt < 4; mt++) {
        int row = mt * 16 + m; if (row > 48) row = 48;
        a[mt] = ld8(&yl[row * 264 + ks * 32 + k0]);
      }
#pragma unroll
      for (int nt = 0; nt < 4; nt++) {
        short8 bb = ld8(W + WPROJ + (size_t)(cb + nt * 16 + m) * 256 + ks * 32 + k0);
#pragma unroll
        for (int mt = 0; mt < 4; mt++)
          acc[mt][nt] = mfma16(a[mt], bb, acc[mt][nt]);
      }
    }
#pragma unroll
    for (int mt = 0; mt < 4; mt++)
#pragma unroll
      for (int rr = 0; rr < 4; rr++) {
        int row = mt * 16 + gq * 4 + rr;
        if (row >= 49) continue;
        int hh = h0 + row / 7, ww = w0 + row % 7;
        if (hh >= 96 || ww >= 96) continue;
        size_t tok = (size_t)hh * 96 + ww;
#pragma unroll
        for (int nt = 0; nt < 4; nt++) {
          int c = cb + nt * 16 + m;
          float v = acc[mt][nt][rr] + proj_b[c] + b2f(scb[tok * 256 + c]);
          scb[tok * 256 + c] = f2b(v);
        }
      }
  }
}

// ============== K_LN2: x2 -> ln2q (no LDS, 1 row per wave-iter) ===============
__global__ __launch_bounds__(256) void k_ln2(
    const u16* x2b, const float* g2, const float* be2, u16* ln2q) {
  int tid = threadIdx.x, lane = tid & 63, wave = tid >> 6;
  f32x4 gg = *(const f32x4*)&g2[lane * 4];
  f32x4 be = *(const f32x4*)&be2[lane * 4];
#pragma unroll
  for (int rr = 0; rr < 4; rr++) {
    int row = blockIdx.x * 16 + wave * 4 + rr;
    u16x4 raw = *reinterpret_cast<const u16x4*>(x2b + (size_t)row * 256 + lane * 4);
    f32x4 v;
#pragma unroll
    for (int q2 = 0; q2 < 4; q2++) v[q2] = b2f(raw[q2]);
    float s1 = wredsum(v[0] + v[1] + v[2] + v[3]);
    float mean = s1 * 0.00390625f;
    f32x4 dv; float sq = 0.f;
#pragma unroll
    for (int q2 = 0; q2 < 4; q2++) { dv[q2] = v[q2] - mean; sq += dv[q2] * dv[q2]; }
    float s2 = wredsum(sq);
    float rstd = rsqrtf(s2 * 0.00390625f + 1e-6f);
    u16x4 ov;
#pragma unroll
    for (int q2 = 0; q2 < 4; q2++) ov[q2] = f2b(dv[q2] * rstd * gg[q2] + be[q2]);
    *reinterpret_cast<u16x4*>(ln2q + (size_t)row * 256 + lane * 4) = ov;
  }
}

// ====== K5G: mlp1 GEMM (M=18432,N=1024,K=256), 128x128 tile, dbuf LDS =========
__global__ __launch_bounds__(256) void k5g(
    const u16* W, const u16* ln2q, const float* mb1, u16* h1q) {
  __shared__ __align__(16) u16 Ab[2][4096];
  __shared__ __align__(16) u16 Bb[2][4096];
  int tid = threadIdx.x;
  int lane = tid & 63, wave = tid >> 6;
  int m = lane & 15, gq = lane >> 4;
  int wr = wave >> 1, wc = wave & 1;
  int bm = blockIdx.x * 128, bn = blockIdx.y * 128;
  const u16* Ag = ln2q + (size_t)bm * 256;
  const u16* Bg = W + WM1 + (size_t)bn * 256;
  f32x4 acc[4][4] = {};
#pragma unroll
  for (int c = 0; c < 2; c++) {
    int flat = (wave * 2 + c) * 512 + lane * 8;
    int r = flat >> 5, cc = flat & 31;
    GLL(Ag + (size_t)r * 256 + cc, &Ab[0][(wave * 2 + c) * 512]);
    GLL(Bg + (size_t)r * 256 + cc, &Bb[0][(wave * 2 + c) * 512]);
  }
  __syncthreads();
  int cur = 0;
  for (int ki = 0; ki < 8; ki++) {
    if (ki < 7) {
      int kk = (ki + 1) * 32;
#pragma unroll
      for (int c = 0; c < 2; c++) {
        int flat = (wave * 2 + c) * 512 + lane * 8;
        int r = flat >> 5, cc = flat & 31;
        GLL(Ag + (size_t)r * 256 + kk + cc, &Ab[cur ^ 1][(wave * 2 + c) * 512]);
        GLL(Bg + (size_t)r * 256 + kk + cc, &Bb[cur ^ 1][(wave * 2 + c) * 512]);
      }
    }
    short8 aF[4], bF[4];
#pragma unroll
    for (int mt = 0; mt < 4; mt++)
      aF[mt] = ld8(&Ab[cur][(wr * 64 + mt * 16 + m) * 32 + gq * 8]);
#pragma unroll
    for (int nt = 0; nt < 4; nt++)
      bF[nt] = ld8(&Bb[cur][(wc * 64 + nt * 16 + m) * 32 + gq * 8]);
#pragma unroll
    for (int mt = 0; mt < 4; mt++)
#pragma unroll
      for (int nt = 0; nt < 4; nt++)
        acc[mt][nt] = mfma16(aF[mt], bF[nt], acc[mt][nt]);
    __syncthreads();
    cur ^= 1;
  }
#pragma unroll
  for (int nt = 0; nt < 4; nt++) {
    int ch = bn + wc * 64 + nt * 16 + m;
    float bias = mb1[ch];
#pragma unroll
    for (int mt = 0; mt < 4; mt++)
#pragma unroll
      for (int rr = 0; rr < 4; rr++) {
        int tok = bm + wr * 64 + mt * 16 + gq * 4 + rr;
        float v = acc[mt][nt][rr] + bias;
        v = 0.5f * v * (1.f + erff(v * 0.7071067811865475f));
        h1q[(size_t)tok * 1024 + ch] = f2b(v);
      }
  }
}

// ====== K6G: mlp2 GEMM (M=18432,N=256,K=1024), 64x128 tile + NCHW out =========
__global__ __launch_bounds__(256) void k6g(
    const u16* W, const u16* h1q, const float* mb2, const u16* x2b,
    float* out, int tok_base) {
  __shared__ __align__(16) u16 Ab[2][2048];
  __shared__ __align__(16) u16 Bb[2][4096];
  __shared__ float ot[128 * 66];
  int tid = threadIdx.x;
  int lane = tid & 63, wave = tid >> 6;
  int m = lane & 15, gq = lane >> 4;
  int wr = wave >> 1, wc = wave & 1;
  int bm = blockIdx.x * 64, bn = blockIdx.y * 128;
  const u16* Ag = h1q + (size_t)bm * 1024;
  const u16* Bg = W + WM2 + (size_t)bn * 1024;
  f32x4 acc[2][4] = {};
  {
    int flatA = wave * 512 + lane * 8;
    GLL(Ag + (size_t)(flatA >> 5) * 1024 + (flatA & 31), &Ab[0][wave * 512]);
#pragma unroll
    for (int c = 0; c < 2; c++) {
      int flat = (wave * 2 + c) * 512 + lane * 8;
      GLL(Bg + (size_t)(flat >> 5) * 1024 + (flat & 31), &Bb[0][(wave * 2 + c) * 512]);
    }
  }
  __syncthreads();
  int cur = 0;
  for (int ki = 0; ki < 32; ki++) {
    if (ki < 31) {
      int kk = (ki + 1) * 32;
      int flatA = wave * 512 + lane * 8;
      GLL(Ag + (size_t)(flatA >> 5) * 1024 + kk + (flatA & 31), &Ab[cur ^ 1][wave * 512]);
#pragma unroll
      for (int c = 0; c < 2; c++) {
        int flat = (wave * 2 + c) * 512 + lane * 8;
        GLL(Bg + (size_t)(flat >> 5) * 1024 + kk + (flat & 31), &Bb[cur ^ 1][(wave * 2 + c) * 512]);
      }
    }
    short8 aF[2], bF[4];
#pragma unroll
    for (int mt = 0; mt < 2; mt++)
      aF[mt] = ld8(&Ab[cur][(wr * 32 + mt * 16 + m) * 32 + gq * 8]);
#pragma unroll
    for (int nt = 0; nt < 4; nt++)
      bF[nt] = ld8(&Bb[cur][(wc * 64 + nt * 16 + m) * 32 + gq * 8]);
#pragma unroll
    for (int mt = 0; mt < 2; mt++)
#pragma unroll
      for (int nt = 0; nt < 4; nt++)
        acc[mt][nt] = mfma16(aF[mt], bF[nt], acc[mt][nt]);
    __syncthreads();
    cur ^= 1;
  }
#pragma unroll
  for (int nt = 0; nt < 4; nt++) {
    int nl = wc * 64 + nt * 16 + m;
    int ch = bn + nl;
    float bias = mb2[ch];
#pragma unroll
    for (int mt = 0; mt < 2; mt++)
#pragma unroll
      for (int rr = 0; rr < 4; rr++) {
        int tl = wr * 32 + mt * 16 + gq * 4 + rr;
        float v = acc[mt][nt][rr] + bias + b2f(x2b[(size_t)(bm + tl) * 256 + ch]);
        ot[nl * 66 + tl] = v;
      }
  }
  __syncthreads();
  int tg = tok_base + bm;
  int bimg = tg / 9216, hw0 = tg % 9216;
  for (int it = 0; it < 32; it++) {
    int flat = it * 256 + tid;
    int j = flat >> 6, t = flat & 63;
    out[((size_t)bimg * 256 + bn + j) * 9216 + hw0 + t] = ot[j * 66 + t];
  }
}

extern "C" void kernel_launch(void* const* d_in, const int* in_sizes, int n_in,
                              void* d_out, int out_size, void* d_ws, size_t ws_size,
                              hipStream_t stream) {
  const float* x      = (const float*)d_in[0];
  const float* skipf  = (const float*)d_in[1];
  const float* up_w   = (const float*)d_in[2];
  const float* up_b   = (const float*)d_in[3];
  const float* skip_w = (const float*)d_in[4];
  const float* g1     = (const float*)d_in[5];
  const float* be1    = (const float*)d_in[6];
  const float* qkv_w  = (const float*)d_in[7];
  const float* qkv_b  = (const float*)d_in[8];
  const float* rpb    = (const float*)d_in[9];
  const float* proj_w = (const float*)d_in[10];
  const float* proj_b = (const float*)d_in[11];
  const float* g2     = (const float*)d_in[12];
  const float* be2    = (const float*)d_in[13];
  const float* m_w1   = (const float*)d_in[14];
  const float* m_b1   = (const float*)d_in[15];
  const float* m_w2   = (const float*)d_in[16];
  const float* m_b2   = (const float*)d_in[17];
  if (ws_size < WS_NEED) {
    k_sentinel<<<1, 256, 0, stream>>>((float*)d_out);
    return;
  }
  char* ws = (char*)d_ws;
  u16*   W    = (u16*)ws;
  float* bias = (float*)(ws + OFF_BIAS);
  u16*   sc   = (u16*)(ws + OFF_SC);
  u16*   xt   = (u16*)(ws + OFF_OVR);
  u16*   skt  = (u16*)(ws + OFF_OVR);
  u16*   ln2q = (u16*)(ws + OFF_OVR);
  u16*   h1q  = (u16*)(ws + OFF_OVR + 9437184u);

  k_prep<<<5504, 256, 0, stream>>>(qkv_w, proj_w, m_w1, m_w2, skip_w, up_w, rpb, W, bias);
  k_tr<<<dim3(72, 16, 8), 256, 0, stream>>>(x, xt, 512, 2304);
  k1_conv<<<dim3(768, 2), 256, 0, stream>>>(W, xt, up_b, sc);
  k_tr_skip<<<dim3(3, 8, 768), 256, 0, stream>>>(skipf, skt);
  k234<<<1568, 256, 0, stream>>>(W, sc, skt, g1, be1, qkv_b, bias, proj_b);
  for (int q = 0; q < 4; q++) {
    const u16* x2b = sc + (size_t)q * 18432 * 256;
    k_ln2<<<1152, 256, 0, stream>>>(x2b, g2, be2, ln2q);
    k5g<<<dim3(144, 8), 256, 0, stream>>>(W, ln2q, m_b1, h1q);
    k6g<<<dim3(288, 2), 256, 0, stream>>>(W, h1q, m_b2, x2b, (float*)d_out, q * 18432);
  }
}

// Round 7
// 768.301 us; speedup vs baseline: 1.7824x; 1.0773x over previous
//
#include <hip/hip_runtime.h>

typedef __attribute__((ext_vector_type(8))) short short8;
typedef __attribute__((ext_vector_type(4))) float f32x4;
typedef __attribute__((ext_vector_type(4))) unsigned short u16x4;
typedef unsigned short u16;
typedef unsigned int u32;

#define DEV static __device__ __forceinline__

DEV u16 f2b(float f) {
  u32 u = __builtin_bit_cast(u32, f);
  return (u16)((u + 0x7fffu + ((u >> 16) & 1u)) >> 16);
}
DEV float b2f(u16 h) {
  u32 u = ((u32)h) << 16;
  return __builtin_bit_cast(float, u);
}
DEV short8 ld8(const u16* p) { return *reinterpret_cast<const short8*>(p); }
DEV f32x4 mfma16(short8 a, short8 b, f32x4 c) {
  return __builtin_amdgcn_mfma_f32_16x16x32_bf16(a, b, c, 0, 0, 0);
}
DEV float wredsum(float v) {
#pragma unroll
  for (int off = 1; off < 64; off <<= 1) v += __shfl_xor(v, off);
  return v;
}

#define GLL(gp, lp) __builtin_amdgcn_global_load_lds( \
    (const __attribute__((address_space(1))) void*)(gp), \
    (__attribute__((address_space(3))) void*)(lp), 16, 0, 0)

// ---- weight arena (u16 element offsets) ----
#define WQKV   0         // [768][256]
#define WPROJ  196608    // [256][256]
#define WM1    262144    // [1024][256]
#define WM2    524288    // [256][1024]
#define WSKIP  786432    // [256][256]
#define WUP    851968    // [4][256][512]  kk = kh*2+kw

// ---- ws byte offsets ----
#define OFF_BIAS 2752512u
#define OFF_SC   2883584u     // bf16 sc: conv shortcut -> x2 [73728][256]
#define OFF_OVR  40632320u    // 55,595,008B overlay:
// phase A: xt @OVR (18,874,368)  [dead after k1]
// phase B: skt @OVR (37,748,736) [dead after k2a]
// phase C (per 2-img chunk): qc @OVR (9,834,496); kc @+9,834,496;
//         vtc @+19,668,992 (12,845,056)  -> ends 32,514,048
// phase D (per quarter): ln2q @OVR (9,437,184); h1q @+9,437,184 (37,748,736)
// d_out scratch: win u16 @0 (39,337,984); ob_c u16 @36,159,488+(3-c)*9,834,496
#define WS_NEED  96227328u

__global__ void k_sentinel(float* out) { out[threadIdx.x] = 31337.0f; }

// ================= prep: weights -> bf16, up_w transpose, bias table ==========
__global__ __launch_bounds__(256) void k_prep(
    const float* qkv_w, const float* proj_w, const float* mlp_w1,
    const float* mlp_w2, const float* skip_w, const float* up_w,
    const float* rpb, u16* W, float* bias_g) {
  int i = blockIdx.x * 256 + threadIdx.x;
  if (i < 196608) { W[WQKV + i] = f2b(qkv_w[i]); return; }
  i -= 196608;
  if (i < 65536) { W[WPROJ + i] = f2b(proj_w[i]); return; }
  i -= 65536;
  if (i < 262144) { W[WM1 + i] = f2b(mlp_w1[i]); return; }
  i -= 262144;
  if (i < 262144) { W[WM2 + i] = f2b(mlp_w2[i]); return; }
  i -= 262144;
  if (i < 65536) { W[WSKIP + i] = f2b(skip_w[i]); return; }
  i -= 65536;
  if (i < 524288) {
    int ci = i & 511; int rest = i >> 9; int co = rest & 255; int kk = rest >> 8;
    W[WUP + i] = f2b(up_w[ci * 1024 + co * 4 + kk]);
    return;
  }
  i -= 524288;
  if (i < 32768) {
    int h = i >> 12, r = i & 4095, ii = r >> 6, j = r & 63;
    float v;
    if (j >= 49) v = -1e30f;
    else if (ii >= 49) v = 0.f;
    else {
      int d0 = (ii / 7 - j / 7) + 6, d1 = (ii % 7 - j % 7) + 6;
      v = rpb[(d0 * 13 + d1) * 8 + h];
    }
    bias_g[i] = v;
  }
}

// ============== NCHW f32 -> NHWC bf16 tiled transpose (for x) =================
__global__ __launch_bounds__(256) void k_tr(const float* src, u16* dst, int C, int HW) {
  __shared__ float t[32][33];
  int hw0 = blockIdx.x * 32, c0 = blockIdx.y * 32, b = blockIdx.z;
  int tx = threadIdx.x & 31, ty = threadIdx.x >> 5;
  const float* s = src + (size_t)b * C * HW;
  u16* d = dst + (size_t)b * C * HW;
#pragma unroll
  for (int i = 0; i < 4; i++)
    t[ty + i * 8][tx] = s[(size_t)(c0 + ty + i * 8) * HW + hw0 + tx];
  __syncthreads();
#pragma unroll
  for (int i = 0; i < 4; i++)
    d[(size_t)(hw0 + ty + i * 8) * C + c0 + tx] = f2b(t[tx][ty + i * 8]);
}

// ===== batched skip transpose: skip[b][c][h][w] -> skt[b][h][w][c] (bf16) =====
__global__ __launch_bounds__(256) void k_tr_skip(const float* src, u16* dst) {
  __shared__ float t[32][33];
  int w0 = blockIdx.x * 32, c0 = blockIdx.y * 32;
  int z = blockIdx.z;
  int b = z / 96, h = z - b * 96;
  int tx = threadIdx.x & 31, ty = threadIdx.x >> 5;
  const float* s = src + (size_t)b * 256 * 9216 + (size_t)h * 96;
  u16* d = dst + (((size_t)b * 96 + h) * 96) * 256;
#pragma unroll
  for (int i = 0; i < 4; i++)
    t[ty + i * 8][tx] = s[(size_t)(c0 + ty + i * 8) * 9216 + w0 + tx];
  __syncthreads();
#pragma unroll
  for (int i = 0; i < 4; i++)
    d[(size_t)(w0 + ty + i * 8) * 256 + c0 + tx] = f2b(t[tx][ty + i * 8]);
}

// ============== K1: convT only -> sc (conv-only shortcut) =====================
__global__ __launch_bounds__(256) void k1_conv(
    const u16* W, const u16* xt, const float* up_b, u16* sc) {
  int blk = blockIdx.x;
  int par = blockIdx.y;
  int b = blk / 96, r0 = blk % 96;
  int h2 = r0 >> 1, kw = r0 & 1;
  int h = h2 * 2 + par;
  int lane = threadIdx.x & 63, wave = threadIdx.x >> 6;
  int m = lane & 15, gq = lane >> 4, k0 = gq * 8;
  const u16* A = xt + (((size_t)b * 48 + h2) * 48) * 512;
  const u16* B = W + WUP + (size_t)(par * 2 + kw) * 131072;
  f32x4 acc[3][4] = {};
#pragma unroll 4
  for (int ks = 0; ks < 16; ks++) {
    short8 a[3];
#pragma unroll
    for (int mt = 0; mt < 3; mt++)
      a[mt] = ld8(A + (size_t)(mt * 16 + m) * 512 + ks * 32 + k0);
#pragma unroll
    for (int nt = 0; nt < 4; nt++) {
      short8 bb = ld8(B + (size_t)(wave * 64 + nt * 16 + m) * 512 + ks * 32 + k0);
#pragma unroll
      for (int mt = 0; mt < 3; mt++)
        acc[mt][nt] = mfma16(a[mt], bb, acc[mt][nt]);
    }
  }
  float ub[4];
#pragma unroll
  for (int nt = 0; nt < 4; nt++) ub[nt] = up_b[wave * 64 + nt * 16 + m];
#pragma unroll
  for (int mt = 0; mt < 3; mt++)
#pragma unroll
    for (int nt = 0; nt < 4; nt++)
#pragma unroll
      for (int rr = 0; rr < 4; rr++) {
        int t = mt * 16 + gq * 4 + rr;
        int w = kw + 2 * t;
        int c = wave * 64 + nt * 16 + m;
        sc[(((size_t)b * 96 + h) * 96 + w) * 256 + c] = f2b(acc[mt][nt][rr] + ub[nt]);
      }
}

// ============== K2A: gather + skip 1x1 GEMM + LN1 -> win (d_out scratch) ======
// grid (301, 8): 32 window-tokens per block of image blockIdx.y
__global__ __launch_bounds__(256) void k2a(
    const u16* W, const u16* sc, const u16* skt, const float* g1,
    const float* be1, u16* win) {
  __shared__ __align__(16) u16 cv[32 * 264];
  __shared__ __align__(16) u16 sk[32 * 264];
  int tid = threadIdx.x;
  int lane = tid & 63, wave = tid >> 6;
  int m = lane & 15, gq = lane >> 4, k0 = gq * 8;
  int y = blockIdx.y;
  int tok0 = blockIdx.x * 32;
  const u16* scb = sc + (size_t)y * 2359296;
  const u16* skb = skt + (size_t)y * 2359296;
#pragma unroll
  for (int it = 0; it < 4; it++) {
    int flat = it * 2048 + tid * 8;
    int row = flat >> 8, col = flat & 255;
    int g = tok0 + row;
    int w_ = g / 49, i = g - w_ * 49;
    int wrow = w_ / 14, wcol = w_ - wrow * 14;
    int hh = wrow * 7 + i / 7, ww = wcol * 7 + i % 7;
    bool valid = (g < 9604) && (hh < 96) && (ww < 96);
    short8 vc = {}, vs = {};
    if (valid) {
      size_t base = ((size_t)hh * 96 + ww) * 256 + col;
      vc = ld8(scb + base);
      vs = ld8(skb + base);
    }
    *reinterpret_cast<short8*>(&cv[row * 264 + col]) = vc;
    *reinterpret_cast<short8*>(&sk[row * 264 + col]) = vs;
  }
  __syncthreads();
  // skip GEMM (K=256), wave owns 64 cols
  int cb = wave * 64;
  f32x4 acc[2][4] = {};
#pragma unroll 4
  for (int ks = 0; ks < 8; ks++) {
    short8 a0 = ld8(&sk[m * 264 + ks * 32 + k0]);
    short8 a1 = ld8(&sk[(16 + m) * 264 + ks * 32 + k0]);
#pragma unroll
    for (int nt = 0; nt < 4; nt++) {
      short8 bb = ld8(W + WSKIP + (size_t)(cb + nt * 16 + m) * 256 + ks * 32 + k0);
      acc[0][nt] = mfma16(a0, bb, acc[0][nt]);
      acc[1][nt] = mfma16(a1, bb, acc[1][nt]);
    }
  }
  __syncthreads();
  // y = skipterm + conv -> sk
#pragma unroll
  for (int mt = 0; mt < 2; mt++)
#pragma unroll
    for (int nt = 0; nt < 4; nt++) {
      int c = cb + nt * 16 + m;
#pragma unroll
      for (int rr = 0; rr < 4; rr++) {
        int row = mt * 16 + gq * 4 + rr;
        float yv = acc[mt][nt][rr] + b2f(cv[row * 264 + c]);
        sk[row * 264 + c] = f2b(yv);
      }
    }
  __syncthreads();
  // LN1 -> win (zeros for pad rows)
  f32x4 gg = *(const f32x4*)&g1[lane * 4];
  f32x4 be = *(const f32x4*)&be1[lane * 4];
  for (int tt = 0; tt < 8; tt++) {
    int row = wave * 8 + tt;
    int g = tok0 + row;
    if (g >= 9604) continue;
    int w_ = g / 49, i = g - w_ * 49;
    int wrow = w_ / 14, wcol = w_ - wrow * 14;
    int hh = wrow * 7 + i / 7, ww = wcol * 7 + i % 7;
    u16x4 ov = {};
    if (hh < 96 && ww < 96) {
      u16x4 raw = *(const u16x4*)&sk[row * 264 + lane * 4];
      f32x4 v;
#pragma unroll
      for (int q2 = 0; q2 < 4; q2++) v[q2] = b2f(raw[q2]);
      float s1 = wredsum(v[0] + v[1] + v[2] + v[3]);
      float mean = s1 * 0.00390625f;
      f32x4 dv; float sq = 0.f;
#pragma unroll
      for (int q2 = 0; q2 < 4; q2++) { dv[q2] = v[q2] - mean; sq += dv[q2] * dv[q2]; }
      float s2 = wredsum(sq);
      float rstd = rsqrtf(s2 * 0.00390625f + 1e-6f);
#pragma unroll
      for (int q2 = 0; q2 < 4; q2++) ov[q2] = f2b(dv[q2] * rstd * gg[q2] + be[q2]);
    }
    *reinterpret_cast<u16x4*>(win + ((size_t)y * 9604 + g) * 256 + lane * 4) = ov;
  }
}

// ====== K2B: qkv GEMM 128x128 dbuf (per 2-image chunk, M=19208 pad 19328) =====
__global__ __launch_bounds__(256) void k2b(
    const u16* W, const u16* win, const float* qkv_b,
    u16* qc, u16* kc, u16* vtc, int chunk) {
  __shared__ __align__(16) u16 Ab[2][4096];
  __shared__ __align__(16) u16 Bb[2][4096];
  int tid = threadIdx.x;
  int lane = tid & 63, wave = tid >> 6;
  int m = lane & 15, gq = lane >> 4;
  int wr = wave >> 1, wc = wave & 1;
  int bm = blockIdx.x * 128, bn = blockIdx.y * 128;
  const u16* Ag = win + (size_t)(chunk * 19208 + bm) * 256;
  const u16* Bg = W + WQKV + (size_t)bn * 256;
  f32x4 acc[4][4] = {};
#pragma unroll
  for (int c = 0; c < 2; c++) {
    int flat = (wave * 2 + c) * 512 + lane * 8;
    int r = flat >> 5, cc = flat & 31;
    GLL(Ag + (size_t)r * 256 + cc, &Ab[0][(wave * 2 + c) * 512]);
    GLL(Bg + (size_t)r * 256 + cc, &Bb[0][(wave * 2 + c) * 512]);
  }
  __syncthreads();
  int cur = 0;
  for (int ki = 0; ki < 8; ki++) {
    if (ki < 7) {
      int kk = (ki + 1) * 32;
#pragma unroll
      for (int c = 0; c < 2; c++) {
        int flat = (wave * 2 + c) * 512 + lane * 8;
        int r = flat >> 5, cc = flat & 31;
        GLL(Ag + (size_t)r * 256 + kk + cc, &Ab[cur ^ 1][(wave * 2 + c) * 512]);
        GLL(Bg + (size_t)r * 256 + kk + cc, &Bb[cur ^ 1][(wave * 2 + c) * 512]);
      }
    }
    short8 aF[4], bF[4];
#pragma unroll
    for (int mt = 0; mt < 4; mt++)
      aF[mt] = ld8(&Ab[cur][(wr * 64 + mt * 16 + m) * 32 + gq * 8]);
#pragma unroll
    for (int nt = 0; nt < 4; nt++)
      bF[nt] = ld8(&Bb[cur][(wc * 64 + nt * 16 + m) * 32 + gq * 8]);
#pragma unroll
    for (int mt = 0; mt < 4; mt++)
#pragma unroll
      for (int nt = 0; nt < 4; nt++)
        acc[mt][nt] = mfma16(aF[mt], bF[nt], acc[mt][nt]);
    __syncthreads();
    cur ^= 1;
  }
  // epilogue: scatter q/k/vt (chunk-local)
  int chv[4], typev[4], hdv[4], bhoff[4];
  float qbv[4];
#pragma unroll
  for (int nt = 0; nt < 4; nt++) {
    int ch = bn + wc * 64 + nt * 16 + m;
    chv[nt] = ch;
    qbv[nt] = qkv_b[ch];
    typev[nt] = ch >> 8;
    hdv[nt] = ch & 31;
    bhoff[nt] = (ch >> 5) & 7;
  }
#pragma unroll
  for (int mt = 0; mt < 4; mt++)
#pragma unroll
    for (int rr = 0; rr < 4; rr++) {
      int t = bm + wr * 64 + mt * 16 + gq * 4 + rr;
      if (t >= 19208) continue;
      int bloc = t / 49, i = t - bloc * 49;
#pragma unroll
      for (int nt = 0; nt < 4; nt++) {
        float v = acc[mt][nt][rr] + qbv[nt];
        size_t bh = (size_t)bloc * 8 + bhoff[nt];
        u16 val = f2b(v);
        if (typev[nt] == 0) qc[bh * 1568 + i * 32 + hdv[nt]] = val;
        else if (typev[nt] == 1) kc[bh * 1568 + i * 32 + hdv[nt]] = val;
        else vtc[bh * 2048 + hdv[nt] * 64 + i] = val;
      }
    }
}

// ============== K3: window attention, one wave per (window, head) =============
__global__ __launch_bounds__(256) void k3_attn(
    const u16* qc, const u16* kc, const u16* vtc, const float* bias_g, u16* obb) {
  __shared__ u16 plds[4][64 * 64];
  int lane = threadIdx.x & 63, wave = threadIdx.x >> 6;
  int b_ = blockIdx.x >> 1;
  int h = (blockIdx.x & 1) * 4 + wave;
  int m = lane & 15, gq = lane >> 4, k0 = gq * 8;
  size_t bh = (size_t)b_ * 8 + h;
  const u16* Q = qc + bh * 1568;
  const u16* K = kc + bh * 1568;
  const u16* V = vtc + bh * 2048;
  const float* BI = bias_g + h * 4096;
  short8 aq[4], bk[4];
#pragma unroll
  for (int mt = 0; mt < 4; mt++) { int i = mt * 16 + m; if (i > 48) i = 48; aq[mt] = ld8(Q + i * 32 + k0); }
#pragma unroll
  for (int nt = 0; nt < 4; nt++) { int j = nt * 16 + m; if (j > 48) j = 48; bk[nt] = ld8(K + j * 32 + k0); }
  f32x4 s[4][4] = {};
#pragma unroll
  for (int mt = 0; mt < 4; mt++)
#pragma unroll
    for (int nt = 0; nt < 4; nt++)
      s[mt][nt] = mfma16(aq[mt], bk[nt], s[mt][nt]);
  const float scale = 0.1767766952966369f;  // 1/sqrt(32)
  float rsum[4][4];
#pragma unroll
  for (int mt = 0; mt < 4; mt++)
#pragma unroll
    for (int rr = 0; rr < 4; rr++) {
      int i = mt * 16 + gq * 4 + rr;
      float sv[4];
      float mx = -1e38f;
#pragma unroll
      for (int nt = 0; nt < 4; nt++) {
        sv[nt] = s[mt][nt][rr] * scale + BI[i * 64 + nt * 16 + m];
        mx = fmaxf(mx, sv[nt]);
      }
      mx = fmaxf(mx, __shfl_xor(mx, 1));
      mx = fmaxf(mx, __shfl_xor(mx, 2));
      mx = fmaxf(mx, __shfl_xor(mx, 4));
      mx = fmaxf(mx, __shfl_xor(mx, 8));
      float sum = 0.f;
#pragma unroll
      for (int nt = 0; nt < 4; nt++) { sv[nt] = __expf(sv[nt] - mx); sum += sv[nt]; }
      sum += __shfl_xor(sum, 1);
      sum += __shfl_xor(sum, 2);
      sum += __shfl_xor(sum, 4);
      sum += __shfl_xor(sum, 8);
      rsum[mt][rr] = sum;
      int isw = (i & 7) * 8;
#pragma unroll
      for (int nt = 0; nt < 4; nt++) {
        int j = nt * 16 + m;
        plds[wave][i * 64 + (j ^ isw)] = f2b(sv[nt]);
      }
    }
  __syncthreads();
  f32x4 o[4][2] = {};
#pragma unroll
  for (int ks = 0; ks < 2; ks++) {
    short8 bv[2];
#pragma unroll
    for (int nt = 0; nt < 2; nt++)
      bv[nt] = ld8(V + (size_t)(nt * 16 + m) * 64 + ks * 32 + k0);
#pragma unroll
    for (int mt = 0; mt < 4; mt++) {
      int i = mt * 16 + m;
      short8 ap = *reinterpret_cast<const short8*>(
          &plds[wave][i * 64 + ((ks * 32 + k0) ^ ((i & 7) * 8))]);
#pragma unroll
      for (int nt = 0; nt < 2; nt++)
        o[mt][nt] = mfma16(ap, bv[nt], o[mt][nt]);
    }
  }
#pragma unroll
  for (int mt = 0; mt < 4; mt++)
#pragma unroll
    for (int rr = 0; rr < 4; rr++) {
      int i = mt * 16 + gq * 4 + rr;
      if (i >= 49) continue;
      float rinv = 1.f / rsum[mt][rr];
#pragma unroll
      for (int nt = 0; nt < 2; nt++) {
        int c = h * 32 + nt * 16 + m;
        obb[((size_t)b_ * 49 + i) * 256 + c] = f2b(o[mt][nt][rr] * rinv);
      }
    }
}

// ====== K4W: proj GEMM 128x128 dbuf + shortcut -> x2 (grid (151,2,4)) =========
__global__ __launch_bounds__(256) void k4w(
    const u16* W, const char* dout, const float* proj_b, u16* sc) {
  __shared__ __align__(16) u16 Ab[2][4096];
  __shared__ __align__(16) u16 Bb[2][4096];
  int tid = threadIdx.x;
  int lane = tid & 63, wave = tid >> 6;
  int m = lane & 15, gq = lane >> 4;
  int wr = wave >> 1, wc = wave & 1;
  int bm = blockIdx.x * 128, bn = blockIdx.y * 128;
  int z = blockIdx.z;
  const u16* Ag = (const u16*)(dout + 36159488u + (size_t)(3 - z) * 9834496u);
  const u16* Bg = W + WPROJ + (size_t)bn * 256;
  f32x4 acc[4][4] = {};
#pragma unroll
  for (int c = 0; c < 2; c++) {
    int flat = (wave * 2 + c) * 512 + lane * 8;
    int r = flat >> 5, cc = flat & 31;
    int rg = bm + r; if (rg > 19207) rg = 19207;
    GLL(Ag + (size_t)rg * 256 + cc, &Ab[0][(wave * 2 + c) * 512]);
    GLL(Bg + (size_t)r * 256 + cc, &Bb[0][(wave * 2 + c) * 512]);
  }
  __syncthreads();
  int cur = 0;
  for (int ki = 0; ki < 8; ki++) {
    if (ki < 7) {
      int kk = (ki + 1) * 32;
#pragma unroll
      for (int c = 0; c < 2; c++) {
        int flat = (wave * 2 + c) * 512 + lane * 8;
        int r = flat >> 5, cc = flat & 31;
        int rg = bm + r; if (rg > 19207) rg = 19207;
        GLL(Ag + (size_t)rg * 256 + kk + cc, &Ab[cur ^ 1][(wave * 2 + c) * 512]);
        GLL(Bg + (size_t)r * 256 + kk + cc, &Bb[cur ^ 1][(wave * 2 + c) * 512]);
      }
    }
    short8 aF[4], bF[4];
#pragma unroll
    for (int mt = 0; mt < 4; mt++)
      aF[mt] = ld8(&Ab[cur][(wr * 64 + mt * 16 + m) * 32 + gq * 8]);
#pragma unroll
    for (int nt = 0; nt < 4; nt++)
      bF[nt] = ld8(&Bb[cur][(wc * 64 + nt * 16 + m) * 32 + gq * 8]);
#pragma unroll
    for (int mt = 0; mt < 4; mt++)
#pragma unroll
      for (int nt = 0; nt < 4; nt++)
        acc[mt][nt] = mfma16(aF[mt], bF[nt], acc[mt][nt]);
    __syncthreads();
    cur ^= 1;
  }
#pragma unroll
  for (int mt = 0; mt < 4; mt++)
#pragma unroll
    for (int rr = 0; rr < 4; rr++) {
      int t = bm + wr * 64 + mt * 16 + gq * 4 + rr;
      if (t >= 19208) continue;
      int bloc = t / 49, i = t - bloc * 49;
      int b_ = z * 392 + bloc;
      int img = b_ / 196, wl = b_ - img * 196;
      int wrow = wl / 14, wcol = wl - wrow * 14;
      int hh = wrow * 7 + i / 7, ww = wcol * 7 + i % 7;
      if (hh >= 96 || ww >= 96) continue;
      size_t tok = ((size_t)img * 96 + hh) * 96 + ww;
#pragma unroll
      for (int nt = 0; nt < 4; nt++) {
        int ch = bn + wc * 64 + nt * 16 + m;
        float v = acc[mt][nt][rr] + proj_b[ch] + b2f(sc[tok * 256 + ch]);
        sc[tok * 256 + ch] = f2b(v);
      }
    }
}

// ============== K_LN2: x2 -> ln2q (no LDS, 1 row per wave-iter) ===============
__global__ __launch_bounds__(256) void k_ln2(
    const u16* x2b, const float* g2, const float* be2, u16* ln2q) {
  int tid = threadIdx.x, lane = tid & 63, wave = tid >> 6;
  f32x4 gg = *(const f32x4*)&g2[lane * 4];
  f32x4 be = *(const f32x4*)&be2[lane * 4];
#pragma unroll
  for (int rr = 0; rr < 4; rr++) {
    int row = blockIdx.x * 16 + wave * 4 + rr;
    u16x4 raw = *reinterpret_cast<const u16x4*>(x2b + (size_t)row * 256 + lane * 4);
    f32x4 v;
#pragma unroll
    for (int q2 = 0; q2 < 4; q2++) v[q2] = b2f(raw[q2]);
    float s1 = wredsum(v[0] + v[1] + v[2] + v[3]);
    float mean = s1 * 0.00390625f;
    f32x4 dv; float sq = 0.f;
#pragma unroll
    for (int q2 = 0; q2 < 4; q2++) { dv[q2] = v[q2] - mean; sq += dv[q2] * dv[q2]; }
    float s2 = wredsum(sq);
    float rstd = rsqrtf(s2 * 0.00390625f + 1e-6f);
    u16x4 ov;
#pragma unroll
    for (int q2 = 0; q2 < 4; q2++) ov[q2] = f2b(dv[q2] * rstd * gg[q2] + be[q2]);
    *reinterpret_cast<u16x4*>(ln2q + (size_t)row * 256 + lane * 4) = ov;
  }
}

// ====== K5G: mlp1 GEMM (M=18432,N=1024,K=256), 128x128 tile, dbuf LDS =========
__global__ __launch_bounds__(256) void k5g(
    const u16* W, const u16* ln2q, const float* mb1, u16* h1q) {
  __shared__ __align__(16) u16 Ab[2][4096];
  __shared__ __align__(16) u16 Bb[2][4096];
  int tid = threadIdx.x;
  int lane = tid & 63, wave = tid >> 6;
  int m = lane & 15, gq = lane >> 4;
  int wr = wave >> 1, wc = wave & 1;
  int bm = blockIdx.x * 128, bn = blockIdx.y * 128;
  const u16* Ag = ln2q + (size_t)bm * 256;
  const u16* Bg = W + WM1 + (size_t)bn * 256;
  f32x4 acc[4][4] = {};
#pragma unroll
  for (int c = 0; c < 2; c++) {
    int flat = (wave * 2 + c) * 512 + lane * 8;
    int r = flat >> 5, cc = flat & 31;
    GLL(Ag + (size_t)r * 256 + cc, &Ab[0][(wave * 2 + c) * 512]);
    GLL(Bg + (size_t)r * 256 + cc, &Bb[0][(wave * 2 + c) * 512]);
  }
  __syncthreads();
  int cur = 0;
  for (int ki = 0; ki < 8; ki++) {
    if (ki < 7) {
      int kk = (ki + 1) * 32;
#pragma unroll
      for (int c = 0; c < 2; c++) {
        int flat = (wave * 2 + c) * 512 + lane * 8;
        int r = flat >> 5, cc = flat & 31;
        GLL(Ag + (size_t)r * 256 + kk + cc, &Ab[cur ^ 1][(wave * 2 + c) * 512]);
        GLL(Bg + (size_t)r * 256 + kk + cc, &Bb[cur ^ 1][(wave * 2 + c) * 512]);
      }
    }
    short8 aF[4], bF[4];
#pragma unroll
    for (int mt = 0; mt < 4; mt++)
      aF[mt] = ld8(&Ab[cur][(wr * 64 + mt * 16 + m) * 32 + gq * 8]);
#pragma unroll
    for (int nt = 0; nt < 4; nt++)
      bF[nt] = ld8(&Bb[cur][(wc * 64 + nt * 16 + m) * 32 + gq * 8]);
#pragma unroll
    for (int mt = 0; mt < 4; mt++)
#pragma unroll
      for (int nt = 0; nt < 4; nt++)
        acc[mt][nt] = mfma16(aF[mt], bF[nt], acc[mt][nt]);
    __syncthreads();
    cur ^= 1;
  }
#pragma unroll
  for (int nt = 0; nt < 4; nt++) {
    int ch = bn + wc * 64 + nt * 16 + m;
    float bias = mb1[ch];
#pragma unroll
    for (int mt = 0; mt < 4; mt++)
#pragma unroll
      for (int rr = 0; rr < 4; rr++) {
        int tok = bm + wr * 64 + mt * 16 + gq * 4 + rr;
        float v = acc[mt][nt][rr] + bias;
        v = 0.5f * v * (1.f + erff(v * 0.7071067811865475f));
        h1q[(size_t)tok * 1024 + ch] = f2b(v);
      }
  }
}

// ====== K6G: mlp2 GEMM (M=18432,N=256,K=1024), 64x128 tile + NCHW out =========
__global__ __launch_bounds__(256) void k6g(
    const u16* W, const u16* h1q, const float* mb2, const u16* x2b,
    float* out, int tok_base) {
  __shared__ __align__(16) u16 Ab[2][2048];
  __shared__ __align__(16) u16 Bb[2][4096];
  __shared__ float ot[128 * 66];
  int tid = threadIdx.x;
  int lane = tid & 63, wave = tid >> 6;
  int m = lane & 15, gq = lane >> 4;
  int wr = wave >> 1, wc = wave & 1;
  int bm = blockIdx.x * 64, bn = blockIdx.y * 128;
  const u16* Ag = h1q + (size_t)bm * 1024;
  const u16* Bg = W + WM2 + (size_t)bn * 1024;
  f32x4 acc[2][4] = {};
  {
    int flatA = wave * 512 + lane * 8;
    GLL(Ag + (size_t)(flatA >> 5) * 1024 + (flatA & 31), &Ab[0][wave * 512]);
#pragma unroll
    for (int c = 0; c < 2; c++) {
      int flat = (wave * 2 + c) * 512 + lane * 8;
      GLL(Bg + (size_t)(flat >> 5) * 1024 + (flat & 31), &Bb[0][(wave * 2 + c) * 512]);
    }
  }
  __syncthreads();
  int cur = 0;
  for (int ki = 0; ki < 32; ki++) {
    if (ki < 31) {
      int kk = (ki + 1) * 32;
      int flatA = wave * 512 + lane * 8;
      GLL(Ag + (size_t)(flatA >> 5) * 1024 + kk + (flatA & 31), &Ab[cur ^ 1][wave * 512]);
#pragma unroll
      for (int c = 0; c < 2; c++) {
        int flat = (wave * 2 + c) * 512 + lane * 8;
        GLL(Bg + (size_t)(flat >> 5) * 1024 + kk + (flat & 31), &Bb[cur ^ 1][(wave * 2 + c) * 512]);
      }
    }
    short8 aF[2], bF[4];
#pragma unroll
    for (int mt = 0; mt < 2; mt++)
      aF[mt] = ld8(&Ab[cur][(wr * 32 + mt * 16 + m) * 32 + gq * 8]);
#pragma unroll
    for (int nt = 0; nt < 4; nt++)
      bF[nt] = ld8(&Bb[cur][(wc * 64 + nt * 16 + m) * 32 + gq * 8]);
#pragma unroll
    for (int mt = 0; mt < 2; mt++)
#pragma unroll
      for (int nt = 0; nt < 4; nt++)
        acc[mt][nt] = mfma16(aF[mt], bF[nt], acc[mt][nt]);
    __syncthreads();
    cur ^= 1;
  }
#pragma unroll
  for (int nt = 0; nt < 4; nt++) {
    int nl = wc * 64 + nt * 16 + m;
    int ch = bn + nl;
    float bias = mb2[ch];
#pragma unroll
    for (int mt = 0; mt < 2; mt++)
#pragma unroll
      for (int rr = 0; rr < 4; rr++) {
        int tl = wr * 32 + mt * 16 + gq * 4 + rr;
        float v = acc[mt][nt][rr] + bias + b2f(x2b[(size_t)(bm + tl) * 256 + ch]);
        ot[nl * 66 + tl] = v;
      }
  }
  __syncthreads();
  int tg = tok_base + bm;
  int bimg = tg / 9216, hw0 = tg % 9216;
  for (int it = 0; it < 32; it++) {
    int flat = it * 256 + tid;
    int j = flat >> 6, t = flat & 63;
    out[((size_t)bimg * 256 + bn + j) * 9216 + hw0 + t] = ot[j * 66 + t];
  }
}

extern "C" void kernel_launch(void* const* d_in, const int* in_sizes, int n_in,
                              void* d_out, int out_size, void* d_ws, size_t ws_size,
                              hipStream_t stream) {
  const float* x      = (const float*)d_in[0];
  const float* skipf  = (const float*)d_in[1];
  const float* up_w   = (const float*)d_in[2];
  const float* up_b   = (const float*)d_in[3];
  const float* skip_w = (const float*)d_in[4];
  const float* g1     = (const float*)d_in[5];
  const float* be1    = (const float*)d_in[6];
  const float* qkv_w  = (const float*)d_in[7];
  const float* qkv_b  = (const float*)d_in[8];
  const float* rpb    = (const float*)d_in[9];
  const float* proj_w = (const float*)d_in[10];
  const float* proj_b = (const float*)d_in[11];
  const float* g2     = (const float*)d_in[12];
  const float* be2    = (const float*)d_in[13];
  const float* m_w1   = (const float*)d_in[14];
  const float* m_b1   = (const float*)d_in[15];
  const float* m_w2   = (const float*)d_in[16];
  const float* m_b2   = (const float*)d_in[17];
  if (ws_size < WS_NEED) {
    k_sentinel<<<1, 256, 0, stream>>>((float*)d_out);
    return;
  }
  char* ws = (char*)d_ws;
  u16*   W    = (u16*)ws;
  float* bias = (float*)(ws + OFF_BIAS);
  u16*   sc   = (u16*)(ws + OFF_SC);
  u16*   xt   = (u16*)(ws + OFF_OVR);
  u16*   skt  = (u16*)(ws + OFF_OVR);
  u16*   qc   = (u16*)(ws + OFF_OVR);
  u16*   kc   = (u16*)(ws + OFF_OVR + 9834496u);
  u16*   vtc  = (u16*)(ws + OFF_OVR + 19668992u);
  u16*   ln2q = (u16*)(ws + OFF_OVR);
  u16*   h1q  = (u16*)(ws + OFF_OVR + 9437184u);
  u16*   win  = (u16*)d_out;

  k_prep<<<5504, 256, 0, stream>>>(qkv_w, proj_w, m_w1, m_w2, skip_w, up_w, rpb, W, bias);
  k_tr<<<dim3(72, 16, 8), 256, 0, stream>>>(x, xt, 512, 2304);
  k1_conv<<<dim3(768, 2), 256, 0, stream>>>(W, xt, up_b, sc);
  k_tr_skip<<<dim3(3, 8, 768), 256, 0, stream>>>(skipf, skt);
  k2a<<<dim3(301, 8), 256, 0, stream>>>(W, sc, skt, g1, be1, win);
  for (int c = 0; c < 4; c++) {
    k2b<<<dim3(151, 6), 256, 0, stream>>>(W, win, qkv_b, qc, kc, vtc, c);
    u16* obc = (u16*)((char*)d_out + 36159488u + (size_t)(3 - c) * 9834496u);
    k3_attn<<<784, 256, 0, stream>>>(qc, kc, vtc, bias, obc);
  }
  k4w<<<dim3(151, 2, 4), 256, 0, stream>>>(W, (const char*)d_out, proj_b, sc);
  for (int q = 0; q < 4; q++) {
    const u16* x2b = sc + (size_t)q * 18432 * 256;
    k_ln2<<<1152, 256, 0, stream>>>(x2b, g2, be2, ln2q);
    k5g<<<dim3(144, 8), 256, 0, stream>>>(W, ln2q, m_b1, h1q);
    k6g<<<dim3(288, 2), 256, 0, stream>>>(W, h1q, m_b2, x2b, (float*)d_out, q * 18432);
  }
}

// Round 8
// 735.233 us; speedup vs baseline: 1.8626x; 1.0450x over previous
//
#include <hip/hip_runtime.h>

typedef __attribute__((ext_vector_type(8))) short short8;
typedef __attribute__((ext_vector_type(4))) float f32x4;
typedef __attribute__((ext_vector_type(4))) unsigned short u16x4;
typedef unsigned short u16;
typedef unsigned int u32;

#define DEV static __device__ __forceinline__

DEV u16 f2b(float f) {
  u32 u = __builtin_bit_cast(u32, f);
  return (u16)((u + 0x7fffu + ((u >> 16) & 1u)) >> 16);
}
DEV float b2f(u16 h) {
  u32 u = ((u32)h) << 16;
  return __builtin_bit_cast(float, u);
}
DEV short8 ld8(const u16* p) { return *reinterpret_cast<const short8*>(p); }
DEV f32x4 mfma16(short8 a, short8 b, f32x4 c) {
  return __builtin_amdgcn_mfma_f32_16x16x32_bf16(a, b, c, 0, 0, 0);
}
DEV float wredsum(float v) {
#pragma unroll
  for (int off = 1; off < 64; off <<= 1) v += __shfl_xor(v, off);
  return v;
}

#define GLL(gp, lp) __builtin_amdgcn_global_load_lds( \
    (const __attribute__((address_space(1))) void*)(gp), \
    (__attribute__((address_space(3))) void*)(lp), 16, 0, 0)

// ---- weight arena (u16 element offsets) ----
#define WQKV   0         // [768][256]
#define WPROJ  196608    // [256][256]
#define WM1    262144    // [1024][256]  (pre-scaled by gamma2)
#define WM2    524288    // [256][1024]
#define WSKIP  786432    // [256][256]
#define WUP    851968    // [4][256][512]  kk = kh*2+kw

// ---- ws byte offsets ----
#define OFF_BIAS 2752512u
#define OFF_SC   2883584u     // bf16 sc: conv shortcut -> x2 [73728][256]
#define OFF_OVR  40632320u    // 55,595,008B overlay:
// phase A: xt @OVR (18,874,368)  [dead after k1]
// phase B: skt @OVR (37,748,736) [dead after k2a]
// phase C (per 2-img chunk): qc @OVR; kc @+9,834,496; vtc @+19,668,992
// phase D: h1q @OVR (37,748,736)
// persistent: stats @OVR+52,000,000 (589,824); SgSb @OVR+54,000,000 (8,192)
#define OFF_STAT (OFF_OVR + 52000000u)
#define OFF_SGB  (OFF_OVR + 54000000u)
// d_out scratch: win u16 @0 (39,337,984); ob_c u16 @36,159,488+(3-c)*9,834,496
#define WS_NEED  96227328u

__global__ void k_sentinel(float* out) { out[threadIdx.x] = 31337.0f; }

// ================= prep: weights -> bf16, up_w transpose, bias table, Sg/Sb ===
__global__ __launch_bounds__(256) void k_prep(
    const float* qkv_w, const float* proj_w, const float* mlp_w1,
    const float* mlp_w2, const float* skip_w, const float* up_w,
    const float* rpb, const float* g2, const float* be2,
    u16* W, float* bias_g, float* sgb) {
  int i = blockIdx.x * 256 + threadIdx.x;
  if (i < 196608) { W[WQKV + i] = f2b(qkv_w[i]); return; }
  i -= 196608;
  if (i < 65536) { W[WPROJ + i] = f2b(proj_w[i]); return; }
  i -= 65536;
  if (i < 262144) { W[WM1 + i] = f2b(mlp_w1[i] * g2[i & 255]); return; }
  i -= 262144;
  if (i < 262144) { W[WM2 + i] = f2b(mlp_w2[i]); return; }
  i -= 262144;
  if (i < 65536) { W[WSKIP + i] = f2b(skip_w[i]); return; }
  i -= 65536;
  if (i < 524288) {
    int ci = i & 511; int rest = i >> 9; int co = rest & 255; int kk = rest >> 8;
    W[WUP + i] = f2b(up_w[ci * 1024 + co * 4 + kk]);
    return;
  }
  i -= 524288;
  if (i < 32768) {
    int h = i >> 12, r = i & 4095, ii = r >> 6, j = r & 63;
    float v;
    if (j >= 49) v = -1e30f;
    else if (ii >= 49) v = 0.f;
    else {
      int d0 = (ii / 7 - j / 7) + 6, d1 = (ii % 7 - j % 7) + 6;
      v = rpb[(d0 * 13 + d1) * 8 + h];
    }
    bias_g[i] = v;
    return;
  }
  i -= 32768;
  if (i < 1024) {  // Sg[c] = sum_k g2[k]*W1[c][k]
    float s = 0.f;
    for (int k = 0; k < 256; k++) s += g2[k] * mlp_w1[i * 256 + k];
    sgb[i] = s;
    return;
  }
  i -= 1024;
  if (i < 1024) {  // Sb[c] = sum_k be2[k]*W1[c][k]
    float s = 0.f;
    for (int k = 0; k < 256; k++) s += be2[k] * mlp_w1[i * 256 + k];
    sgb[1024 + i] = s;
  }
}

// ============== NCHW f32 -> NHWC bf16 tiled transpose (for x) =================
__global__ __launch_bounds__(256) void k_tr(const float* src, u16* dst, int C, int HW) {
  __shared__ float t[32][33];
  int hw0 = blockIdx.x * 32, c0 = blockIdx.y * 32, b = blockIdx.z;
  int tx = threadIdx.x & 31, ty = threadIdx.x >> 5;
  const float* s = src + (size_t)b * C * HW;
  u16* d = dst + (size_t)b * C * HW;
#pragma unroll
  for (int i = 0; i < 4; i++)
    t[ty + i * 8][tx] = s[(size_t)(c0 + ty + i * 8) * HW + hw0 + tx];
  __syncthreads();
#pragma unroll
  for (int i = 0; i < 4; i++)
    d[(size_t)(hw0 + ty + i * 8) * C + c0 + tx] = f2b(t[tx][ty + i * 8]);
}

// ===== batched skip transpose: skip[b][c][h][w] -> skt[b][h][w][c] (bf16) =====
__global__ __launch_bounds__(256) void k_tr_skip(const float* src, u16* dst) {
  __shared__ float t[32][33];
  int w0 = blockIdx.x * 32, c0 = blockIdx.y * 32;
  int z = blockIdx.z;
  int b = z / 96, h = z - b * 96;
  int tx = threadIdx.x & 31, ty = threadIdx.x >> 5;
  const float* s = src + (size_t)b * 256 * 9216 + (size_t)h * 96;
  u16* d = dst + (((size_t)b * 96 + h) * 96) * 256;
#pragma unroll
  for (int i = 0; i < 4; i++)
    t[ty + i * 8][tx] = s[(size_t)(c0 + ty + i * 8) * 9216 + w0 + tx];
  __syncthreads();
#pragma unroll
  for (int i = 0; i < 4; i++)
    d[(size_t)(w0 + ty + i * 8) * 256 + c0 + tx] = f2b(t[tx][ty + i * 8]);
}

// ====== K1G: convT as GEMM (M=18432,N=256,K=512) x4 parities, dbuf gll ========
__global__ __launch_bounds__(256) void k1g(
    const u16* W, const u16* xt, const float* up_b, u16* sc) {
  __shared__ __align__(16) u16 Ab[2][4096];
  __shared__ __align__(16) u16 Bb[2][4096];
  int tid = threadIdx.x;
  int lane = tid & 63, wave = tid >> 6;
  int m = lane & 15, gq = lane >> 4;
  int wr = wave >> 1, wc = wave & 1;
  int bm = blockIdx.x * 128, bn = blockIdx.y * 128;
  int kk = blockIdx.z, kh = kk >> 1, kw = kk & 1;
  const u16* Ag = xt + (size_t)bm * 512;
  const u16* Bg = W + WUP + (size_t)kk * 131072 + (size_t)bn * 512;
  f32x4 acc[4][4] = {};
#pragma unroll
  for (int c = 0; c < 2; c++) {
    int flat = (wave * 2 + c) * 512 + lane * 8;
    int r = flat >> 5, cc = flat & 31;
    GLL(Ag + (size_t)r * 512 + cc, &Ab[0][(wave * 2 + c) * 512]);
    GLL(Bg + (size_t)r * 512 + cc, &Bb[0][(wave * 2 + c) * 512]);
  }
  __syncthreads();
  int cur = 0;
  for (int ki = 0; ki < 16; ki++) {
    if (ki < 15) {
      int kkk = (ki + 1) * 32;
#pragma unroll
      for (int c = 0; c < 2; c++) {
        int flat = (wave * 2 + c) * 512 + lane * 8;
        int r = flat >> 5, cc = flat & 31;
        GLL(Ag + (size_t)r * 512 + kkk + cc, &Ab[cur ^ 1][(wave * 2 + c) * 512]);
        GLL(Bg + (size_t)r * 512 + kkk + cc, &Bb[cur ^ 1][(wave * 2 + c) * 512]);
      }
    }
    short8 aF[4], bF[4];
#pragma unroll
    for (int mt = 0; mt < 4; mt++)
      aF[mt] = ld8(&Ab[cur][(wr * 64 + mt * 16 + m) * 32 + gq * 8]);
#pragma unroll
    for (int nt = 0; nt < 4; nt++)
      bF[nt] = ld8(&Bb[cur][(wc * 64 + nt * 16 + m) * 32 + gq * 8]);
#pragma unroll
    for (int mt = 0; mt < 4; mt++)
#pragma unroll
      for (int nt = 0; nt < 4; nt++)
        acc[mt][nt] = mfma16(aF[mt], bF[nt], acc[mt][nt]);
    __syncthreads();
    cur ^= 1;
  }
  float ub[4];
#pragma unroll
  for (int nt = 0; nt < 4; nt++) ub[nt] = up_b[bn + wc * 64 + nt * 16 + m];
#pragma unroll
  for (int mt = 0; mt < 4; mt++)
#pragma unroll
    for (int rr = 0; rr < 4; rr++) {
      int t = bm + wr * 64 + mt * 16 + gq * 4 + rr;
      int b = t / 2304, rem = t - b * 2304;
      int ih = rem / 48, iw = rem - ih * 48;
      int h = 2 * ih + kh, w = 2 * iw + kw;
      size_t tok = ((size_t)b * 96 + h) * 96 + w;
#pragma unroll
      for (int nt = 0; nt < 4; nt++) {
        int ch = bn + wc * 64 + nt * 16 + m;
        sc[tok * 256 + ch] = f2b(acc[mt][nt][rr] + ub[nt]);
      }
    }
}

// ============== K2A: gather + skip 1x1 GEMM + LN1 -> win (d_out scratch) ======
__global__ __launch_bounds__(256) void k2a(
    const u16* W, const u16* sc, const u16* skt, const float* g1,
    const float* be1, u16* win) {
  __shared__ __align__(16) u16 cv[32 * 264];
  __shared__ __align__(16) u16 sk[32 * 264];
  int tid = threadIdx.x;
  int lane = tid & 63, wave = tid >> 6;
  int m = lane & 15, gq = lane >> 4, k0 = gq * 8;
  int y = blockIdx.y;
  int tok0 = blockIdx.x * 32;
  const u16* scb = sc + (size_t)y * 2359296;
  const u16* skb = skt + (size_t)y * 2359296;
#pragma unroll
  for (int it = 0; it < 4; it++) {
    int flat = it * 2048 + tid * 8;
    int row = flat >> 8, col = flat & 255;
    int g = tok0 + row;
    int w_ = g / 49, i = g - w_ * 49;
    int wrow = w_ / 14, wcol = w_ - wrow * 14;
    int hh = wrow * 7 + i / 7, ww = wcol * 7 + i % 7;
    bool valid = (g < 9604) && (hh < 96) && (ww < 96);
    short8 vc = {}, vs = {};
    if (valid) {
      size_t base = ((size_t)hh * 96 + ww) * 256 + col;
      vc = ld8(scb + base);
      vs = ld8(skb + base);
    }
    *reinterpret_cast<short8*>(&cv[row * 264 + col]) = vc;
    *reinterpret_cast<short8*>(&sk[row * 264 + col]) = vs;
  }
  __syncthreads();
  int cb = wave * 64;
  f32x4 acc[2][4] = {};
#pragma unroll 4
  for (int ks = 0; ks < 8; ks++) {
    short8 a0 = ld8(&sk[m * 264 + ks * 32 + k0]);
    short8 a1 = ld8(&sk[(16 + m) * 264 + ks * 32 + k0]);
#pragma unroll
    for (int nt = 0; nt < 4; nt++) {
      short8 bb = ld8(W + WSKIP + (size_t)(cb + nt * 16 + m) * 256 + ks * 32 + k0);
      acc[0][nt] = mfma16(a0, bb, acc[0][nt]);
      acc[1][nt] = mfma16(a1, bb, acc[1][nt]);
    }
  }
  __syncthreads();
#pragma unroll
  for (int mt = 0; mt < 2; mt++)
#pragma unroll
    for (int nt = 0; nt < 4; nt++) {
      int c = cb + nt * 16 + m;
#pragma unroll
      for (int rr = 0; rr < 4; rr++) {
        int row = mt * 16 + gq * 4 + rr;
        float yv = acc[mt][nt][rr] + b2f(cv[row * 264 + c]);
        sk[row * 264 + c] = f2b(yv);
      }
    }
  __syncthreads();
  f32x4 gg = *(const f32x4*)&g1[lane * 4];
  f32x4 be = *(const f32x4*)&be1[lane * 4];
  for (int tt = 0; tt < 8; tt++) {
    int row = wave * 8 + tt;
    int g = tok0 + row;
    if (g >= 9604) continue;
    int w_ = g / 49, i = g - w_ * 49;
    int wrow = w_ / 14, wcol = w_ - wrow * 14;
    int hh = wrow * 7 + i / 7, ww = wcol * 7 + i % 7;
    u16x4 ov = {};
    if (hh < 96 && ww < 96) {
      u16x4 raw = *(const u16x4*)&sk[row * 264 + lane * 4];
      f32x4 v;
#pragma unroll
      for (int q2 = 0; q2 < 4; q2++) v[q2] = b2f(raw[q2]);
      float s1 = wredsum(v[0] + v[1] + v[2] + v[3]);
      float mean = s1 * 0.00390625f;
      f32x4 dv; float sq = 0.f;
#pragma unroll
      for (int q2 = 0; q2 < 4; q2++) { dv[q2] = v[q2] - mean; sq += dv[q2] * dv[q2]; }
      float s2 = wredsum(sq);
      float rstd = rsqrtf(s2 * 0.00390625f + 1e-6f);
#pragma unroll
      for (int q2 = 0; q2 < 4; q2++) ov[q2] = f2b(dv[q2] * rstd * gg[q2] + be[q2]);
    }
    *reinterpret_cast<u16x4*>(win + ((size_t)y * 9604 + g) * 256 + lane * 4) = ov;
  }
}

// ====== K2B: qkv GEMM 128x128 dbuf (per 2-image chunk, M=19208) ===============
__global__ __launch_bounds__(256) void k2b(
    const u16* W, const u16* win, const float* qkv_b,
    u16* qc, u16* kc, u16* vtc, int chunk) {
  __shared__ __align__(16) u16 Ab[2][4096];
  __shared__ __align__(16) u16 Bb[2][4096];
  int tid = threadIdx.x;
  int lane = tid & 63, wave = tid >> 6;
  int m = lane & 15, gq = lane >> 4;
  int wr = wave >> 1, wc = wave & 1;
  int bm = blockIdx.x * 128, bn = blockIdx.y * 128;
  const u16* Ag = win + (size_t)(chunk * 19208 + bm) * 256;
  const u16* Bg = W + WQKV + (size_t)bn * 256;
  f32x4 acc[4][4] = {};
#pragma unroll
  for (int c = 0; c < 2; c++) {
    int flat = (wave * 2 + c) * 512 + lane * 8;
    int r = flat >> 5, cc = flat & 31;
    GLL(Ag + (size_t)r * 256 + cc, &Ab[0][(wave * 2 + c) * 512]);
    GLL(Bg + (size_t)r * 256 + cc, &Bb[0][(wave * 2 + c) * 512]);
  }
  __syncthreads();
  int cur = 0;
  for (int ki = 0; ki < 8; ki++) {
    if (ki < 7) {
      int kk = (ki + 1) * 32;
#pragma unroll
      for (int c = 0; c < 2; c++) {
        int flat = (wave * 2 + c) * 512 + lane * 8;
        int r = flat >> 5, cc = flat & 31;
        GLL(Ag + (size_t)r * 256 + kk + cc, &Ab[cur ^ 1][(wave * 2 + c) * 512]);
        GLL(Bg + (size_t)r * 256 + kk + cc, &Bb[cur ^ 1][(wave * 2 + c) * 512]);
      }
    }
    short8 aF[4], bF[4];
#pragma unroll
    for (int mt = 0; mt < 4; mt++)
      aF[mt] = ld8(&Ab[cur][(wr * 64 + mt * 16 + m) * 32 + gq * 8]);
#pragma unroll
    for (int nt = 0; nt < 4; nt++)
      bF[nt] = ld8(&Bb[cur][(wc * 64 + nt * 16 + m) * 32 + gq * 8]);
#pragma unroll
    for (int mt = 0; mt < 4; mt++)
#pragma unroll
      for (int nt = 0; nt < 4; nt++)
        acc[mt][nt] = mfma16(aF[mt], bF[nt], acc[mt][nt]);
    __syncthreads();
    cur ^= 1;
  }
  int typev[4], hdv[4], bhoff[4];
  float qbv[4];
#pragma unroll
  for (int nt = 0; nt < 4; nt++) {
    int ch = bn + wc * 64 + nt * 16 + m;
    qbv[nt] = qkv_b[ch];
    typev[nt] = ch >> 8;
    hdv[nt] = ch & 31;
    bhoff[nt] = (ch >> 5) & 7;
  }
#pragma unroll
  for (int mt = 0; mt < 4; mt++)
#pragma unroll
    for (int rr = 0; rr < 4; rr++) {
      int t = bm + wr * 64 + mt * 16 + gq * 4 + rr;
      if (t >= 19208) continue;
      int bloc = t / 49, i = t - bloc * 49;
#pragma unroll
      for (int nt = 0; nt < 4; nt++) {
        float v = acc[mt][nt][rr] + qbv[nt];
        size_t bh = (size_t)bloc * 8 + bhoff[nt];
        u16 val = f2b(v);
        if (typev[nt] == 0) qc[bh * 1568 + i * 32 + hdv[nt]] = val;
        else if (typev[nt] == 1) kc[bh * 1568 + i * 32 + hdv[nt]] = val;
        else vtc[bh * 2048 + hdv[nt] * 64 + i] = val;
      }
    }
}

// ============== K3: window attention, one wave per (window, head) =============
__global__ __launch_bounds__(256) void k3_attn(
    const u16* qc, const u16* kc, const u16* vtc, const float* bias_g, u16* obb) {
  __shared__ u16 plds[4][64 * 64];
  int lane = threadIdx.x & 63, wave = threadIdx.x >> 6;
  int b_ = blockIdx.x >> 1;
  int h = (blockIdx.x & 1) * 4 + wave;
  int m = lane & 15, gq = lane >> 4, k0 = gq * 8;
  size_t bh = (size_t)b_ * 8 + h;
  const u16* Q = qc + bh * 1568;
  const u16* K = kc + bh * 1568;
  const u16* V = vtc + bh * 2048;
  const float* BI = bias_g + h * 4096;
  short8 aq[4], bk[4];
#pragma unroll
  for (int mt = 0; mt < 4; mt++) { int i = mt * 16 + m; if (i > 48) i = 48; aq[mt] = ld8(Q + i * 32 + k0); }
#pragma unroll
  for (int nt = 0; nt < 4; nt++) { int j = nt * 16 + m; if (j > 48) j = 48; bk[nt] = ld8(K + j * 32 + k0); }
  f32x4 s[4][4] = {};
#pragma unroll
  for (int mt = 0; mt < 4; mt++)
#pragma unroll
    for (int nt = 0; nt < 4; nt++)
      s[mt][nt] = mfma16(aq[mt], bk[nt], s[mt][nt]);
  const float scale = 0.1767766952966369f;  // 1/sqrt(32)
  float rsum[4][4];
#pragma unroll
  for (int mt = 0; mt < 4; mt++)
#pragma unroll
    for (int rr = 0; rr < 4; rr++) {
      int i = mt * 16 + gq * 4 + rr;
      float sv[4];
      float mx = -1e38f;
#pragma unroll
      for (int nt = 0; nt < 4; nt++) {
        sv[nt] = s[mt][nt][rr] * scale + BI[i * 64 + nt * 16 + m];
        mx = fmaxf(mx, sv[nt]);
      }
      mx = fmaxf(mx, __shfl_xor(mx, 1));
      mx = fmaxf(mx, __shfl_xor(mx, 2));
      mx = fmaxf(mx, __shfl_xor(mx, 4));
      mx = fmaxf(mx, __shfl_xor(mx, 8));
      float sum = 0.f;
#pragma unroll
      for (int nt = 0; nt < 4; nt++) { sv[nt] = __expf(sv[nt] - mx); sum += sv[nt]; }
      sum += __shfl_xor(sum, 1);
      sum += __shfl_xor(sum, 2);
      sum += __shfl_xor(sum, 4);
      sum += __shfl_xor(sum, 8);
      rsum[mt][rr] = sum;
      int isw = (i & 7) * 8;
#pragma unroll
      for (int nt = 0; nt < 4; nt++) {
        int j = nt * 16 + m;
        plds[wave][i * 64 + (j ^ isw)] = f2b(sv[nt]);
      }
    }
  __syncthreads();
  f32x4 o[4][2] = {};
#pragma unroll
  for (int ks = 0; ks < 2; ks++) {
    short8 bv[2];
#pragma unroll
    for (int nt = 0; nt < 2; nt++)
      bv[nt] = ld8(V + (size_t)(nt * 16 + m) * 64 + ks * 32 + k0);
#pragma unroll
    for (int mt = 0; mt < 4; mt++) {
      int i = mt * 16 + m;
      short8 ap = *reinterpret_cast<const short8*>(
          &plds[wave][i * 64 + ((ks * 32 + k0) ^ ((i & 7) * 8))]);
#pragma unroll
      for (int nt = 0; nt < 2; nt++)
        o[mt][nt] = mfma16(ap, bv[nt], o[mt][nt]);
    }
  }
#pragma unroll
  for (int mt = 0; mt < 4; mt++)
#pragma unroll
    for (int rr = 0; rr < 4; rr++) {
      int i = mt * 16 + gq * 4 + rr;
      if (i >= 49) continue;
      float rinv = 1.f / rsum[mt][rr];
#pragma unroll
      for (int nt = 0; nt < 2; nt++) {
        int c = h * 32 + nt * 16 + m;
        obb[((size_t)b_ * 49 + i) * 256 + c] = f2b(o[mt][nt][rr] * rinv);
      }
    }
}

// ====== K4W: proj GEMM 128x128 dbuf + shortcut -> x2 (grid (151,2,4)) =========
__global__ __launch_bounds__(256) void k4w(
    const u16* W, const char* dout, const float* proj_b, u16* sc) {
  __shared__ __align__(16) u16 Ab[2][4096];
  __shared__ __align__(16) u16 Bb[2][4096];
  int tid = threadIdx.x;
  int lane = tid & 63, wave = tid >> 6;
  int m = lane & 15, gq = lane >> 4;
  int wr = wave >> 1, wc = wave & 1;
  int bm = blockIdx.x * 128, bn = blockIdx.y * 128;
  int z = blockIdx.z;
  const u16* Ag = (const u16*)(dout + 36159488u + (size_t)(3 - z) * 9834496u);
  const u16* Bg = W + WPROJ + (size_t)bn * 256;
  f32x4 acc[4][4] = {};
#pragma unroll
  for (int c = 0; c < 2; c++) {
    int flat = (wave * 2 + c) * 512 + lane * 8;
    int r = flat >> 5, cc = flat & 31;
    int rg = bm + r; if (rg > 19207) rg = 19207;
    GLL(Ag + (size_t)rg * 256 + cc, &Ab[0][(wave * 2 + c) * 512]);
    GLL(Bg + (size_t)r * 256 + cc, &Bb[0][(wave * 2 + c) * 512]);
  }
  __syncthreads();
  int cur = 0;
  for (int ki = 0; ki < 8; ki++) {
    if (ki < 7) {
      int kk = (ki + 1) * 32;
#pragma unroll
      for (int c = 0; c < 2; c++) {
        int flat = (wave * 2 + c) * 512 + lane * 8;
        int r = flat >> 5, cc = flat & 31;
        int rg = bm + r; if (rg > 19207) rg = 19207;
        GLL(Ag + (size_t)rg * 256 + kk + cc, &Ab[cur ^ 1][(wave * 2 + c) * 512]);
        GLL(Bg + (size_t)r * 256 + kk + cc, &Bb[cur ^ 1][(wave * 2 + c) * 512]);
      }
    }
    short8 aF[4], bF[4];
#pragma unroll
    for (int mt = 0; mt < 4; mt++)
      aF[mt] = ld8(&Ab[cur][(wr * 64 + mt * 16 + m) * 32 + gq * 8]);
#pragma unroll
    for (int nt = 0; nt < 4; nt++)
      bF[nt] = ld8(&Bb[cur][(wc * 64 + nt * 16 + m) * 32 + gq * 8]);
#pragma unroll
    for (int mt = 0; mt < 4; mt++)
#pragma unroll
      for (int nt = 0; nt < 4; nt++)
        acc[mt][nt] = mfma16(aF[mt], bF[nt], acc[mt][nt]);
    __syncthreads();
    cur ^= 1;
  }
#pragma unroll
  for (int mt = 0; mt < 4; mt++)
#pragma unroll
    for (int rr = 0; rr < 4; rr++) {
      int t = bm + wr * 64 + mt * 16 + gq * 4 + rr;
      if (t >= 19208) continue;
      int bloc = t / 49, i = t - bloc * 49;
      int b_ = z * 392 + bloc;
      int img = b_ / 196, wl = b_ - img * 196;
      int wrow = wl / 14, wcol = wl - wrow * 14;
      int hh = wrow * 7 + i / 7, ww = wcol * 7 + i % 7;
      if (hh >= 96 || ww >= 96) continue;
      size_t tok = ((size_t)img * 96 + hh) * 96 + ww;
#pragma unroll
      for (int nt = 0; nt < 4; nt++) {
        int ch = bn + wc * 64 + nt * 16 + m;
        float v = acc[mt][nt][rr] + proj_b[ch] + b2f(sc[tok * 256 + ch]);
        sc[tok * 256 + ch] = f2b(v);
      }
    }
}

// ============== K_STATS: per-token mean/rstd of x2 (full 73728 rows) ==========
__global__ __launch_bounds__(256) void k_stats(const u16* x2, float* stat) {
  int tid = threadIdx.x, lane = tid & 63, wave = tid >> 6;
#pragma unroll
  for (int rr = 0; rr < 4; rr++) {
    int row = blockIdx.x * 16 + wave * 4 + rr;
    u16x4 raw = *reinterpret_cast<const u16x4*>(x2 + (size_t)row * 256 + lane * 4);
    f32x4 v;
#pragma unroll
    for (int q2 = 0; q2 < 4; q2++) v[q2] = b2f(raw[q2]);
    float s1 = wredsum(v[0] + v[1] + v[2] + v[3]);
    float mean = s1 * 0.00390625f;
    float sq = 0.f;
#pragma unroll
    for (int q2 = 0; q2 < 4; q2++) { float d = v[q2] - mean; sq += d * d; }
    float s2 = wredsum(sq);
    float rstd = rsqrtf(s2 * 0.00390625f + 1e-6f);
    if (lane == 0) {
      stat[row * 2] = mean;
      stat[row * 2 + 1] = rstd;
    }
  }
}

// ====== K5F: mlp1 GEMM on raw x2 + LN2 fold + GELU (M=18432,N=1024,K=256) =====
__global__ __launch_bounds__(256) void k5f(
    const u16* W, const u16* x2b, const float* stat, const float* sgb,
    const float* mb1, u16* h1q) {
  __shared__ __align__(16) u16 Ab[2][4096];
  __shared__ __align__(16) u16 Bb[2][4096];
  int tid = threadIdx.x;
  int lane = tid & 63, wave = tid >> 6;
  int m = lane & 15, gq = lane >> 4;
  int wr = wave >> 1, wc = wave & 1;
  int bm = blockIdx.x * 128, bn = blockIdx.y * 128;
  const u16* Ag = x2b + (size_t)bm * 256;
  const u16* Bg = W + WM1 + (size_t)bn * 256;
  f32x4 acc[4][4] = {};
#pragma unroll
  for (int c = 0; c < 2; c++) {
    int flat = (wave * 2 + c) * 512 + lane * 8;
    int r = flat >> 5, cc = flat & 31;
    GLL(Ag + (size_t)r * 256 + cc, &Ab[0][(wave * 2 + c) * 512]);
    GLL(Bg + (size_t)r * 256 + cc, &Bb[0][(wave * 2 + c) * 512]);
  }
  __syncthreads();
  int cur = 0;
  for (int ki = 0; ki < 8; ki++) {
    if (ki < 7) {
      int kk = (ki + 1) * 32;
#pragma unroll
      for (int c = 0; c < 2; c++) {
        int flat = (wave * 2 + c) * 512 + lane * 8;
        int r = flat >> 5, cc = flat & 31;
        GLL(Ag + (size_t)r * 256 + kk + cc, &Ab[cur ^ 1][(wave * 2 + c) * 512]);
        GLL(Bg + (size_t)r * 256 + kk + cc, &Bb[cur ^ 1][(wave * 2 + c) * 512]);
      }
    }
    short8 aF[4], bF[4];
#pragma unroll
    for (int mt = 0; mt < 4; mt++)
      aF[mt] = ld8(&Ab[cur][(wr * 64 + mt * 16 + m) * 32 + gq * 8]);
#pragma unroll
    for (int nt = 0; nt < 4; nt++)
      bF[nt] = ld8(&Bb[cur][(wc * 64 + nt * 16 + m) * 32 + gq * 8]);
#pragma unroll
    for (int mt = 0; mt < 4; mt++)
#pragma unroll
      for (int nt = 0; nt < 4; nt++)
        acc[mt][nt] = mfma16(aF[mt], bF[nt], acc[mt][nt]);
    __syncthreads();
    cur ^= 1;
  }
  float sgv[4], sbv[4], b1v[4];
#pragma unroll
  for (int nt = 0; nt < 4; nt++) {
    int ch = bn + wc * 64 + nt * 16 + m;
    sgv[nt] = sgb[ch];
    sbv[nt] = sgb[1024 + ch];
    b1v[nt] = mb1[ch];
  }
#pragma unroll
  for (int mt = 0; mt < 4; mt++)
#pragma unroll
    for (int rr = 0; rr < 4; rr++) {
      int tok = bm + wr * 64 + mt * 16 + gq * 4 + rr;
      float mu = stat[tok * 2], r = stat[tok * 2 + 1];
#pragma unroll
      for (int nt = 0; nt < 4; nt++) {
        float v = r * acc[mt][nt][rr] - r * mu * sgv[nt] + sbv[nt] + b1v[nt];
        v = 0.5f * v * (1.f + erff(v * 0.7071067811865475f));
        h1q[(size_t)tok * 1024 + (bn + wc * 64 + nt * 16 + m)] = f2b(v);
      }
    }
}

// ====== K6G: mlp2 GEMM (M=18432,N=256,K=1024), 64x128 tile + NCHW out =========
__global__ __launch_bounds__(256) void k6g(
    const u16* W, const u16* h1q, const float* mb2, const u16* x2b,
    float* out, int tok_base) {
  __shared__ __align__(16) u16 Ab[2][2048];
  __shared__ __align__(16) u16 Bb[2][4096];
  __shared__ float ot[128 * 66];
  int tid = threadIdx.x;
  int lane = tid & 63, wave = tid >> 6;
  int m = lane & 15, gq = lane >> 4;
  int wr = wave >> 1, wc = wave & 1;
  int bm = blockIdx.x * 64, bn = blockIdx.y * 128;
  const u16* Ag = h1q + (size_t)bm * 1024;
  const u16* Bg = W + WM2 + (size_t)bn * 1024;
  f32x4 acc[2][4] = {};
  {
    int flatA = wave * 512 + lane * 8;
    GLL(Ag + (size_t)(flatA >> 5) * 1024 + (flatA & 31), &Ab[0][wave * 512]);
#pragma unroll
    for (int c = 0; c < 2; c++) {
      int flat = (wave * 2 + c) * 512 + lane * 8;
      GLL(Bg + (size_t)(flat >> 5) * 1024 + (flat & 31), &Bb[0][(wave * 2 + c) * 512]);
    }
  }
  __syncthreads();
  int cur = 0;
  for (int ki = 0; ki < 32; ki++) {
    if (ki < 31) {
      int kk = (ki + 1) * 32;
      int flatA = wave * 512 + lane * 8;
      GLL(Ag + (size_t)(flatA >> 5) * 1024 + kk + (flatA & 31), &Ab[cur ^ 1][wave * 512]);
#pragma unroll
      for (int c = 0; c < 2; c++) {
        int flat = (wave * 2 + c) * 512 + lane * 8;
        GLL(Bg + (size_t)(flat >> 5) * 1024 + kk + (flat & 31), &Bb[cur ^ 1][(wave * 2 + c) * 512]);
      }
    }
    short8 aF[2], bF[4];
#pragma unroll
    for (int mt = 0; mt < 2; mt++)
      aF[mt] = ld8(&Ab[cur][(wr * 32 + mt * 16 + m) * 32 + gq * 8]);
#pragma unroll
    for (int nt = 0; nt < 4; nt++)
      bF[nt] = ld8(&Bb[cur][(wc * 64 + nt * 16 + m) * 32 + gq * 8]);
#pragma unroll
    for (int mt = 0; mt < 2; mt++)
#pragma unroll
      for (int nt = 0; nt < 4; nt++)
        acc[mt][nt] = mfma16(aF[mt], bF[nt], acc[mt][nt]);
    __syncthreads();
    cur ^= 1;
  }
#pragma unroll
  for (int nt = 0; nt < 4; nt++) {
    int nl = wc * 64 + nt * 16 + m;
    int ch = bn + nl;
    float bias = mb2[ch];
#pragma unroll
    for (int mt = 0; mt < 2; mt++)
#pragma unroll
      for (int rr = 0; rr < 4; rr++) {
        int tl = wr * 32 + mt * 16 + gq * 4 + rr;
        float v = acc[mt][nt][rr] + bias + b2f(x2b[(size_t)(bm + tl) * 256 + ch]);
        ot[nl * 66 + tl] = v;
      }
  }
  __syncthreads();
  int tg = tok_base + bm;
  int bimg = tg / 9216, hw0 = tg % 9216;
  for (int it = 0; it < 32; it++) {
    int flat = it * 256 + tid;
    int j = flat >> 6, t = flat & 63;
    out[((size_t)bimg * 256 + bn + j) * 9216 + hw0 + t] = ot[j * 66 + t];
  }
}

extern "C" void kernel_launch(void* const* d_in, const int* in_sizes, int n_in,
                              void* d_out, int out_size, void* d_ws, size_t ws_size,
                              hipStream_t stream) {
  const float* x      = (const float*)d_in[0];
  const float* skipf  = (const float*)d_in[1];
  const float* up_w   = (const float*)d_in[2];
  const float* up_b   = (const float*)d_in[3];
  const float* skip_w = (const float*)d_in[4];
  const float* g1     = (const float*)d_in[5];
  const float* be1    = (const float*)d_in[6];
  const float* qkv_w  = (const float*)d_in[7];
  const float* qkv_b  = (const float*)d_in[8];
  const float* rpb    = (const float*)d_in[9];
  const float* proj_w = (const float*)d_in[10];
  const float* proj_b = (const float*)d_in[11];
  const float* g2     = (const float*)d_in[12];
  const float* be2    = (const float*)d_in[13];
  const float* m_w1   = (const float*)d_in[14];
  const float* m_b1   = (const float*)d_in[15];
  const float* m_w2   = (const float*)d_in[16];
  const float* m_b2   = (const float*)d_in[17];
  if (ws_size < WS_NEED) {
    k_sentinel<<<1, 256, 0, stream>>>((float*)d_out);
    return;
  }
  char* ws = (char*)d_ws;
  u16*   W    = (u16*)ws;
  float* bias = (float*)(ws + OFF_BIAS);
  u16*   sc   = (u16*)(ws + OFF_SC);
  u16*   xt   = (u16*)(ws + OFF_OVR);
  u16*   skt  = (u16*)(ws + OFF_OVR);
  u16*   qc   = (u16*)(ws + OFF_OVR);
  u16*   kc   = (u16*)(ws + OFF_OVR + 9834496u);
  u16*   vtc  = (u16*)(ws + OFF_OVR + 19668992u);
  u16*   h1q  = (u16*)(ws + OFF_OVR);
  float* stat = (float*)(ws + OFF_STAT);
  float* sgb  = (float*)(ws + OFF_SGB);
  u16*   win  = (u16*)d_out;

  k_prep<<<5512, 256, 0, stream>>>(qkv_w, proj_w, m_w1, m_w2, skip_w, up_w, rpb,
                                   g2, be2, W, bias, sgb);
  k_tr<<<dim3(72, 16, 8), 256, 0, stream>>>(x, xt, 512, 2304);
  k1g<<<dim3(144, 2, 4), 256, 0, stream>>>(W, xt, up_b, sc);
  k_tr_skip<<<dim3(3, 8, 768), 256, 0, stream>>>(skipf, skt);
  k2a<<<dim3(301, 8), 256, 0, stream>>>(W, sc, skt, g1, be1, win);
  for (int c = 0; c < 4; c++) {
    k2b<<<dim3(151, 6), 256, 0, stream>>>(W, win, qkv_b, qc, kc, vtc, c);
    u16* obc = (u16*)((char*)d_out + 36159488u + (size_t)(3 - c) * 9834496u);
    k3_attn<<<784, 256, 0, stream>>>(qc, kc, vtc, bias, obc);
  }
  k4w<<<dim3(151, 2, 4), 256, 0, stream>>>(W, (const char*)d_out, proj_b, sc);
  k_stats<<<4608, 256, 0, stream>>>(sc, stat);
  for (int q = 0; q < 4; q++) {
    const u16* x2b = sc + (size_t)q * 18432 * 256;
    k5f<<<dim3(144, 8), 256, 0, stream>>>(W, x2b, stat + (size_t)q * 36864,
                                          sgb, m_b1, h1q);
    k6g<<<dim3(288, 2), 256, 0, stream>>>(W, h1q, m_b2, x2b, (float*)d_out, q * 18432);
  }
}

// Round 9
// 724.090 us; speedup vs baseline: 1.8913x; 1.0154x over previous
//
#include <hip/hip_runtime.h>

typedef __attribute__((ext_vector_type(8))) short short8;
typedef __attribute__((ext_vector_type(4))) float f32x4;
typedef __attribute__((ext_vector_type(4))) unsigned short u16x4;
typedef unsigned short u16;
typedef unsigned int u32;

#define DEV static __device__ __forceinline__

DEV u16 f2b(float f) {
  u32 u = __builtin_bit_cast(u32, f);
  return (u16)((u + 0x7fffu + ((u >> 16) & 1u)) >> 16);
}
DEV float b2f(u16 h) {
  u32 u = ((u32)h) << 16;
  return __builtin_bit_cast(float, u);
}
DEV short8 ld8(const u16* p) { return *reinterpret_cast<const short8*>(p); }
DEV f32x4 mfma16(short8 a, short8 b, f32x4 c) {
  return __builtin_amdgcn_mfma_f32_16x16x32_bf16(a, b, c, 0, 0, 0);
}
DEV float wredsum(float v) {
#pragma unroll
  for (int off = 1; off < 64; off <<= 1) v += __shfl_xor(v, off);
  return v;
}

#define GLL(gp, lp) __builtin_amdgcn_global_load_lds( \
    (const __attribute__((address_space(1))) void*)(gp), \
    (__attribute__((address_space(3))) void*)(lp), 16, 0, 0)

// ---- weight arena (u16 element offsets) ----
#define WQKV   0         // [768][256]  (pre-scaled by gamma1)
#define WPROJ  196608    // [256][256]
#define WM1    262144    // [1024][256] (pre-scaled by gamma2)
#define WM2    524288    // [256][1024]
#define WSKIP  786432    // [256][256]
#define WUP    851968    // [4][256][512]  kk = kh*2+kw

// ---- ws byte offsets ----
#define OFF_BIAS 2752512u
#define OFF_SC   2883584u     // bf16 sc: conv shortcut -> x2 [73728][256]
#define OFF_OVR  40632320u    // 55,595,008B overlay:
// phase A: xt @OVR (18,874,368)  [dead after k1g]
// phase B: skt @OVR (37,748,736) [dead after k2y]
// phase C (per 2-img chunk): qc @OVR; kc @+9,834,496; vtc @+19,668,992
// phase D: h1q @OVR (37,748,736)
// persistent: stat @+52,000,000 (589,824); pstat @+52,600,000 (2,359,296);
//             sgb @+55,000,000 (17,408; floats: Sg2[1024],Sb2[1024],
//             Sg1@2048[768],Sb1@2816[768], zero-page @float idx 4096 x256)
#define OFF_STAT (OFF_OVR + 52000000u)
#define OFF_PST  (OFF_OVR + 52600000u)
#define OFF_SGB  (OFF_OVR + 55000000u)
// d_out scratch: ybuf u16 @0 (37,748,736); ob_c u16 @36,159,488+(3-c)*9,834,496
#define WS_NEED  96227328u

__global__ void k_sentinel(float* out) { out[threadIdx.x] = 31337.0f; }

// ================= prep: weights -> bf16, folds, bias table ==================
__global__ __launch_bounds__(256) void k_prep(
    const float* qkv_w, const float* proj_w, const float* mlp_w1,
    const float* mlp_w2, const float* skip_w, const float* up_w,
    const float* rpb, const float* g1, const float* be1,
    const float* g2, const float* be2, u16* W, float* bias_g, float* sgb) {
  int i = blockIdx.x * 256 + threadIdx.x;
  if (i < 196608) { W[WQKV + i] = f2b(qkv_w[i] * g1[i & 255]); return; }
  i -= 196608;
  if (i < 65536) { W[WPROJ + i] = f2b(proj_w[i]); return; }
  i -= 65536;
  if (i < 262144) { W[WM1 + i] = f2b(mlp_w1[i] * g2[i & 255]); return; }
  i -= 262144;
  if (i < 262144) { W[WM2 + i] = f2b(mlp_w2[i]); return; }
  i -= 262144;
  if (i < 65536) { W[WSKIP + i] = f2b(skip_w[i]); return; }
  i -= 65536;
  if (i < 524288) {
    int ci = i & 511; int rest = i >> 9; int co = rest & 255; int kk = rest >> 8;
    W[WUP + i] = f2b(up_w[ci * 1024 + co * 4 + kk]);
    return;
  }
  i -= 524288;
  if (i < 32768) {
    int h = i >> 12, r = i & 4095, ii = r >> 6, j = r & 63;
    float v;
    if (j >= 49) v = -1e30f;
    else if (ii >= 49) v = 0.f;
    else {
      int d0 = (ii / 7 - j / 7) + 6, d1 = (ii % 7 - j % 7) + 6;
      v = rpb[(d0 * 13 + d1) * 8 + h];
    }
    bias_g[i] = v;
    return;
  }
  i -= 32768;
  if (i < 1024) {  // Sg2[c]
    float s = 0.f;
    for (int k = 0; k < 256; k++) s += g2[k] * mlp_w1[i * 256 + k];
    sgb[i] = s;
    return;
  }
  i -= 1024;
  if (i < 1024) {  // Sb2[c]
    float s = 0.f;
    for (int k = 0; k < 256; k++) s += be2[k] * mlp_w1[i * 256 + k];
    sgb[1024 + i] = s;
    return;
  }
  i -= 1024;
  if (i < 768) {  // Sg1[c]
    float s = 0.f;
    for (int k = 0; k < 256; k++) s += g1[k] * qkv_w[i * 256 + k];
    sgb[2048 + i] = s;
    return;
  }
  i -= 768;
  if (i < 768) {  // Sb1[c]
    float s = 0.f;
    for (int k = 0; k < 256; k++) s += be1[k] * qkv_w[i * 256 + k];
    sgb[2816 + i] = s;
    return;
  }
  i -= 768;
  if (i < 256) sgb[4096 + i] = 0.f;  // zero page (1KB)
}

// ============== NCHW f32 -> NHWC bf16 tiled transpose (for x) =================
__global__ __launch_bounds__(256) void k_tr(const float* src, u16* dst, int C, int HW) {
  __shared__ float t[32][33];
  int hw0 = blockIdx.x * 32, c0 = blockIdx.y * 32, b = blockIdx.z;
  int tx = threadIdx.x & 31, ty = threadIdx.x >> 5;
  const float* s = src + (size_t)b * C * HW;
  u16* d = dst + (size_t)b * C * HW;
#pragma unroll
  for (int i = 0; i < 4; i++)
    t[ty + i * 8][tx] = s[(size_t)(c0 + ty + i * 8) * HW + hw0 + tx];
  __syncthreads();
#pragma unroll
  for (int i = 0; i < 4; i++)
    d[(size_t)(hw0 + ty + i * 8) * C + c0 + tx] = f2b(t[tx][ty + i * 8]);
}

// ===== batched skip transpose: skip[b][c][h][w] -> skt[b][h][w][c] (bf16) =====
__global__ __launch_bounds__(256) void k_tr_skip(const float* src, u16* dst) {
  __shared__ float t[32][33];
  int w0 = blockIdx.x * 32, c0 = blockIdx.y * 32;
  int z = blockIdx.z;
  int b = z / 96, h = z - b * 96;
  int tx = threadIdx.x & 31, ty = threadIdx.x >> 5;
  const float* s = src + (size_t)b * 256 * 9216 + (size_t)h * 96;
  u16* d = dst + (((size_t)b * 96 + h) * 96) * 256;
#pragma unroll
  for (int i = 0; i < 4; i++)
    t[ty + i * 8][tx] = s[(size_t)(c0 + ty + i * 8) * 9216 + w0 + tx];
  __syncthreads();
#pragma unroll
  for (int i = 0; i < 4; i++)
    d[(size_t)(w0 + ty + i * 8) * 256 + c0 + tx] = f2b(t[tx][ty + i * 8]);
}

// ====== K1G: convT as GEMM (M=18432,N=256,K=512) x4 parities, dbuf gll ========
__global__ __launch_bounds__(256) void k1g(
    const u16* W, const u16* xt, const float* up_b, u16* sc) {
  __shared__ __align__(16) u16 Ab[2][4096];
  __shared__ __align__(16) u16 Bb[2][4096];
  int tid = threadIdx.x;
  int lane = tid & 63, wave = tid >> 6;
  int m = lane & 15, gq = lane >> 4;
  int wr = wave >> 1, wc = wave & 1;
  int bm = blockIdx.x * 128, bn = blockIdx.y * 128;
  int kk = blockIdx.z, kh = kk >> 1, kw = kk & 1;
  const u16* Ag = xt + (size_t)bm * 512;
  const u16* Bg = W + WUP + (size_t)kk * 131072 + (size_t)bn * 512;
  f32x4 acc[4][4] = {};
#pragma unroll
  for (int c = 0; c < 2; c++) {
    int flat = (wave * 2 + c) * 512 + lane * 8;
    int r = flat >> 5, cc = flat & 31;
    GLL(Ag + (size_t)r * 512 + cc, &Ab[0][(wave * 2 + c) * 512]);
    GLL(Bg + (size_t)r * 512 + cc, &Bb[0][(wave * 2 + c) * 512]);
  }
  __syncthreads();
  int cur = 0;
  for (int ki = 0; ki < 16; ki++) {
    if (ki < 15) {
      int kkk = (ki + 1) * 32;
#pragma unroll
      for (int c = 0; c < 2; c++) {
        int flat = (wave * 2 + c) * 512 + lane * 8;
        int r = flat >> 5, cc = flat & 31;
        GLL(Ag + (size_t)r * 512 + kkk + cc, &Ab[cur ^ 1][(wave * 2 + c) * 512]);
        GLL(Bg + (size_t)r * 512 + kkk + cc, &Bb[cur ^ 1][(wave * 2 + c) * 512]);
      }
    }
    short8 aF[4], bF[4];
#pragma unroll
    for (int mt = 0; mt < 4; mt++)
      aF[mt] = ld8(&Ab[cur][(wr * 64 + mt * 16 + m) * 32 + gq * 8]);
#pragma unroll
    for (int nt = 0; nt < 4; nt++)
      bF[nt] = ld8(&Bb[cur][(wc * 64 + nt * 16 + m) * 32 + gq * 8]);
#pragma unroll
    for (int mt = 0; mt < 4; mt++)
#pragma unroll
      for (int nt = 0; nt < 4; nt++)
        acc[mt][nt] = mfma16(aF[mt], bF[nt], acc[mt][nt]);
    __syncthreads();
    cur ^= 1;
  }
  float ub[4];
#pragma unroll
  for (int nt = 0; nt < 4; nt++) ub[nt] = up_b[bn + wc * 64 + nt * 16 + m];
#pragma unroll
  for (int mt = 0; mt < 4; mt++)
#pragma unroll
    for (int rr = 0; rr < 4; rr++) {
      int t = bm + wr * 64 + mt * 16 + gq * 4 + rr;
      int b = t / 2304, rem = t - b * 2304;
      int ih = rem / 48, iw = rem - ih * 48;
      int h = 2 * ih + kh, w = 2 * iw + kw;
      size_t tok = ((size_t)b * 96 + h) * 96 + w;
#pragma unroll
      for (int nt = 0; nt < 4; nt++) {
        int ch = bn + wc * 64 + nt * 16 + m;
        sc[tok * 256 + ch] = f2b(acc[mt][nt][rr] + ub[nt]);
      }
    }
}

// ====== K2Y: skip 1x1 GEMM raster (M=73728,N=256,K=256) + y + LN1 partials ====
__global__ __launch_bounds__(256) void k2y(
    const u16* W, const u16* skt, const u16* sc, u16* ybuf, float* pstat) {
  __shared__ __align__(16) u16 Ab[2][4096];
  __shared__ __align__(16) u16 Bb[2][4096];
  int tid = threadIdx.x;
  int lane = tid & 63, wave = tid >> 6;
  int m = lane & 15, gq = lane >> 4;
  int wr = wave >> 1, wc = wave & 1;
  int bm = blockIdx.x * 128, bn = blockIdx.y * 128;
  const u16* Ag = skt + (size_t)bm * 256;
  const u16* Bg = W + WSKIP + (size_t)bn * 256;
  f32x4 acc[4][4] = {};
#pragma unroll
  for (int c = 0; c < 2; c++) {
    int flat = (wave * 2 + c) * 512 + lane * 8;
    int r = flat >> 5, cc = flat & 31;
    GLL(Ag + (size_t)r * 256 + cc, &Ab[0][(wave * 2 + c) * 512]);
    GLL(Bg + (size_t)r * 256 + cc, &Bb[0][(wave * 2 + c) * 512]);
  }
  __syncthreads();
  int cur = 0;
  for (int ki = 0; ki < 8; ki++) {
    if (ki < 7) {
      int kk = (ki + 1) * 32;
#pragma unroll
      for (int c = 0; c < 2; c++) {
        int flat = (wave * 2 + c) * 512 + lane * 8;
        int r = flat >> 5, cc = flat & 31;
        GLL(Ag + (size_t)r * 256 + kk + cc, &Ab[cur ^ 1][(wave * 2 + c) * 512]);
        GLL(Bg + (size_t)r * 256 + kk + cc, &Bb[cur ^ 1][(wave * 2 + c) * 512]);
      }
    }
    short8 aF[4], bF[4];
#pragma unroll
    for (int mt = 0; mt < 4; mt++)
      aF[mt] = ld8(&Ab[cur][(wr * 64 + mt * 16 + m) * 32 + gq * 8]);
#pragma unroll
    for (int nt = 0; nt < 4; nt++)
      bF[nt] = ld8(&Bb[cur][(wc * 64 + nt * 16 + m) * 32 + gq * 8]);
#pragma unroll
    for (int mt = 0; mt < 4; mt++)
#pragma unroll
      for (int nt = 0; nt < 4; nt++)
        acc[mt][nt] = mfma16(aF[mt], bF[nt], acc[mt][nt]);
    __syncthreads();
    cur ^= 1;
  }
#pragma unroll
  for (int mt = 0; mt < 4; mt++)
#pragma unroll
    for (int rr = 0; rr < 4; rr++) {
      int tok = bm + wr * 64 + mt * 16 + gq * 4 + rr;
      float s = 0.f, s2 = 0.f;
#pragma unroll
      for (int nt = 0; nt < 4; nt++) {
        int ch = bn + wc * 64 + nt * 16 + m;
        float y = acc[mt][nt][rr] + b2f(sc[(size_t)tok * 256 + ch]);
        ybuf[(size_t)tok * 256 + ch] = f2b(y);
        s += y; s2 += y * y;
      }
#pragma unroll
      for (int off = 1; off < 16; off <<= 1) {
        s += __shfl_xor(s, off);
        s2 += __shfl_xor(s2, off);
      }
      if (m == 0) {
        int pi = (tok * 4 + blockIdx.y * 2 + wc) * 2;
        pstat[pi] = s;
        pstat[pi + 1] = s2;
      }
    }
}

// ====== K_STATFIN: merge 4 partials -> (rstd, rstd*mean) per row ==============
__global__ __launch_bounds__(256) void k_statfin(const float* pstat, float* stat) {
  int row = blockIdx.x * 256 + threadIdx.x;
  float s = 0.f, s2 = 0.f;
#pragma unroll
  for (int j = 0; j < 4; j++) {
    s += pstat[(row * 4 + j) * 2];
    s2 += pstat[(row * 4 + j) * 2 + 1];
  }
  float mean = s * 0.00390625f;
  float var = s2 * 0.00390625f - mean * mean;
  float r = rsqrtf(var + 1e-6f);
  stat[row * 2] = r;
  stat[row * 2 + 1] = r * mean;
}

// ====== K2B: qkv GEMM with gathered A + LN1 fold (per 2-img chunk) ============
__global__ __launch_bounds__(256) void k2b(
    const u16* W, const u16* ybuf, const float* stat, const float* sgb,
    const u16* zp, const float* qkv_b, u16* qc, u16* kc, u16* vtc, int chunk) {
  __shared__ __align__(16) u16 Ab[2][4096];
  __shared__ __align__(16) u16 Bb[2][4096];
  int tid = threadIdx.x;
  int lane = tid & 63, wave = tid >> 6;
  int m = lane & 15, gq = lane >> 4;
  int wr = wave >> 1, wc = wave & 1;
  int bm = blockIdx.x * 128, bn = blockIdx.y * 128;
  const u16* Bg = W + WQKV + (size_t)bn * 256;
  // per-lane gathered A row addresses (window token -> raster)
  const u16* aptr[2];
#pragma unroll
  for (int c = 0; c < 2; c++) {
    int flat = (wave * 2 + c) * 512 + lane * 8;
    int r = flat >> 5, cc = flat & 31;
    int t = bm + r;
    const u16* p = zp + cc;
    if (t < 19208) {
      int bloc = t / 49, i = t - bloc * 49;
      int blocg = chunk * 392 + bloc;
      int img = blocg / 196, wl = blocg - img * 196;
      int wrow = wl / 14, wcol = wl - wrow * 14;
      int hh = wrow * 7 + i / 7, ww = wcol * 7 + i % 7;
      if (hh < 96 && ww < 96)
        p = ybuf + ((size_t)(img * 9216 + hh * 96 + ww) * 256 + cc);
    }
    aptr[c] = p;
  }
  f32x4 acc[4][4] = {};
#pragma unroll
  for (int c = 0; c < 2; c++) {
    int flat = (wave * 2 + c) * 512 + lane * 8;
    int r = flat >> 5, cc = flat & 31;
    GLL(aptr[c], &Ab[0][(wave * 2 + c) * 512]);
    GLL(Bg + (size_t)r * 256 + cc, &Bb[0][(wave * 2 + c) * 512]);
  }
  __syncthreads();
  int cur = 0;
  for (int ki = 0; ki < 8; ki++) {
    if (ki < 7) {
      int kk = (ki + 1) * 32;
#pragma unroll
      for (int c = 0; c < 2; c++) {
        int flat = (wave * 2 + c) * 512 + lane * 8;
        int r = flat >> 5, cc = flat & 31;
        GLL(aptr[c] + kk, &Ab[cur ^ 1][(wave * 2 + c) * 512]);
        GLL(Bg + (size_t)r * 256 + kk + cc, &Bb[cur ^ 1][(wave * 2 + c) * 512]);
      }
    }
    short8 aF[4], bF[4];
#pragma unroll
    for (int mt = 0; mt < 4; mt++)
      aF[mt] = ld8(&Ab[cur][(wr * 64 + mt * 16 + m) * 32 + gq * 8]);
#pragma unroll
    for (int nt = 0; nt < 4; nt++)
      bF[nt] = ld8(&Bb[cur][(wc * 64 + nt * 16 + m) * 32 + gq * 8]);
#pragma unroll
    for (int mt = 0; mt < 4; mt++)
#pragma unroll
      for (int nt = 0; nt < 4; nt++)
        acc[mt][nt] = mfma16(aF[mt], bF[nt], acc[mt][nt]);
    __syncthreads();
    cur ^= 1;
  }
  int typev[4], hdv[4], bhoff[4];
  float qbv[4], sg1v[4], sb1v[4];
#pragma unroll
  for (int nt = 0; nt < 4; nt++) {
    int ch = bn + wc * 64 + nt * 16 + m;
    qbv[nt] = qkv_b[ch];
    sg1v[nt] = sgb[2048 + ch];
    sb1v[nt] = sgb[2816 + ch];
    typev[nt] = ch >> 8;
    hdv[nt] = ch & 31;
    bhoff[nt] = (ch >> 5) & 7;
  }
#pragma unroll
  for (int mt = 0; mt < 4; mt++)
#pragma unroll
    for (int rr = 0; rr < 4; rr++) {
      int t = bm + wr * 64 + mt * 16 + gq * 4 + rr;
      if (t >= 19208) continue;
      int bloc = t / 49, i = t - bloc * 49;
      int blocg = chunk * 392 + bloc;
      int img = blocg / 196, wl = blocg - img * 196;
      int wrow = wl / 14, wcol = wl - wrow * 14;
      int hh = wrow * 7 + i / 7, ww = wcol * 7 + i % 7;
      float rs = 0.f, rmu = 0.f, vf = 0.f;
      if (hh < 96 && ww < 96) {
        int ras = img * 9216 + hh * 96 + ww;
        rs = stat[ras * 2];
        rmu = stat[ras * 2 + 1];
        vf = 1.f;
      }
#pragma unroll
      for (int nt = 0; nt < 4; nt++) {
        float v = rs * acc[mt][nt][rr] - rmu * sg1v[nt] + vf * sb1v[nt] + qbv[nt];
        size_t bh = (size_t)bloc * 8 + bhoff[nt];
        u16 val = f2b(v);
        if (typev[nt] == 0) qc[bh * 1568 + i * 32 + hdv[nt]] = val;
        else if (typev[nt] == 1) kc[bh * 1568 + i * 32 + hdv[nt]] = val;
        else vtc[bh * 2048 + hdv[nt] * 64 + i] = val;
      }
    }
}

// ============== K3: window attention, one wave per (window, head) =============
__global__ __launch_bounds__(256) void k3_attn(
    const u16* qc, const u16* kc, const u16* vtc, const float* bias_g, u16* obb) {
  __shared__ u16 plds[4][64 * 64];
  int lane = threadIdx.x & 63, wave = threadIdx.x >> 6;
  int b_ = blockIdx.x >> 1;
  int h = (blockIdx.x & 1) * 4 + wave;
  int m = lane & 15, gq = lane >> 4, k0 = gq * 8;
  size_t bh = (size_t)b_ * 8 + h;
  const u16* Q = qc + bh * 1568;
  const u16* K = kc + bh * 1568;
  const u16* V = vtc + bh * 2048;
  const float* BI = bias_g + h * 4096;
  short8 aq[4], bk[4];
#pragma unroll
  for (int mt = 0; mt < 4; mt++) { int i = mt * 16 + m; if (i > 48) i = 48; aq[mt] = ld8(Q + i * 32 + k0); }
#pragma unroll
  for (int nt = 0; nt < 4; nt++) { int j = nt * 16 + m; if (j > 48) j = 48; bk[nt] = ld8(K + j * 32 + k0); }
  f32x4 s[4][4] = {};
#pragma unroll
  for (int mt = 0; mt < 4; mt++)
#pragma unroll
    for (int nt = 0; nt < 4; nt++)
      s[mt][nt] = mfma16(aq[mt], bk[nt], s[mt][nt]);
  const float scale = 0.1767766952966369f;  // 1/sqrt(32)
  float rsum[4][4];
#pragma unroll
  for (int mt = 0; mt < 4; mt++)
#pragma unroll
    for (int rr = 0; rr < 4; rr++) {
      int i = mt * 16 + gq * 4 + rr;
      float sv[4];
      float mx = -1e38f;
#pragma unroll
      for (int nt = 0; nt < 4; nt++) {
        sv[nt] = s[mt][nt][rr] * scale + BI[i * 64 + nt * 16 + m];
        mx = fmaxf(mx, sv[nt]);
      }
      mx = fmaxf(mx, __shfl_xor(mx, 1));
      mx = fmaxf(mx, __shfl_xor(mx, 2));
      mx = fmaxf(mx, __shfl_xor(mx, 4));
      mx = fmaxf(mx, __shfl_xor(mx, 8));
      float sum = 0.f;
#pragma unroll
      for (int nt = 0; nt < 4; nt++) { sv[nt] = __expf(sv[nt] - mx); sum += sv[nt]; }
      sum += __shfl_xor(sum, 1);
      sum += __shfl_xor(sum, 2);
      sum += __shfl_xor(sum, 4);
      sum += __shfl_xor(sum, 8);
      rsum[mt][rr] = sum;
      int isw = (i & 7) * 8;
#pragma unroll
      for (int nt = 0; nt < 4; nt++) {
        int j = nt * 16 + m;
        plds[wave][i * 64 + (j ^ isw)] = f2b(sv[nt]);
      }
    }
  __syncthreads();
  f32x4 o[4][2] = {};
#pragma unroll
  for (int ks = 0; ks < 2; ks++) {
    short8 bv[2];
#pragma unroll
    for (int nt = 0; nt < 2; nt++)
      bv[nt] = ld8(V + (size_t)(nt * 16 + m) * 64 + ks * 32 + k0);
#pragma unroll
    for (int mt = 0; mt < 4; mt++) {
      int i = mt * 16 + m;
      short8 ap = *reinterpret_cast<const short8*>(
          &plds[wave][i * 64 + ((ks * 32 + k0) ^ ((i & 7) * 8))]);
#pragma unroll
      for (int nt = 0; nt < 2; nt++)
        o[mt][nt] = mfma16(ap, bv[nt], o[mt][nt]);
    }
  }
#pragma unroll
  for (int mt = 0; mt < 4; mt++)
#pragma unroll
    for (int rr = 0; rr < 4; rr++) {
      int i = mt * 16 + gq * 4 + rr;
      if (i >= 49) continue;
      float rinv = 1.f / rsum[mt][rr];
#pragma unroll
      for (int nt = 0; nt < 2; nt++) {
        int c = h * 32 + nt * 16 + m;
        obb[((size_t)b_ * 49 + i) * 256 + c] = f2b(o[mt][nt][rr] * rinv);
      }
    }
}

// ====== K4W: proj GEMM + shortcut -> x2 + LN2 partials (grid (151,2,4)) =======
__global__ __launch_bounds__(256) void k4w(
    const u16* W, const char* dout, const float* proj_b, u16* sc, float* pstat) {
  __shared__ __align__(16) u16 Ab[2][4096];
  __shared__ __align__(16) u16 Bb[2][4096];
  int tid = threadIdx.x;
  int lane = tid & 63, wave = tid >> 6;
  int m = lane & 15, gq = lane >> 4;
  int wr = wave >> 1, wc = wave & 1;
  int bm = blockIdx.x * 128, bn = blockIdx.y * 128;
  int z = blockIdx.z;
  const u16* Ag = (const u16*)(dout + 36159488u + (size_t)(3 - z) * 9834496u);
  const u16* Bg = W + WPROJ + (size_t)bn * 256;
  f32x4 acc[4][4] = {};
#pragma unroll
  for (int c = 0; c < 2; c++) {
    int flat = (wave * 2 + c) * 512 + lane * 8;
    int r = flat >> 5, cc = flat & 31;
    int rg = bm + r; if (rg > 19207) rg = 19207;
    GLL(Ag + (size_t)rg * 256 + cc, &Ab[0][(wave * 2 + c) * 512]);
    GLL(Bg + (size_t)r * 256 + cc, &Bb[0][(wave * 2 + c) * 512]);
  }
  __syncthreads();
  int cur = 0;
  for (int ki = 0; ki < 8; ki++) {
    if (ki < 7) {
      int kk = (ki + 1) * 32;
#pragma unroll
      for (int c = 0; c < 2; c++) {
        int flat = (wave * 2 + c) * 512 + lane * 8;
        int r = flat >> 5, cc = flat & 31;
        int rg = bm + r; if (rg > 19207) rg = 19207;
        GLL(Ag + (size_t)rg * 256 + kk + cc, &Ab[cur ^ 1][(wave * 2 + c) * 512]);
        GLL(Bg + (size_t)r * 256 + kk + cc, &Bb[cur ^ 1][(wave * 2 + c) * 512]);
      }
    }
    short8 aF[4], bF[4];
#pragma unroll
    for (int mt = 0; mt < 4; mt++)
      aF[mt] = ld8(&Ab[cur][(wr * 64 + mt * 16 + m) * 32 + gq * 8]);
#pragma unroll
    for (int nt = 0; nt < 4; nt++)
      bF[nt] = ld8(&Bb[cur][(wc * 64 + nt * 16 + m) * 32 + gq * 8]);
#pragma unroll
    for (int mt = 0; mt < 4; mt++)
#pragma unroll
      for (int nt = 0; nt < 4; nt++)
        acc[mt][nt] = mfma16(aF[mt], bF[nt], acc[mt][nt]);
    __syncthreads();
    cur ^= 1;
  }
#pragma unroll
  for (int mt = 0; mt < 4; mt++)
#pragma unroll
    for (int rr = 0; rr < 4; rr++) {
      int t = bm + wr * 64 + mt * 16 + gq * 4 + rr;
      if (t >= 19208) continue;
      int bloc = t / 49, i = t - bloc * 49;
      int b_ = z * 392 + bloc;
      int img = b_ / 196, wl = b_ - img * 196;
      int wrow = wl / 14, wcol = wl - wrow * 14;
      int hh = wrow * 7 + i / 7, ww = wcol * 7 + i % 7;
      if (hh >= 96 || ww >= 96) continue;
      size_t tok = ((size_t)img * 96 + hh) * 96 + ww;
      float s = 0.f, s2 = 0.f;
#pragma unroll
      for (int nt = 0; nt < 4; nt++) {
        int ch = bn + wc * 64 + nt * 16 + m;
        float v = acc[mt][nt][rr] + proj_b[ch] + b2f(sc[tok * 256 + ch]);
        sc[tok * 256 + ch] = f2b(v);
        s += v; s2 += v * v;
      }
#pragma unroll
      for (int off = 1; off < 16; off <<= 1) {
        s += __shfl_xor(s, off);
        s2 += __shfl_xor(s2, off);
      }
      if (m == 0) {
        int pi = ((int)tok * 4 + blockIdx.y * 2 + wc) * 2;
        pstat[pi] = s;
        pstat[pi + 1] = s2;
      }
    }
}

// ====== K5F: mlp1 GEMM on raw x2 + LN2 fold + GELU (M=18432,N=1024,K=256) =====
__global__ __launch_bounds__(256) void k5f(
    const u16* W, const u16* x2b, const float* stat, const float* sgb,
    const float* mb1, u16* h1q) {
  __shared__ __align__(16) u16 Ab[2][4096];
  __shared__ __align__(16) u16 Bb[2][4096];
  int tid = threadIdx.x;
  int lane = tid & 63, wave = tid >> 6;
  int m = lane & 15, gq = lane >> 4;
  int wr = wave >> 1, wc = wave & 1;
  int bm = blockIdx.x * 128, bn = blockIdx.y * 128;
  const u16* Ag = x2b + (size_t)bm * 256;
  const u16* Bg = W + WM1 + (size_t)bn * 256;
  f32x4 acc[4][4] = {};
#pragma unroll
  for (int c = 0; c < 2; c++) {
    int flat = (wave * 2 + c) * 512 + lane * 8;
    int r = flat >> 5, cc = flat & 31;
    GLL(Ag + (size_t)r * 256 + cc, &Ab[0][(wave * 2 + c) * 512]);
    GLL(Bg + (size_t)r * 256 + cc, &Bb[0][(wave * 2 + c) * 512]);
  }
  __syncthreads();
  int cur = 0;
  for (int ki = 0; ki < 8; ki++) {
    if (ki < 7) {
      int kk = (ki + 1) * 32;
#pragma unroll
      for (int c = 0; c < 2; c++) {
        int flat = (wave * 2 + c) * 512 + lane * 8;
        int r = flat >> 5, cc = flat & 31;
        GLL(Ag + (size_t)r * 256 + kk + cc, &Ab[cur ^ 1][(wave * 2 + c) * 512]);
        GLL(Bg + (size_t)r * 256 + kk + cc, &Bb[cur ^ 1][(wave * 2 + c) * 512]);
      }
    }
    short8 aF[4], bF[4];
#pragma unroll
    for (int mt = 0; mt < 4; mt++)
      aF[mt] = ld8(&Ab[cur][(wr * 64 + mt * 16 + m) * 32 + gq * 8]);
#pragma unroll
    for (int nt = 0; nt < 4; nt++)
      bF[nt] = ld8(&Bb[cur][(wc * 64 + nt * 16 + m) * 32 + gq * 8]);
#pragma unroll
    for (int mt = 0; mt < 4; mt++)
#pragma unroll
      for (int nt = 0; nt < 4; nt++)
        acc[mt][nt] = mfma16(aF[mt], bF[nt], acc[mt][nt]);
    __syncthreads();
    cur ^= 1;
  }
  float sgv[4], sbv[4], b1v[4];
#pragma unroll
  for (int nt = 0; nt < 4; nt++) {
    int ch = bn + wc * 64 + nt * 16 + m;
    sgv[nt] = sgb[ch];
    sbv[nt] = sgb[1024 + ch];
    b1v[nt] = mb1[ch];
  }
#pragma unroll
  for (int mt = 0; mt < 4; mt++)
#pragma unroll
    for (int rr = 0; rr < 4; rr++) {
      int tok = bm + wr * 64 + mt * 16 + gq * 4 + rr;
      float rs = stat[tok * 2], rmu = stat[tok * 2 + 1];
#pragma unroll
      for (int nt = 0; nt < 4; nt++) {
        float v = rs * acc[mt][nt][rr] - rmu * sgv[nt] + sbv[nt] + b1v[nt];
        v = 0.5f * v * (1.f + erff(v * 0.7071067811865475f));
        h1q[(size_t)tok * 1024 + (bn + wc * 64 + nt * 16 + m)] = f2b(v);
      }
    }
}

// ====== K6G: mlp2 GEMM (M=18432,N=256,K=1024), 64x128 tile + NCHW out =========
__global__ __launch_bounds__(256) void k6g(
    const u16* W, const u16* h1q, const float* mb2, const u16* x2b,
    float* out, int tok_base) {
  __shared__ __align__(16) u16 Ab[2][2048];
  __shared__ __align__(16) u16 Bb[2][4096];
  __shared__ float ot[128 * 66];
  int tid = threadIdx.x;
  int lane = tid & 63, wave = tid >> 6;
  int m = lane & 15, gq = lane >> 4;
  int wr = wave >> 1, wc = wave & 1;
  int bm = blockIdx.x * 64, bn = blockIdx.y * 128;
  const u16* Ag = h1q + (size_t)bm * 1024;
  const u16* Bg = W + WM2 + (size_t)bn * 1024;
  f32x4 acc[2][4] = {};
  {
    int flatA = wave * 512 + lane * 8;
    GLL(Ag + (size_t)(flatA >> 5) * 1024 + (flatA & 31), &Ab[0][wave * 512]);
#pragma unroll
    for (int c = 0; c < 2; c++) {
      int flat = (wave * 2 + c) * 512 + lane * 8;
      GLL(Bg + (size_t)(flat >> 5) * 1024 + (flat & 31), &Bb[0][(wave * 2 + c) * 512]);
    }
  }
  __syncthreads();
  int cur = 0;
  for (int ki = 0; ki < 32; ki++) {
    if (ki < 31) {
      int kk = (ki + 1) * 32;
      int flatA = wave * 512 + lane * 8;
      GLL(Ag + (size_t)(flatA >> 5) * 1024 + kk + (flatA & 31), &Ab[cur ^ 1][wave * 512]);
#pragma unroll
      for (int c = 0; c < 2; c++) {
        int flat = (wave * 2 + c) * 512 + lane * 8;
        GLL(Bg + (size_t)(flat >> 5) * 1024 + kk + (flat & 31), &Bb[cur ^ 1][(wave * 2 + c) * 512]);
      }
    }
    short8 aF[2], bF[4];
#pragma unroll
    for (int mt = 0; mt < 2; mt++)
      aF[mt] = ld8(&Ab[cur][(wr * 32 + mt * 16 + m) * 32 + gq * 8]);
#pragma unroll
    for (int nt = 0; nt < 4; nt++)
      bF[nt] = ld8(&Bb[cur][(wc * 64 + nt * 16 + m) * 32 + gq * 8]);
#pragma unroll
    for (int mt = 0; mt < 2; mt++)
#pragma unroll
      for (int nt = 0; nt < 4; nt++)
        acc[mt][nt] = mfma16(aF[mt], bF[nt], acc[mt][nt]);
    __syncthreads();
    cur ^= 1;
  }
#pragma unroll
  for (int nt = 0; nt < 4; nt++) {
    int nl = wc * 64 + nt * 16 + m;
    int ch = bn + nl;
    float bias = mb2[ch];
#pragma unroll
    for (int mt = 0; mt < 2; mt++)
#pragma unroll
      for (int rr = 0; rr < 4; rr++) {
        int tl = wr * 32 + mt * 16 + gq * 4 + rr;
        float v = acc[mt][nt][rr] + bias + b2f(x2b[(size_t)(bm + tl) * 256 + ch]);
        ot[nl * 66 + tl] = v;
      }
  }
  __syncthreads();
  int tg = tok_base + bm;
  int bimg = tg / 9216, hw0 = tg % 9216;
  for (int it = 0; it < 32; it++) {
    int flat = it * 256 + tid;
    int j = flat >> 6, t = flat & 63;
    out[((size_t)bimg * 256 + bn + j) * 9216 + hw0 + t] = ot[j * 66 + t];
  }
}

extern "C" void kernel_launch(void* const* d_in, const int* in_sizes, int n_in,
                              void* d_out, int out_size, void* d_ws, size_t ws_size,
                              hipStream_t stream) {
  const float* x      = (const float*)d_in[0];
  const float* skipf  = (const float*)d_in[1];
  const float* up_w   = (const float*)d_in[2];
  const float* up_b   = (const float*)d_in[3];
  const float* skip_w = (const float*)d_in[4];
  const float* g1     = (const float*)d_in[5];
  const float* be1    = (const float*)d_in[6];
  const float* qkv_w  = (const float*)d_in[7];
  const float* qkv_b  = (const float*)d_in[8];
  const float* rpb    = (const float*)d_in[9];
  const float* proj_w = (const float*)d_in[10];
  const float* proj_b = (const float*)d_in[11];
  const float* g2     = (const float*)d_in[12];
  const float* be2    = (const float*)d_in[13];
  const float* m_w1   = (const float*)d_in[14];
  const float* m_b1   = (const float*)d_in[15];
  const float* m_w2   = (const float*)d_in[16];
  const float* m_b2   = (const float*)d_in[17];
  if (ws_size < WS_NEED) {
    k_sentinel<<<1, 256, 0, stream>>>((float*)d_out);
    return;
  }
  char* ws = (char*)d_ws;
  u16*   W    = (u16*)ws;
  float* bias = (float*)(ws + OFF_BIAS);
  u16*   sc   = (u16*)(ws + OFF_SC);
  u16*   xt   = (u16*)(ws + OFF_OVR);
  u16*   skt  = (u16*)(ws + OFF_OVR);
  u16*   qc   = (u16*)(ws + OFF_OVR);
  u16*   kc   = (u16*)(ws + OFF_OVR + 9834496u);
  u16*   vtc  = (u16*)(ws + OFF_OVR + 19668992u);
  u16*   h1q  = (u16*)(ws + OFF_OVR);
  float* stat = (float*)(ws + OFF_STAT);
  float* pst  = (float*)(ws + OFF_PST);
  float* sgb  = (float*)(ws + OFF_SGB);
  const u16* zp = (const u16*)(ws + OFF_SGB + 16384u);
  u16*   ybuf = (u16*)d_out;

  k_prep<<<5519, 256, 0, stream>>>(qkv_w, proj_w, m_w1, m_w2, skip_w, up_w, rpb,
                                   g1, be1, g2, be2, W, bias, sgb);
  k_tr<<<dim3(72, 16, 8), 256, 0, stream>>>(x, xt, 512, 2304);
  k1g<<<dim3(144, 2, 4), 256, 0, stream>>>(W, xt, up_b, sc);
  k_tr_skip<<<dim3(3, 8, 768), 256, 0, stream>>>(skipf, skt);
  k2y<<<dim3(576, 2), 256, 0, stream>>>(W, skt, sc, ybuf, pst);
  k_statfin<<<288, 256, 0, stream>>>(pst, stat);
  for (int c = 0; c < 4; c++) {
    k2b<<<dim3(151, 6), 256, 0, stream>>>(W, ybuf, stat, sgb, zp, qkv_b,
                                          qc, kc, vtc, c);
    u16* obc = (u16*)((char*)d_out + 36159488u + (size_t)(3 - c) * 9834496u);
    k3_attn<<<784, 256, 0, stream>>>(qc, kc, vtc, bias, obc);
  }
  k4w<<<dim3(151, 2, 4), 256, 0, stream>>>(W, (const char*)d_out, proj_b, sc, pst);
  k_statfin<<<288, 256, 0, stream>>>(pst, stat);
  for (int q = 0; q < 4; q++) {
    const u16* x2b = sc + (size_t)q * 18432 * 256;
    k5f<<<dim3(144, 8), 256, 0, stream>>>(W, x2b, stat + (size_t)q * 36864,
                                          sgb, m_b1, h1q);
    k6g<<<dim3(288, 2), 256, 0, stream>>>(W, h1q, m_b2, x2b, (float*)d_out, q * 18432);
  }
}

// Round 10
// 665.780 us; speedup vs baseline: 2.0569x; 1.0876x over previous
//
#include <hip/hip_runtime.h>

typedef __attribute__((ext_vector_type(8))) short short8;
typedef __attribute__((ext_vector_type(4))) float f32x4;
typedef __attribute__((ext_vector_type(4))) unsigned short u16x4;
typedef unsigned short u16;
typedef unsigned int u32;

#define DEV static __device__ __forceinline__

DEV u16 f2b(float f) {
  u32 u = __builtin_bit_cast(u32, f);
  return (u16)((u + 0x7fffu + ((u >> 16) & 1u)) >> 16);
}
DEV float b2f(u16 h) {
  u32 u = ((u32)h) << 16;
  return __builtin_bit_cast(float, u);
}
DEV short8 ld8(const u16* p) { return *reinterpret_cast<const short8*>(p); }
DEV f32x4 mfma16(short8 a, short8 b, f32x4 c) {
  return __builtin_amdgcn_mfma_f32_16x16x32_bf16(a, b, c, 0, 0, 0);
}
DEV float wredsum(float v) {
#pragma unroll
  for (int off = 1; off < 64; off <<= 1) v += __shfl_xor(v, off);
  return v;
}

#define GLL(gp, lp) __builtin_amdgcn_global_load_lds( \
    (const __attribute__((address_space(1))) void*)(gp), \
    (__attribute__((address_space(3))) void*)(lp), 16, 0, 0)

// ---- weight arena (u16 element offsets) ----
#define WQKV   0         // [768][256]  (pre-scaled by gamma1)
#define WPROJ  196608    // [256][256]
#define WM1    262144    // [1024][256] (pre-scaled by gamma2)
#define WM2    524288    // [256][1024]
#define WSKIP  786432    // [256][256]
#define WUP    851968    // [4][256][512]  kk = kh*2+kw

// ---- ws byte offsets ----
#define OFF_BIAS 2752512u
#define OFF_SC   2883584u     // bf16 sc: conv shortcut -> x2 [73728][256]
#define OFF_OVR  40632320u    // overlay:
// phase A: xt @OVR (18,874,368)  [dead after k1g]
// phase B: skt @OVR (37,748,736) [dead after k2y]
// phase D: h1q @OVR (37,748,736)
// persistent: stat @+52,000,000; pstat @+52,600,000; sgb @+55,000,000
#define OFF_STAT (OFF_OVR + 52000000u)
#define OFF_PST  (OFF_OVR + 52600000u)
#define OFF_SGB  (OFF_OVR + 55000000u)
// d_out scratch: ybuf u16 @0 (37,748,736); obr u16 @37,748,736 (37,748,736)
#define WS_NEED  96227328u

__global__ void k_sentinel(float* out) { out[threadIdx.x] = 31337.0f; }

// ================= prep: weights -> bf16, folds, bias table ==================
__global__ __launch_bounds__(256) void k_prep(
    const float* qkv_w, const float* proj_w, const float* mlp_w1,
    const float* mlp_w2, const float* skip_w, const float* up_w,
    const float* rpb, const float* g1, const float* be1,
    const float* g2, const float* be2, u16* W, float* bias_g, float* sgb) {
  int i = blockIdx.x * 256 + threadIdx.x;
  if (i < 196608) { W[WQKV + i] = f2b(qkv_w[i] * g1[i & 255]); return; }
  i -= 196608;
  if (i < 65536) { W[WPROJ + i] = f2b(proj_w[i]); return; }
  i -= 65536;
  if (i < 262144) { W[WM1 + i] = f2b(mlp_w1[i] * g2[i & 255]); return; }
  i -= 262144;
  if (i < 262144) { W[WM2 + i] = f2b(mlp_w2[i]); return; }
  i -= 262144;
  if (i < 65536) { W[WSKIP + i] = f2b(skip_w[i]); return; }
  i -= 65536;
  if (i < 524288) {
    int ci = i & 511; int rest = i >> 9; int co = rest & 255; int kk = rest >> 8;
    W[WUP + i] = f2b(up_w[ci * 1024 + co * 4 + kk]);
    return;
  }
  i -= 524288;
  if (i < 32768) {
    int h = i >> 12, r = i & 4095, ii = r >> 6, j = r & 63;
    float v;
    if (j >= 49) v = -1e30f;
    else if (ii >= 49) v = 0.f;
    else {
      int d0 = (ii / 7 - j / 7) + 6, d1 = (ii % 7 - j % 7) + 6;
      v = rpb[(d0 * 13 + d1) * 8 + h];
    }
    bias_g[i] = v;
    return;
  }
  i -= 32768;
  if (i < 1024) {  // Sg2[c]
    float s = 0.f;
    for (int k = 0; k < 256; k++) s += g2[k] * mlp_w1[i * 256 + k];
    sgb[i] = s;
    return;
  }
  i -= 1024;
  if (i < 1024) {  // Sb2[c]
    float s = 0.f;
    for (int k = 0; k < 256; k++) s += be2[k] * mlp_w1[i * 256 + k];
    sgb[1024 + i] = s;
    return;
  }
  i -= 1024;
  if (i < 768) {  // Sb1[c] = sum_k be1[k]*qkv_w[c][k]
    float s = 0.f;
    for (int k = 0; k < 256; k++) s += be1[k] * qkv_w[i * 256 + k];
    sgb[2816 + i] = s;
    return;
  }
}

// ============== NCHW f32 -> NHWC bf16 tiled transpose (for x) =================
__global__ __launch_bounds__(256) void k_tr(const float* src, u16* dst, int C, int HW) {
  __shared__ float t[32][33];
  int hw0 = blockIdx.x * 32, c0 = blockIdx.y * 32, b = blockIdx.z;
  int tx = threadIdx.x & 31, ty = threadIdx.x >> 5;
  const float* s = src + (size_t)b * C * HW;
  u16* d = dst + (size_t)b * C * HW;
#pragma unroll
  for (int i = 0; i < 4; i++)
    t[ty + i * 8][tx] = s[(size_t)(c0 + ty + i * 8) * HW + hw0 + tx];
  __syncthreads();
#pragma unroll
  for (int i = 0; i < 4; i++)
    d[(size_t)(hw0 + ty + i * 8) * C + c0 + tx] = f2b(t[tx][ty + i * 8]);
}

// ===== batched skip transpose: skip[b][c][h][w] -> skt[b][h][w][c] (bf16) =====
__global__ __launch_bounds__(256) void k_tr_skip(const float* src, u16* dst) {
  __shared__ float t[32][33];
  int w0 = blockIdx.x * 32, c0 = blockIdx.y * 32;
  int z = blockIdx.z;
  int b = z / 96, h = z - b * 96;
  int tx = threadIdx.x & 31, ty = threadIdx.x >> 5;
  const float* s = src + (size_t)b * 256 * 9216 + (size_t)h * 96;
  u16* d = dst + (((size_t)b * 96 + h) * 96) * 256;
#pragma unroll
  for (int i = 0; i < 4; i++)
    t[ty + i * 8][tx] = s[(size_t)(c0 + ty + i * 8) * 9216 + w0 + tx];
  __syncthreads();
#pragma unroll
  for (int i = 0; i < 4; i++)
    d[(size_t)(w0 + ty + i * 8) * 256 + c0 + tx] = f2b(t[tx][ty + i * 8]);
}

// ====== K1G: convT as GEMM (M=18432,N=256,K=512) x4 parities, dbuf gll ========
__global__ __launch_bounds__(256) void k1g(
    const u16* W, const u16* xt, const float* up_b, u16* sc) {
  __shared__ __align__(16) u16 Ab[2][4096];
  __shared__ __align__(16) u16 Bb[2][4096];
  int tid = threadIdx.x;
  int lane = tid & 63, wave = tid >> 6;
  int m = lane & 15, gq = lane >> 4;
  int wr = wave >> 1, wc = wave & 1;
  int bm = blockIdx.x * 128, bn = blockIdx.y * 128;
  int kk = blockIdx.z, kh = kk >> 1, kw = kk & 1;
  const u16* Ag = xt + (size_t)bm * 512;
  const u16* Bg = W + WUP + (size_t)kk * 131072 + (size_t)bn * 512;
  f32x4 acc[4][4] = {};
#pragma unroll
  for (int c = 0; c < 2; c++) {
    int flat = (wave * 2 + c) * 512 + lane * 8;
    int r = flat >> 5, cc = flat & 31;
    GLL(Ag + (size_t)r * 512 + cc, &Ab[0][(wave * 2 + c) * 512]);
    GLL(Bg + (size_t)r * 512 + cc, &Bb[0][(wave * 2 + c) * 512]);
  }
  __syncthreads();
  int cur = 0;
  for (int ki = 0; ki < 16; ki++) {
    if (ki < 15) {
      int kkk = (ki + 1) * 32;
#pragma unroll
      for (int c = 0; c < 2; c++) {
        int flat = (wave * 2 + c) * 512 + lane * 8;
        int r = flat >> 5, cc = flat & 31;
        GLL(Ag + (size_t)r * 512 + kkk + cc, &Ab[cur ^ 1][(wave * 2 + c) * 512]);
        GLL(Bg + (size_t)r * 512 + kkk + cc, &Bb[cur ^ 1][(wave * 2 + c) * 512]);
      }
    }
    short8 aF[4], bF[4];
#pragma unroll
    for (int mt = 0; mt < 4; mt++)
      aF[mt] = ld8(&Ab[cur][(wr * 64 + mt * 16 + m) * 32 + gq * 8]);
#pragma unroll
    for (int nt = 0; nt < 4; nt++)
      bF[nt] = ld8(&Bb[cur][(wc * 64 + nt * 16 + m) * 32 + gq * 8]);
#pragma unroll
    for (int mt = 0; mt < 4; mt++)
#pragma unroll
      for (int nt = 0; nt < 4; nt++)
        acc[mt][nt] = mfma16(aF[mt], bF[nt], acc[mt][nt]);
    __syncthreads();
    cur ^= 1;
  }
  float ub[4];
#pragma unroll
  for (int nt = 0; nt < 4; nt++) ub[nt] = up_b[bn + wc * 64 + nt * 16 + m];
#pragma unroll
  for (int mt = 0; mt < 4; mt++)
#pragma unroll
    for (int rr = 0; rr < 4; rr++) {
      int t = bm + wr * 64 + mt * 16 + gq * 4 + rr;
      int b = t / 2304, rem = t - b * 2304;
      int ih = rem / 48, iw = rem - ih * 48;
      int h = 2 * ih + kh, w = 2 * iw + kw;
      size_t tok = ((size_t)b * 96 + h) * 96 + w;
#pragma unroll
      for (int nt = 0; nt < 4; nt++) {
        int ch = bn + wc * 64 + nt * 16 + m;
        sc[tok * 256 + ch] = f2b(acc[mt][nt][rr] + ub[nt]);
      }
    }
}

// ====== K2Y: skip 1x1 GEMM raster (M=73728,N=256,K=256) + y + LN1 partials ====
__global__ __launch_bounds__(256) void k2y(
    const u16* W, const u16* skt, const u16* sc, u16* ybuf, float* pstat) {
  __shared__ __align__(16) u16 Ab[2][4096];
  __shared__ __align__(16) u16 Bb[2][4096];
  int tid = threadIdx.x;
  int lane = tid & 63, wave = tid >> 6;
  int m = lane & 15, gq = lane >> 4;
  int wr = wave >> 1, wc = wave & 1;
  int bm = blockIdx.x * 128, bn = blockIdx.y * 128;
  const u16* Ag = skt + (size_t)bm * 256;
  const u16* Bg = W + WSKIP + (size_t)bn * 256;
  f32x4 acc[4][4] = {};
#pragma unroll
  for (int c = 0; c < 2; c++) {
    int flat = (wave * 2 + c) * 512 + lane * 8;
    int r = flat >> 5, cc = flat & 31;
    GLL(Ag + (size_t)r * 256 + cc, &Ab[0][(wave * 2 + c) * 512]);
    GLL(Bg + (size_t)r * 256 + cc, &Bb[0][(wave * 2 + c) * 512]);
  }
  __syncthreads();
  int cur = 0;
  for (int ki = 0; ki < 8; ki++) {
    if (ki < 7) {
      int kk = (ki + 1) * 32;
#pragma unroll
      for (int c = 0; c < 2; c++) {
        int flat = (wave * 2 + c) * 512 + lane * 8;
        int r = flat >> 5, cc = flat & 31;
        GLL(Ag + (size_t)r * 256 + kk + cc, &Ab[cur ^ 1][(wave * 2 + c) * 512]);
        GLL(Bg + (size_t)r * 256 + kk + cc, &Bb[cur ^ 1][(wave * 2 + c) * 512]);
      }
    }
    short8 aF[4], bF[4];
#pragma unroll
    for (int mt = 0; mt < 4; mt++)
      aF[mt] = ld8(&Ab[cur][(wr * 64 + mt * 16 + m) * 32 + gq * 8]);
#pragma unroll
    for (int nt = 0; nt < 4; nt++)
      bF[nt] = ld8(&Bb[cur][(wc * 64 + nt * 16 + m) * 32 + gq * 8]);
#pragma unroll
    for (int mt = 0; mt < 4; mt++)
#pragma unroll
      for (int nt = 0; nt < 4; nt++)
        acc[mt][nt] = mfma16(aF[mt], bF[nt], acc[mt][nt]);
    __syncthreads();
    cur ^= 1;
  }
#pragma unroll
  for (int mt = 0; mt < 4; mt++)
#pragma unroll
    for (int rr = 0; rr < 4; rr++) {
      int tok = bm + wr * 64 + mt * 16 + gq * 4 + rr;
      float s = 0.f, s2 = 0.f;
#pragma unroll
      for (int nt = 0; nt < 4; nt++) {
        int ch = bn + wc * 64 + nt * 16 + m;
        float y = acc[mt][nt][rr] + b2f(sc[(size_t)tok * 256 + ch]);
        ybuf[(size_t)tok * 256 + ch] = f2b(y);
        s += y; s2 += y * y;
      }
#pragma unroll
      for (int off = 1; off < 16; off <<= 1) {
        s += __shfl_xor(s, off);
        s2 += __shfl_xor(s2, off);
      }
      if (m == 0) {
        int pi = (tok * 4 + blockIdx.y * 2 + wc) * 2;
        pstat[pi] = s;
        pstat[pi + 1] = s2;
      }
    }
}

// ====== K_STATFIN: merge 4 partials -> (rstd, rstd*mean) per row ==============
__global__ __launch_bounds__(256) void k_statfin(const float* pstat, float* stat) {
  int row = blockIdx.x * 256 + threadIdx.x;
  float s = 0.f, s2 = 0.f;
#pragma unroll
  for (int j = 0; j < 4; j++) {
    s += pstat[(row * 4 + j) * 2];
    s2 += pstat[(row * 4 + j) * 2 + 1];
  }
  float mean = s * 0.00390625f;
  float var = s2 * 0.00390625f - mean * mean;
  float r = rsqrtf(var + 1e-6f);
  stat[row * 2] = r;
  stat[row * 2 + 1] = r * mean;
}

// ====== K23: fused qkv GEMM + window attention, one block per window ==========
// LDS: yl[52][264] shared z-rows; pws[wave][6144] private:
//   vt @0 (32x64), q @2048 (49x32), k @3616 (49x32), P @2048 (64x64 over q/k)
__global__ __launch_bounds__(256) void k23(
    const u16* W, const u16* ybuf, const float* stat, const float* sgb,
    const float* qkv_b, const float* bias_g, u16* obr) {
  __shared__ __align__(16) u16 yl[52 * 264];
  __shared__ __align__(16) u16 pws[4][6144];
  int tid = threadIdx.x;
  int lane = tid & 63, wave = tid >> 6;
  int m = lane & 15, gq = lane >> 4, k0 = gq * 8;
  int blk = blockIdx.x;
  int bimg = blk / 196, wl = blk - bimg * 196;
  int wrow = wl / 14, wcol = wl - wrow * 14;
  int h0 = wrow * 7, w0 = wcol * 7;
  u16* prv = pws[wave];
  // zero vt region (cols j>=49 never written; must be finite)
#pragma unroll
  for (int t = 0; t < 8; t++) {
    u16x4 z = {};
    *reinterpret_cast<u16x4*>(&prv[t * 256 + lane * 4]) = z;
  }
  // stage z = (y - mu)*r rows into yl (pad/phantom rows = 0)
  for (int it = 0; it < 7; it++) {
    int flat = it * 256 + tid;
    if (flat < 1568) {
      int row = flat >> 5, cc = (flat & 31) * 8;
      int hh = h0 + row / 7, ww = w0 + row % 7;
      short8 v = {};
      if (hh < 96 && ww < 96) {
        int ras = (bimg * 96 + hh) * 96 + ww;
        short8 raw = ld8(ybuf + (size_t)ras * 256 + cc);
        float rs = stat[ras * 2], rmu = stat[ras * 2 + 1];
#pragma unroll
        for (int q2 = 0; q2 < 8; q2++) {
          float zz = b2f(((const u16*)&raw)[q2]) * rs - rmu;
          ((u16*)&v)[q2] = f2b(zz);
        }
      }
      *reinterpret_cast<short8*>(&yl[row * 264 + cc]) = v;
    }
  }
  __syncthreads();  // the only block barrier
  const float scale = 0.1767766952966369f;  // 1/sqrt(32)
#pragma unroll
  for (int hp = 0; hp < 2; hp++) {
    int h = wave * 2 + hp;
    // qkv GEMM for head h: N=96 (q32,k32,v32), M=64(49), K=256
    {
      f32x4 acc[4][6] = {};
#pragma unroll 2
      for (int ks = 0; ks < 8; ks++) {
        short8 a[4];
#pragma unroll
        for (int mt = 0; mt < 4; mt++) {
          int row = mt * 16 + m; if (row > 48) row = 48;
          a[mt] = ld8(&yl[row * 264 + ks * 32 + k0]);
        }
#pragma unroll
        for (int nt = 0; nt < 6; nt++) {
          int brow = (nt >> 1) * 256 + h * 32 + (nt & 1) * 16 + m;
          short8 bb = ld8(W + WQKV + (size_t)brow * 256 + ks * 32 + k0);
#pragma unroll
          for (int mt = 0; mt < 4; mt++)
            acc[mt][nt] = mfma16(a[mt], bb, acc[mt][nt]);
        }
      }
      // epilogue: + vf*Sb1 + qkv_b; scatter into private q/k/vt
      float qb_[6], sb1[6];
      int hdv[6];
#pragma unroll
      for (int nt = 0; nt < 6; nt++) {
        int hd = (nt & 1) * 16 + m;
        int c = (nt >> 1) * 256 + h * 32 + hd;
        qb_[nt] = qkv_b[c];
        sb1[nt] = sgb[2816 + c];
        hdv[nt] = hd;
      }
#pragma unroll
      for (int mt = 0; mt < 4; mt++)
#pragma unroll
        for (int rr = 0; rr < 4; rr++) {
          int row = mt * 16 + gq * 4 + rr;
          if (row >= 49) continue;
          int hh = h0 + row / 7, ww = w0 + row % 7;
          float vf = (hh < 96 && ww < 96) ? 1.f : 0.f;
#pragma unroll
          for (int nt = 0; nt < 6; nt++) {
            u16 val = f2b(acc[mt][nt][rr] + vf * sb1[nt] + qb_[nt]);
            if ((nt >> 1) == 0) prv[2048 + row * 32 + hdv[nt]] = val;
            else if ((nt >> 1) == 1) prv[3616 + row * 32 + hdv[nt]] = val;
            else prv[hdv[nt] * 64 + row] = val;
          }
        }
    }
    // QK^T (same-wave LDS ordering via lgkmcnt)
    short8 aq[4], bk[4];
#pragma unroll
    for (int mt = 0; mt < 4; mt++) { int i = mt * 16 + m; if (i > 48) i = 48; aq[mt] = ld8(&prv[2048 + i * 32 + k0]); }
#pragma unroll
    for (int nt = 0; nt < 4; nt++) { int j = nt * 16 + m; if (j > 48) j = 48; bk[nt] = ld8(&prv[3616 + j * 32 + k0]); }
    f32x4 s[4][4] = {};
#pragma unroll
    for (int mt = 0; mt < 4; mt++)
#pragma unroll
      for (int nt = 0; nt < 4; nt++)
        s[mt][nt] = mfma16(aq[mt], bk[nt], s[mt][nt]);
    const float* BI = bias_g + h * 4096;
    float rsum[4][4];
#pragma unroll
    for (int mt = 0; mt < 4; mt++)
#pragma unroll
      for (int rr = 0; rr < 4; rr++) {
        int i = mt * 16 + gq * 4 + rr;
        float sv[4];
        float mx = -1e38f;
#pragma unroll
        for (int nt = 0; nt < 4; nt++) {
          sv[nt] = s[mt][nt][rr] * scale + BI[i * 64 + nt * 16 + m];
          mx = fmaxf(mx, sv[nt]);
        }
        mx = fmaxf(mx, __shfl_xor(mx, 1));
        mx = fmaxf(mx, __shfl_xor(mx, 2));
        mx = fmaxf(mx, __shfl_xor(mx, 4));
        mx = fmaxf(mx, __shfl_xor(mx, 8));
        float sum = 0.f;
#pragma unroll
        for (int nt = 0; nt < 4; nt++) { sv[nt] = __expf(sv[nt] - mx); sum += sv[nt]; }
        sum += __shfl_xor(sum, 1);
        sum += __shfl_xor(sum, 2);
        sum += __shfl_xor(sum, 4);
        sum += __shfl_xor(sum, 8);
        rsum[mt][rr] = sum;
        int isw = (i & 7) * 8;
#pragma unroll
        for (int nt = 0; nt < 4; nt++) {
          int j = nt * 16 + m;
          prv[2048 + i * 64 + (j ^ isw)] = f2b(sv[nt]);
        }
      }
    // PV
    f32x4 o[4][2] = {};
#pragma unroll
    for (int ks = 0; ks < 2; ks++) {
      short8 bv[2];
#pragma unroll
      for (int nt = 0; nt < 2; nt++)
        bv[nt] = ld8(&prv[(nt * 16 + m) * 64 + ks * 32 + k0]);
#pragma unroll
      for (int mt = 0; mt < 4; mt++) {
        int i = mt * 16 + m;
        short8 ap = *reinterpret_cast<const short8*>(
            &prv[2048 + i * 64 + ((ks * 32 + k0) ^ ((i & 7) * 8))]);
#pragma unroll
        for (int nt = 0; nt < 2; nt++)
          o[mt][nt] = mfma16(ap, bv[nt], o[mt][nt]);
      }
    }
    // write o directly to raster obr
#pragma unroll
    for (int mt = 0; mt < 4; mt++)
#pragma unroll
      for (int rr = 0; rr < 4; rr++) {
        int i = mt * 16 + gq * 4 + rr;
        if (i >= 49) continue;
        int hh = h0 + i / 7, ww = w0 + i % 7;
        if (hh >= 96 || ww >= 96) continue;
        size_t ras = ((size_t)bimg * 96 + hh) * 96 + ww;
        float rinv = 1.f / rsum[mt][rr];
#pragma unroll
        for (int nt = 0; nt < 2; nt++) {
          int c = h * 32 + nt * 16 + m;
          obr[ras * 256 + c] = f2b(o[mt][nt][rr] * rinv);
        }
      }
  }
}

// ====== K4R: proj GEMM raster (M=73728,N=256,K=256) + shortcut + LN2 partials =
__global__ __launch_bounds__(256) void k4r(
    const u16* W, const u16* obr, const float* proj_b, u16* sc, float* pstat) {
  __shared__ __align__(16) u16 Ab[2][4096];
  __shared__ __align__(16) u16 Bb[2][4096];
  int tid = threadIdx.x;
  int lane = tid & 63, wave = tid >> 6;
  int m = lane & 15, gq = lane >> 4;
  int wr = wave >> 1, wc = wave & 1;
  int bm = blockIdx.x * 128, bn = blockIdx.y * 128;
  const u16* Ag = obr + (size_t)bm * 256;
  const u16* Bg = W + WPROJ + (size_t)bn * 256;
  f32x4 acc[4][4] = {};
#pragma unroll
  for (int c = 0; c < 2; c++) {
    int flat = (wave * 2 + c) * 512 + lane * 8;
    int r = flat >> 5, cc = flat & 31;
    GLL(Ag + (size_t)r * 256 + cc, &Ab[0][(wave * 2 + c) * 512]);
    GLL(Bg + (size_t)r * 256 + cc, &Bb[0][(wave * 2 + c) * 512]);
  }
  __syncthreads();
  int cur = 0;
  for (int ki = 0; ki < 8; ki++) {
    if (ki < 7) {
      int kk = (ki + 1) * 32;
#pragma unroll
      for (int c = 0; c < 2; c++) {
        int flat = (wave * 2 + c) * 512 + lane * 8;
        int r = flat >> 5, cc = flat & 31;
        GLL(Ag + (size_t)r * 256 + kk + cc, &Ab[cur ^ 1][(wave * 2 + c) * 512]);
        GLL(Bg + (size_t)r * 256 + kk + cc, &Bb[cur ^ 1][(wave * 2 + c) * 512]);
      }
    }
    short8 aF[4], bF[4];
#pragma unroll
    for (int mt = 0; mt < 4; mt++)
      aF[mt] = ld8(&Ab[cur][(wr * 64 + mt * 16 + m) * 32 + gq * 8]);
#pragma unroll
    for (int nt = 0; nt < 4; nt++)
      bF[nt] = ld8(&Bb[cur][(wc * 64 + nt * 16 + m) * 32 + gq * 8]);
#pragma unroll
    for (int mt = 0; mt < 4; mt++)
#pragma unroll
      for (int nt = 0; nt < 4; nt++)
        acc[mt][nt] = mfma16(aF[mt], bF[nt], acc[mt][nt]);
    __syncthreads();
    cur ^= 1;
  }
#pragma unroll
  for (int mt = 0; mt < 4; mt++)
#pragma unroll
    for (int rr = 0; rr < 4; rr++) {
      int tok = bm + wr * 64 + mt * 16 + gq * 4 + rr;
      float s = 0.f, s2 = 0.f;
#pragma unroll
      for (int nt = 0; nt < 4; nt++) {
        int ch = bn + wc * 64 + nt * 16 + m;
        float v = acc[mt][nt][rr] + proj_b[ch] + b2f(sc[(size_t)tok * 256 + ch]);
        sc[(size_t)tok * 256 + ch] = f2b(v);
        s += v; s2 += v * v;
      }
#pragma unroll
      for (int off = 1; off < 16; off <<= 1) {
        s += __shfl_xor(s, off);
        s2 += __shfl_xor(s2, off);
      }
      if (m == 0) {
        int pi = (tok * 4 + blockIdx.y * 2 + wc) * 2;
        pstat[pi] = s;
        pstat[pi + 1] = s2;
      }
    }
}

// ====== K5F: mlp1 GEMM on raw x2 + LN2 fold + GELU (M=18432,N=1024,K=256) =====
__global__ __launch_bounds__(256) void k5f(
    const u16* W, const u16* x2b, const float* stat, const float* sgb,
    const float* mb1, u16* h1q) {
  __shared__ __align__(16) u16 Ab[2][4096];
  __shared__ __align__(16) u16 Bb[2][4096];
  int tid = threadIdx.x;
  int lane = tid & 63, wave = tid >> 6;
  int m = lane & 15, gq = lane >> 4;
  int wr = wave >> 1, wc = wave & 1;
  int bm = blockIdx.x * 128, bn = blockIdx.y * 128;
  const u16* Ag = x2b + (size_t)bm * 256;
  const u16* Bg = W + WM1 + (size_t)bn * 256;
  f32x4 acc[4][4] = {};
#pragma unroll
  for (int c = 0; c < 2; c++) {
    int flat = (wave * 2 + c) * 512 + lane * 8;
    int r = flat >> 5, cc = flat & 31;
    GLL(Ag + (size_t)r * 256 + cc, &Ab[0][(wave * 2 + c) * 512]);
    GLL(Bg + (size_t)r * 256 + cc, &Bb[0][(wave * 2 + c) * 512]);
  }
  __syncthreads();
  int cur = 0;
  for (int ki = 0; ki < 8; ki++) {
    if (ki < 7) {
      int kk = (ki + 1) * 32;
#pragma unroll
      for (int c = 0; c < 2; c++) {
        int flat = (wave * 2 + c) * 512 + lane * 8;
        int r = flat >> 5, cc = flat & 31;
        GLL(Ag + (size_t)r * 256 + kk + cc, &Ab[cur ^ 1][(wave * 2 + c) * 512]);
        GLL(Bg + (size_t)r * 256 + kk + cc, &Bb[cur ^ 1][(wave * 2 + c) * 512]);
      }
    }
    short8 aF[4], bF[4];
#pragma unroll
    for (int mt = 0; mt < 4; mt++)
      aF[mt] = ld8(&Ab[cur][(wr * 64 + mt * 16 + m) * 32 + gq * 8]);
#pragma unroll
    for (int nt = 0; nt < 4; nt++)
      bF[nt] = ld8(&Bb[cur][(wc * 64 + nt * 16 + m) * 32 + gq * 8]);
#pragma unroll
    for (int mt = 0; mt < 4; mt++)
#pragma unroll
      for (int nt = 0; nt < 4; nt++)
        acc[mt][nt] = mfma16(aF[mt], bF[nt], acc[mt][nt]);
    __syncthreads();
    cur ^= 1;
  }
  float sgv[4], sbv[4], b1v[4];
#pragma unroll
  for (int nt = 0; nt < 4; nt++) {
    int ch = bn + wc * 64 + nt * 16 + m;
    sgv[nt] = sgb[ch];
    sbv[nt] = sgb[1024 + ch];
    b1v[nt] = mb1[ch];
  }
#pragma unroll
  for (int mt = 0; mt < 4; mt++)
#pragma unroll
    for (int rr = 0; rr < 4; rr++) {
      int tok = bm + wr * 64 + mt * 16 + gq * 4 + rr;
      float rs = stat[tok * 2], rmu = stat[tok * 2 + 1];
#pragma unroll
      for (int nt = 0; nt < 4; nt++) {
        float v = rs * acc[mt][nt][rr] - rmu * sgv[nt] + sbv[nt] + b1v[nt];
        v = 0.5f * v * (1.f + erff(v * 0.7071067811865475f));
        h1q[(size_t)tok * 1024 + (bn + wc * 64 + nt * 16 + m)] = f2b(v);
      }
    }
}

// ====== K6G: mlp2 GEMM (M=18432,N=256,K=1024), 64x128 tile + NCHW out =========
__global__ __launch_bounds__(256) void k6g(
    const u16* W, const u16* h1q, const float* mb2, const u16* x2b,
    float* out, int tok_base) {
  __shared__ __align__(16) u16 Ab[2][2048];
  __shared__ __align__(16) u16 Bb[2][4096];
  __shared__ float ot[128 * 66];
  int tid = threadIdx.x;
  int lane = tid & 63, wave = tid >> 6;
  int m = lane & 15, gq = lane >> 4;
  int wr = wave >> 1, wc = wave & 1;
  int bm = blockIdx.x * 64, bn = blockIdx.y * 128;
  const u16* Ag = h1q + (size_t)bm * 1024;
  const u16* Bg = W + WM2 + (size_t)bn * 1024;
  f32x4 acc[2][4] = {};
  {
    int flatA = wave * 512 + lane * 8;
    GLL(Ag + (size_t)(flatA >> 5) * 1024 + (flatA & 31), &Ab[0][wave * 512]);
#pragma unroll
    for (int c = 0; c < 2; c++) {
      int flat = (wave * 2 + c) * 512 + lane * 8;
      GLL(Bg + (size_t)(flat >> 5) * 1024 + (flat & 31), &Bb[0][(wave * 2 + c) * 512]);
    }
  }
  __syncthreads();
  int cur = 0;
  for (int ki = 0; ki < 32; ki++) {
    if (ki < 31) {
      int kk = (ki + 1) * 32;
      int flatA = wave * 512 + lane * 8;
      GLL(Ag + (size_t)(flatA >> 5) * 1024 + kk + (flatA & 31), &Ab[cur ^ 1][wave * 512]);
#pragma unroll
      for (int c = 0; c < 2; c++) {
        int flat = (wave * 2 + c) * 512 + lane * 8;
        GLL(Bg + (size_t)(flat >> 5) * 1024 + kk + (flat & 31), &Bb[cur ^ 1][(wave * 2 + c) * 512]);
      }
    }
    short8 aF[2], bF[4];
#pragma unroll
    for (int mt = 0; mt < 2; mt++)
      aF[mt] = ld8(&Ab[cur][(wr * 32 + mt * 16 + m) * 32 + gq * 8]);
#pragma unroll
    for (int nt = 0; nt < 4; nt++)
      bF[nt] = ld8(&Bb[cur][(wc * 64 + nt * 16 + m) * 32 + gq * 8]);
#pragma unroll
    for (int mt = 0; mt < 2; mt++)
#pragma unroll
      for (int nt = 0; nt < 4; nt++)
        acc[mt][nt] = mfma16(aF[mt], bF[nt], acc[mt][nt]);
    __syncthreads();
    cur ^= 1;
  }
#pragma unroll
  for (int nt = 0; nt < 4; nt++) {
    int nl = wc * 64 + nt * 16 + m;
    int ch = bn + nl;
    float bias = mb2[ch];
#pragma unroll
    for (int mt = 0; mt < 2; mt++)
#pragma unroll
      for (int rr = 0; rr < 4; rr++) {
        int tl = wr * 32 + mt * 16 + gq * 4 + rr;
        float v = acc[mt][nt][rr] + bias + b2f(x2b[(size_t)(bm + tl) * 256 + ch]);
        ot[nl * 66 + tl] = v;
      }
  }
  __syncthreads();
  int tg = tok_base + bm;
  int bimg = tg / 9216, hw0 = tg % 9216;
  for (int it = 0; it < 32; it++) {
    int flat = it * 256 + tid;
    int j = flat >> 6, t = flat & 63;
    out[((size_t)bimg * 256 + bn + j) * 9216 + hw0 + t] = ot[j * 66 + t];
  }
}

extern "C" void kernel_launch(void* const* d_in, const int* in_sizes, int n_in,
                              void* d_out, int out_size, void* d_ws, size_t ws_size,
                              hipStream_t stream) {
  const float* x      = (const float*)d_in[0];
  const float* skipf  = (const float*)d_in[1];
  const float* up_w   = (const float*)d_in[2];
  const float* up_b   = (const float*)d_in[3];
  const float* skip_w = (const float*)d_in[4];
  const float* g1     = (const float*)d_in[5];
  const float* be1    = (const float*)d_in[6];
  const float* qkv_w  = (const float*)d_in[7];
  const float* qkv_b  = (const float*)d_in[8];
  const float* rpb    = (const float*)d_in[9];
  const float* proj_w = (const float*)d_in[10];
  const float* proj_b = (const float*)d_in[11];
  const float* g2     = (const float*)d_in[12];
  const float* be2    = (const float*)d_in[13];
  const float* m_w1   = (const float*)d_in[14];
  const float* m_b1   = (const float*)d_in[15];
  const float* m_w2   = (const float*)d_in[16];
  const float* m_b2   = (const float*)d_in[17];
  if (ws_size < WS_NEED) {
    k_sentinel<<<1, 256, 0, stream>>>((float*)d_out);
    return;
  }
  char* ws = (char*)d_ws;
  u16*   W    = (u16*)ws;
  float* bias = (float*)(ws + OFF_BIAS);
  u16*   sc   = (u16*)(ws + OFF_SC);
  u16*   xt   = (u16*)(ws + OFF_OVR);
  u16*   skt  = (u16*)(ws + OFF_OVR);
  u16*   h1q  = (u16*)(ws + OFF_OVR);
  float* stat = (float*)(ws + OFF_STAT);
  float* pst  = (float*)(ws + OFF_PST);
  float* sgb  = (float*)(ws + OFF_SGB);
  u16*   ybuf = (u16*)d_out;
  u16*   obr  = (u16*)((char*)d_out + 37748736u);

  k_prep<<<5519, 256, 0, stream>>>(qkv_w, proj_w, m_w1, m_w2, skip_w, up_w, rpb,
                                   g1, be1, g2, be2, W, bias, sgb);
  k_tr<<<dim3(72, 16, 8), 256, 0, stream>>>(x, xt, 512, 2304);
  k1g<<<dim3(144, 2, 4), 256, 0, stream>>>(W, xt, up_b, sc);
  k_tr_skip<<<dim3(3, 8, 768), 256, 0, stream>>>(skipf, skt);
  k2y<<<dim3(576, 2), 256, 0, stream>>>(W, skt, sc, ybuf, pst);
  k_statfin<<<288, 256, 0, stream>>>(pst, stat);
  k23<<<1568, 256, 0, stream>>>(W, ybuf, stat, sgb, qkv_b, bias, obr);
  k4r<<<dim3(576, 2), 256, 0, stream>>>(W, obr, proj_b, sc, pst);
  k_statfin<<<288, 256, 0, stream>>>(pst, stat);
  for (int q = 0; q < 4; q++) {
    const u16* x2b = sc + (size_t)q * 18432 * 256;
    k5f<<<dim3(144, 8), 256, 0, stream>>>(W, x2b, stat + (size_t)q * 36864,
                                          sgb, m_b1, h1q);
    k6g<<<dim3(288, 2), 256, 0, stream>>>(W, h1q, m_b2, x2b, (float*)d_out, q * 18432);
  }
}